// Round 3
// baseline (575.668 us; speedup 1.0000x reference)
//
#include <hip/hip_runtime.h>
#include <hip/hip_bf16.h>
#include <math.h>

// Problem constants
#define BATCH 512
#define NSEG  64
#define HID   1024
#define ATT   128

typedef __attribute__((ext_vector_type(8))) __bf16 bf16x8;
typedef __attribute__((ext_vector_type(4))) __bf16 bf16x4;
typedef __attribute__((ext_vector_type(4))) float  f32x4;

// ---------------------------------------------------------------------------
// conv1 weight pre-convert: w[co][ci][kh][kw] (8,3,5,5) fp32 ->
// wt[k8][m16][j8] bf16 with k = tap*4 + ci (ci padded to 4), K=100 pad 128.
// ---------------------------------------------------------------------------
__global__ void wconv1_k(const float* __restrict__ w, __bf16* __restrict__ wt) {
    int t = blockIdx.x * 256 + threadIdx.x;   // n = 16*16*8 = 2048
    if (t >= 2048) return;
    int j = t & 7, m = (t >> 3) & 15, k8 = t >> 7;
    int k = k8 * 8 + j, tap = k >> 2, ci = k & 3;
    float v = 0.f;
    if (m < 8 && ci < 3 && tap < 25) v = w[(m * 3 + ci) * 25 + tap];
    wt[t] = (__bf16)v;
}

// ---------------------------------------------------------------------------
// conv1 via MFMA, 2D tile + zero-padded halo (verified round 1: 75 us).
// ---------------------------------------------------------------------------
__global__ __launch_bounds__(256) void conv1_mfma_k(
    const float* __restrict__ in, const __bf16* __restrict__ Wt,
    const float* __restrict__ bias, __bf16* __restrict__ out) {
    constexpr int W  = 128;
    constexpr int R  = 4;
    constexpr int RP = R + 4;
    constexpr int WP = W + 4;
    constexpr int CSTR = R * W + 4;        // 516 f32

    __shared__ __align__(16) __bf16 xs[RP * WP * 4];   // 8448 B
    __shared__ float cs[8 * CSTR];                     // 16512 B

    const int tid = threadIdx.x;
    const int b   = blockIdx.x >> 5;
    const int y0  = (blockIdx.x & 31) * R;
    const float* inb = in + (size_t)b * 3 * 16384;

    if (tid < RP * 4) {
        int r = tid >> 2, s = tid & 3;
        int c = (s < 2) ? s : (128 + s);        // 0,1,130,131
        *(bf16x4*)(xs + (r * WP + c) * 4) = (bf16x4){};
    }
    {
        int r  = tid >> 5;
        int g  = tid & 31;
        int gy = y0 + r - 2;
        int c0 = g * 4;
        bf16x8 lo = {}, hi = {};
        if ((unsigned)gy < 128u) {
            const float* p = inb + (size_t)gy * 128 + c0;
            float4 a = *(const float4*)(p);
            float4 q = *(const float4*)(p + 16384);
            float4 c = *(const float4*)(p + 32768);
            lo[0] = (__bf16)a.x; lo[1] = (__bf16)q.x; lo[2] = (__bf16)c.x;
            lo[4] = (__bf16)a.y; lo[5] = (__bf16)q.y; lo[6] = (__bf16)c.y;
            hi[0] = (__bf16)a.z; hi[1] = (__bf16)q.z; hi[2] = (__bf16)c.z;
            hi[4] = (__bf16)a.w; hi[5] = (__bf16)q.w; hi[6] = (__bf16)c.w;
        }
        *(bf16x8*)(xs + (r * WP + c0 + 2) * 4)     = lo;
        *(bf16x8*)(xs + (r * WP + c0 + 2) * 4 + 8) = hi;
    }
    __syncthreads();

    const int lane = tid & 63, wave = tid >> 6;
    const int quad = lane >> 4, l15 = lane & 15;
    constexpr int F = 8;

    int pbase[F];
    f32x4 acc[F];
#pragma unroll
    for (int f = 0; f < F; ++f) {
        pbase[f] = ((wave + 2) * WP + f * 16 + l15 + 2) * 8;
        acc[f] = f32x4{0.f, 0.f, 0.f, 0.f};
    }
    const char* xsb = (const char*)xs;

#pragma unroll
    for (int kt = 0; kt < 4; ++kt) {
        int k8 = kt * 4 + quad;
        int tap0 = k8 * 2, tap1 = tap0 + 1;
        int t0 = tap0 < 25 ? tap0 : 0;
        int t1 = tap1 < 25 ? tap1 : 0;
        int s0 = ((t0 / 5 - 2) * WP + (t0 % 5 - 2)) * 8;
        int s1 = ((t1 / 5 - 2) * WP + (t1 % 5 - 2)) * 8;
        bf16x8 av = *(const bf16x8*)(Wt + ((size_t)k8 * 16 + l15) * 8);
#pragma unroll
        for (int f = 0; f < F; ++f) {
            bf16x4 b0 = *(const bf16x4*)(xsb + pbase[f] + s0);
            bf16x4 b1 = *(const bf16x4*)(xsb + pbase[f] + s1);
            bf16x8 bv = __builtin_shufflevector(b0, b1, 0, 1, 2, 3, 4, 5, 6, 7);
            acc[f] = __builtin_amdgcn_mfma_f32_16x16x32_bf16(av, bv, acc[f], 0, 0, 0);
        }
    }

#pragma unroll
    for (int f = 0; f < F; ++f) {
        int pl = wave * 128 + f * 16 + l15;
#pragma unroll
        for (int r = 0; r < 4; ++r) {
            int m = quad * 4 + r;
            if (m < 8) cs[m * CSTR + pl] = acc[f][r];
        }
    }
    __syncthreads();

    {
        int oi  = tid >> 1;
        int cog = (tid & 1) * 4;
        int oy  = oi >> 6, ox = oi & 63;
        int pl0 = oy * 2 * 128 + ox * 2;
        float4 b4 = *(const float4*)(bias + cog);
        bf16x4 ov;
#pragma unroll
        for (int i = 0; i < 4; ++i) {
            int cr = cog + i;
            float v0 = cs[cr * CSTR + pl0],       v1 = cs[cr * CSTR + pl0 + 1];
            float v2 = cs[cr * CSTR + pl0 + 128], v3 = cs[cr * CSTR + pl0 + 129];
            float m = fmaxf(fmaxf(v0, v1), fmaxf(v2, v3)) + ((const float*)&b4)[i];
            ov[i] = (__bf16)fmaxf(m, 0.f);
        }
        size_t ob = ((size_t)b * 4096 + (size_t)(y0 / 2 + oy) * 64 + ox) * 8 + cog;
        *(bf16x4*)(out + ob) = ov;
    }
}

// ---------------------------------------------------------------------------
// Conv weight pre-convert: w[co][ci][kh][kw] fp32 -> wt[k/8][co][k%8] bf16,
// k = (kh*5+kw)*Ci + ci.
// ---------------------------------------------------------------------------
template<int Ci, int Co>
__global__ void wconv_k(const float* __restrict__ w, __bf16* __restrict__ wt) {
    const int n = 25 * Ci * Co;
    int t = blockIdx.x * 256 + threadIdx.x;
    if (t >= n) return;
    int j  = t & 7;
    int t2 = t >> 3;
    int co = t2 % Co;
    int k8 = t2 / Co;
    int k  = k8 * 8 + j;
    int tap = k / Ci, ci = k % Ci;
    int kh = tap / 5, kw = tap % 5;
    wt[t] = (__bf16)w[((co * Ci + ci) * 25) + kh * 5 + kw];
}

// ---------------------------------------------------------------------------
// FC weight pre-convert: fcw[o][k] fp32 (o<1024, k<2048) -> wt[k8][o][j] bf16.
// ---------------------------------------------------------------------------
__global__ void wfc_k(const float* __restrict__ w, __bf16* __restrict__ wt) {
    int t = blockIdx.x * 256 + threadIdx.x;   // n = 2,097,152
    int j  = t & 7;
    int t2 = t >> 3;
    int o  = t2 & 1023;
    int k8 = t2 >> 10;
    wt[t] = (__bf16)w[(size_t)o * 2048 + k8 * 8 + j];
}

// ---------------------------------------------------------------------------
// conv2..5 (round 3): single block per spatial tile handles ALL co-tiles:
// stage once, reuse B-frags across co-tiles (x NCOT arithmetic intensity).
// Pool 2x2 entirely in registers via shfl (no cs LDS pass, one barrier).
// Frag->position mapping guarantees pool partners:
//   horizontal: lane l15^1; vertical: frag pairs (W>=16) or l15^8 (W==8).
// OUTMODE 0 = NHWC bf16, 1 = flat [b][co*16+oy*4+ox] (conv5 -> FC).
// ---------------------------------------------------------------------------
template<int Ci, int Co, int H, int RB, int IMGS, int OUTMODE>
__global__ __launch_bounds__(256) void conv2d_mfma_k(
    const __bf16* __restrict__ X, const __bf16* __restrict__ Wt,
    const float* __restrict__ bias, void* __restrict__ outp) {
    constexpr int W    = H;
    constexpr int PW   = W + 4;
    constexpr int PR   = RB + 4;
    constexpr int PIX  = RB * W;
    constexpr int P    = IMGS * PIX;
    constexpr int SE   = Ci + (Ci >= 16 ? 8 : 0);   // bank-coprime stride
    constexpr int SB   = SE * 2;                    // 16/48/80/144 B
    constexpr int K    = 25 * Ci;
    constexpr int KTF  = K / 32;
    constexpr int FW   = P / 64;                    // frags per wave
    constexpr int NCOT = Co / 16;                   // co tiles
    constexpr int C8   = Ci / 8;
    constexpr int BPI  = H / RB;
    constexpr int OW   = W / 2;

    __shared__ __align__(16) char smem[IMGS * PR * PW * SB];

    const int tid = threadIdx.x;
    const int b0  = (blockIdx.x / BPI) * IMGS;
    const int y0  = (blockIdx.x % BPI) * RB;

    // ---- stage padded tile(s); zeros at all out-of-image positions ----
    constexpr int NSLOT = IMGS * PR * PW * C8;
    for (int i = tid; i < NSLOT; i += 256) {
        int s   = i % C8;
        int t2  = i / C8;
        int pc  = t2 % PW;
        int t3  = t2 / PW;
        int pr  = t3 % PR;
        int img = t3 / PR;
        int gy  = y0 + pr - 2;
        int gx  = pc - 2;
        bf16x8 v = {};
        if ((unsigned)gy < (unsigned)H && (unsigned)gx < (unsigned)W)
            v = *(const bf16x8*)(X + (((size_t)(b0 + img) * H + gy) * W + gx) * Ci + s * 8);
        *(bf16x8*)(smem + ((size_t)(img * PR + pr) * PW + pc) * SB + s * 16) = v;
    }
    __syncthreads();

    const int lane = tid & 63, wave = tid >> 6;
    const int quad = lane >> 4, l15 = lane & 15;

    int pbase[FW];
    f32x4 acc[FW][NCOT];
    int rg = 0, ch = 0, gbase = 0, img5 = 0;
    if constexpr (W >= 16) {
        constexpr int C16 = W / 16;
        ch = wave % C16;
        rg = wave / C16;
#pragma unroll
        for (int f = 0; f < FW; ++f) {
            int row = rg * FW + f;
            pbase[f] = ((row + 2) * PW + ch * 16 + l15 + 2) * SB;
        }
    } else {
        img5  = wave >> 1;
        gbase = (wave & 1) * FW;
#pragma unroll
        for (int f = 0; f < FW; ++f) {
            int g    = gbase + f;
            int row0 = 2 * g + (l15 >> 3);
            pbase[f] = ((img5 * PR + row0 + 2) * PW + (l15 & 7) + 2) * SB;
        }
    }
#pragma unroll
    for (int f = 0; f < FW; ++f)
#pragma unroll
        for (int c = 0; c < NCOT; ++c) acc[f][c] = f32x4{0.f, 0.f, 0.f, 0.f};

    const bf16x8 BZ = {};
    auto kstep = [&](int kt, bool mask) {
        int k8 = kt * 4 + quad;
        int kk = k8 * 8;
        bool kok = true;
        if (mask) { kok = kk < K; if (!kok) { k8 = 0; kk = 0; } }
        int tap = kk / Ci, cio = kk % Ci;
        int dy = tap / 5 - 2, dx = tap % 5 - 2;
        int shift = (dy * PW + dx) * SB + cio * 2;
        bf16x8 bv[FW];
#pragma unroll
        for (int f = 0; f < FW; ++f) {
            bv[f] = *(const bf16x8*)(smem + pbase[f] + shift);
            if (mask && !kok) bv[f] = BZ;
        }
#pragma unroll
        for (int c = 0; c < NCOT; ++c) {
            bf16x8 av = *(const bf16x8*)(Wt + ((size_t)k8 * Co + c * 16 + l15) * 8);
#pragma unroll
            for (int f = 0; f < FW; ++f)
                acc[f][c] = __builtin_amdgcn_mfma_f32_16x16x32_bf16(av, bv[f], acc[f][c], 0, 0, 0);
        }
    };
#pragma unroll 2
    for (int kt = 0; kt < KTF; ++kt) kstep(kt, false);
    if constexpr (K % 32 != 0) kstep(KTF, true);

    // ---- pool 2x2 + bias + relu, all in registers ----
    if constexpr (W >= 16) {
#pragma unroll
        for (int fp = 0; fp < FW / 2; ++fp) {
            int f0  = 2 * fp;
            int row = rg * FW + f0;
            int oy  = (y0 + row) >> 1;
            int ox  = (ch * 16 + l15) >> 1;
            bool on = (l15 & 1) == 0;
#pragma unroll
            for (int c = 0; c < NCOT; ++c) {
                float4 bb = *(const float4*)(bias + c * 16 + quad * 4);
                bf16x4 ov;
#pragma unroll
                for (int r = 0; r < 4; ++r) {
                    float v0 = acc[f0][c][r];
                    float h0 = fmaxf(v0, __shfl_xor(v0, 1));
                    float v1 = acc[f0 + 1][c][r];
                    float h1 = fmaxf(v1, __shfl_xor(v1, 1));
                    float m  = fmaxf(h0, h1) + ((const float*)&bb)[r];
                    ov[r] = (__bf16)fmaxf(m, 0.f);
                }
                if (on)
                    *(bf16x4*)((__bf16*)outp +
                        (((size_t)b0 * (H / 2) + oy) * OW + ox) * Co + c * 16 + quad * 4) = ov;
            }
        }
    } else {
        // W == 8 (conv5): frag spans row pair via l15>>3; OUTMODE==1 flat out
#pragma unroll
        for (int f = 0; f < FW; ++f) {
            int g   = gbase + f;
            bool on = ((l15 & 1) == 0) && (l15 < 8);
            int ox  = (l15 & 7) >> 1;
#pragma unroll
            for (int c = 0; c < NCOT; ++c) {
                float4 bb = *(const float4*)(bias + c * 16 + quad * 4);
#pragma unroll
                for (int r = 0; r < 4; ++r) {
                    float v  = acc[f][c][r];
                    float h  = fmaxf(v, __shfl_xor(v, 1));
                    float m2 = fmaxf(h, __shfl_xor(h, 8));
                    float m  = fmaxf(m2 + ((const float*)&bb)[r], 0.f);
                    if (on)
                        ((__bf16*)outp)[(size_t)(b0 + img5) * 2048 +
                            (c * 16 + quad * 4 + r) * 16 + g * 4 + ox] = (__bf16)m;
                }
            }
        }
    }
}

// ---------------------------------------------------------------------------
// FC via MFMA (verified round 8).
// ---------------------------------------------------------------------------
__global__ __launch_bounds__(256) void fc_mfma_k(
    const __bf16* __restrict__ Xb, const __bf16* __restrict__ Wfc,
    const float* __restrict__ bias, float* __restrict__ emb) {
    const int tid  = threadIdx.x;
    const int lane = tid & 63, wave = tid >> 6;
    const int quad = lane >> 4, l15 = lane & 15;
    const int n0   = blockIdx.x * 128;
    const int co0  = blockIdx.y * 16;

    int n[2];
    f32x4 acc[2];
#pragma unroll
    for (int f = 0; f < 2; ++f) {
        n[f] = n0 + wave * 32 + f * 16 + l15;
        acc[f] = f32x4{0.f, 0.f, 0.f, 0.f};
    }

#pragma unroll 4
    for (int kt = 0; kt < 64; ++kt) {
        int k8 = kt * 4 + quad;
        bf16x8 av = *(const bf16x8*)(Wfc + ((size_t)k8 * 1024 + co0 + l15) * 8);
#pragma unroll
        for (int f = 0; f < 2; ++f) {
            bf16x8 bv = *(const bf16x8*)(Xb + (size_t)n[f] * 2048 + k8 * 8);
            acc[f] = __builtin_amdgcn_mfma_f32_16x16x32_bf16(av, bv, acc[f], 0, 0, 0);
        }
    }

    float4 b4 = *(const float4*)(bias + co0 + quad * 4);
#pragma unroll
    for (int f = 0; f < 2; ++f) {
        f32x4 v = acc[f];
        v[0] += b4.x; v[1] += b4.y; v[2] += b4.z; v[3] += b4.w;
        *(f32x4*)(emb + (size_t)n[f] * 1024 + co0 + quad * 4) = v;
    }
}

// ---------------------------------------------------------------------------
// Attention via MFMA (round 3): S^T = w1 (128xK) x emb^T (Kx512) in bf16,
// f32->bf16 fragment conversion in-register.  C rows = att j (quad*4+r),
// C cols = batch (l15).  tanh+*w2 rowsum reduced via 2 shfl_xor.
// ---------------------------------------------------------------------------
__device__ inline bf16x8 cvt8(const float* __restrict__ p) {
    float4 a = *(const float4*)p, b = *(const float4*)(p + 4);
    bf16x8 v;
    v[0] = (__bf16)a.x; v[1] = (__bf16)a.y; v[2] = (__bf16)a.z; v[3] = (__bf16)a.w;
    v[4] = (__bf16)b.x; v[5] = (__bf16)b.y; v[6] = (__bf16)b.z; v[7] = (__bf16)b.w;
    return v;
}

__global__ __launch_bounds__(256) void att_mfma_k(
    const float* __restrict__ emb, const float* __restrict__ w1,
    const float* __restrict__ b1, const float* __restrict__ w2,
    const float* __restrict__ b2, float* __restrict__ logits) {
    const int tid = threadIdx.x, lane = tid & 63, wave = tid >> 6;
    const int quad = lane >> 4, l15 = lane & 15;
    const int n = (blockIdx.x * 4 + wave) * 16 + l15;   // batch index

    f32x4 acc[8];
#pragma unroll
    for (int t = 0; t < 8; ++t) acc[t] = f32x4{0.f, 0.f, 0.f, 0.f};

    for (int kt = 0; kt < 32; ++kt) {
        int k8 = kt * 4 + quad;
        bf16x8 bv = cvt8(emb + (size_t)n * 1024 + k8 * 8);
#pragma unroll
        for (int t = 0; t < 8; ++t) {
            bf16x8 av = cvt8(w1 + (size_t)(t * 16 + l15) * 1024 + k8 * 8);
            acc[t] = __builtin_amdgcn_mfma_f32_16x16x32_bf16(av, bv, acc[t], 0, 0, 0);
        }
    }

    float sum = 0.f;
#pragma unroll
    for (int t = 0; t < 8; ++t) {
#pragma unroll
        for (int r = 0; r < 4; ++r) {
            int j = t * 16 + quad * 4 + r;
            sum += tanhf(acc[t][r] + b1[j]) * w2[j];
        }
    }
    sum += __shfl_xor(sum, 16);
    sum += __shfl_xor(sum, 32);
    if (quad == 0) logits[n] = sum + b2[0];
}

// ---------------------------------------------------------------------------
// Segment softmax + aggregation + classifier
// ---------------------------------------------------------------------------
__global__ __launch_bounds__(256) void segment_k(
    const float* __restrict__ emb, const float* __restrict__ logits,
    const int* __restrict__ cid, const float* __restrict__ clf_w,
    const float* __restrict__ clf_b, float* __restrict__ out) {
    const int c = blockIdx.x;
    const int t = threadIdx.x;
    __shared__ int cids[BATCH];
    __shared__ float red[256];
    for (int i = t; i < BATCH; i += 256) cids[i] = cid[i];
    __syncthreads();

    float lm = -1e30f;
    for (int b = t; b < BATCH; b += 256)
        if (cids[b] == c) lm = fmaxf(lm, logits[b]);
    red[t] = lm; __syncthreads();
    for (int s = 128; s > 0; s >>= 1) {
        if (t < s) red[t] = fmaxf(red[t], red[t + s]);
        __syncthreads();
    }
    float smax = red[0]; __syncthreads();

    float ls = 0.f;
    for (int b = t; b < BATCH; b += 256)
        if (cids[b] == c) ls += expf(logits[b] - smax);
    red[t] = ls; __syncthreads();
    for (int s = 128; s > 0; s >>= 1) {
        if (t < s) red[t] += red[t + s];
        __syncthreads();
    }
    float denom = red[0]; __syncthreads();
    float inv = (denom > 0.f) ? 1.f / denom : 0.f;

    const int h0 = t * 4;
    float g0 = 0.f, g1 = 0.f, g2 = 0.f, g3 = 0.f;
    for (int b = 0; b < BATCH; ++b) {
        if (cids[b] == c) {
            float wgt = expf(logits[b] - smax) * inv;
            float4 ev = *(const float4*)(emb + (size_t)b * HID + h0);
            g0 = fmaf(wgt, ev.x, g0);
            g1 = fmaf(wgt, ev.y, g1);
            g2 = fmaf(wgt, ev.z, g2);
            g3 = fmaf(wgt, ev.w, g3);
        }
    }
    float4 cw = *(const float4*)(clf_w + h0);
    float ca = g0 * cw.x + g1 * cw.y + g2 * cw.z + g3 * cw.w;
    red[t] = ca; __syncthreads();
    for (int s = 128; s > 0; s >>= 1) {
        if (t < s) red[t] += red[t + s];
        __syncthreads();
    }
    if (t == 0) out[c] = 1.f / (1.f + expf(-(red[0] + clf_b[0])));
}

// ---------------------------------------------------------------------------
extern "C" void kernel_launch(void* const* d_in, const int* in_sizes, int n_in,
                              void* d_out, int out_size, void* d_ws, size_t ws_size,
                              hipStream_t stream) {
    const float* data = (const float*)d_in[0];
    const int*   cid  = (const int*)d_in[1];
    const float* cw1 = (const float*)d_in[2],  * cb1 = (const float*)d_in[3];
    const float* cw2 = (const float*)d_in[4],  * cb2 = (const float*)d_in[5];
    const float* cw3 = (const float*)d_in[6],  * cb3 = (const float*)d_in[7];
    const float* cw4 = (const float*)d_in[8],  * cb4 = (const float*)d_in[9];
    const float* cw5 = (const float*)d_in[10], * cb5 = (const float*)d_in[11];
    const float* fcw = (const float*)d_in[12], * fcb = (const float*)d_in[13];
    const float* aw1 = (const float*)d_in[14], * ab1 = (const float*)d_in[15];
    const float* aw2 = (const float*)d_in[16], * ab2 = (const float*)d_in[17];
    const float* clw = (const float*)d_in[18], * clb = (const float*)d_in[19];
    float* out = (float*)d_out;

    // workspace (bytes), non-overlapping, ~71.9 MB
    char* wsb = (char*)d_ws;
    __bf16* x1  = (__bf16*)(wsb);              // 512*4096*8   bf16 = 33,554,432 B
    __bf16* x2  = (__bf16*)(wsb + 33554432);   // 512*1024*16  bf16 = 16,777,216 B
    __bf16* x3  = (__bf16*)(wsb + 50331648);   // 512*256*32   bf16 =  8,388,608 B
    __bf16* x4  = (__bf16*)(wsb + 58720256);   // 512*64*64    bf16 =  4,194,304 B
    __bf16* x5b = (__bf16*)(wsb + 62914560);   // 512*2048     bf16 =  2,097,152 B
    float*  emb = (float*) (wsb + 65011712);   // 512*1024     f32  =  2,097,152 B
    float*  lg  = (float*) (wsb + 67108864);   // 512 f32
    __bf16* wt2 = (__bf16*)(wsb + 67110912);   //   3,200 bf16
    __bf16* wt3 = (__bf16*)(wsb + 67117312);   //  12,800 bf16
    __bf16* wt4 = (__bf16*)(wsb + 67142912);   //  51,200 bf16
    __bf16* wt5 = (__bf16*)(wsb + 67245312);   // 204,800 bf16
    __bf16* wfc = (__bf16*)(wsb + 67654912);   // 2,097,152 bf16 = 4,194,304 B
    __bf16* wt1 = (__bf16*)(wsb + 71849216);   //   2,048 bf16

    wconv1_k<<<8, 256, 0, stream>>>(cw1, wt1);
    wconv_k<8,  16 ><<<(3200   + 255) / 256, 256, 0, stream>>>(cw2, wt2);
    wconv_k<16, 32 ><<<(12800  + 255) / 256, 256, 0, stream>>>(cw3, wt3);
    wconv_k<32, 64 ><<<(51200  + 255) / 256, 256, 0, stream>>>(cw4, wt4);
    wconv_k<64, 128><<<(204800 + 255) / 256, 256, 0, stream>>>(cw5, wt5);
    wfc_k<<<2097152 / 256, 256, 0, stream>>>(fcw, wfc);

    // conv1: 512 images x 32 row-blocks
    conv1_mfma_k<<<16384, 256, 0, stream>>>(data, wt1, cb1, x1);

    // conv2..5: single y-block, all co-tiles per block, register pooling
    conv2d_mfma_k<8,  16,  64, 8,  1, 0><<<4096, 256, 0, stream>>>(x1, wt2, cb2, x2);
    conv2d_mfma_k<16, 32,  32, 8,  1, 0><<<2048, 256, 0, stream>>>(x2, wt3, cb3, x3);
    conv2d_mfma_k<32, 64,  16, 16, 1, 0><<<512,  256, 0, stream>>>(x3, wt4, cb4, x4);
    conv2d_mfma_k<64, 128, 8,  8,  2, 1><<<256,  256, 0, stream>>>(x4, wt5, cb5, x5b);

    fc_mfma_k<<<dim3(4, 64), 256, 0, stream>>>(x5b, wfc, fcb, emb);
    att_mfma_k<<<8, 256, 0, stream>>>(emb, aw1, ab1, aw2, ab2, lg);
    segment_k<<<NSEG, 256, 0, stream>>>(emb, lg, cid, clw, clb, out);
}

// Round 5
// 447.406 us; speedup vs baseline: 1.2867x; 1.2867x over previous
//
#include <hip/hip_runtime.h>
#include <hip/hip_bf16.h>
#include <math.h>

// Problem constants
#define BATCH 512
#define NSEG  64
#define HID   1024
#define ATT   128

typedef __attribute__((ext_vector_type(8))) __bf16 bf16x8;
typedef __attribute__((ext_vector_type(4))) __bf16 bf16x4;
typedef __attribute__((ext_vector_type(4))) float  f32x4;

// ---------------------------------------------------------------------------
// conv1 weight pre-convert: w[co][ci][kh][kw] (8,3,5,5) fp32 ->
// wt[k8][m16][j8] bf16 with k = tap*4 + ci (ci padded to 4), K=100 pad 128.
// ---------------------------------------------------------------------------
__global__ void wconv1_k(const float* __restrict__ w, __bf16* __restrict__ wt) {
    int t = blockIdx.x * 256 + threadIdx.x;   // n = 16*16*8 = 2048
    if (t >= 2048) return;
    int j = t & 7, m = (t >> 3) & 15, k8 = t >> 7;
    int k = k8 * 8 + j, tap = k >> 2, ci = k & 3;
    float v = 0.f;
    if (m < 8 && ci < 3 && tap < 25) v = w[(m * 3 + ci) * 25 + tap];
    wt[t] = (__bf16)v;
}

// ---------------------------------------------------------------------------
// conv1 via MFMA, 2D tile + zero-padded halo (verified round 1: 75 us).
// ---------------------------------------------------------------------------
__global__ __launch_bounds__(256) void conv1_mfma_k(
    const float* __restrict__ in, const __bf16* __restrict__ Wt,
    const float* __restrict__ bias, __bf16* __restrict__ out) {
    constexpr int W  = 128;
    constexpr int R  = 4;
    constexpr int RP = R + 4;
    constexpr int WP = W + 4;
    constexpr int CSTR = R * W + 4;        // 516 f32

    __shared__ __align__(16) __bf16 xs[RP * WP * 4];   // 8448 B
    __shared__ float cs[8 * CSTR];                     // 16512 B

    const int tid = threadIdx.x;
    const int b   = blockIdx.x >> 5;
    const int y0  = (blockIdx.x & 31) * R;
    const float* inb = in + (size_t)b * 3 * 16384;

    if (tid < RP * 4) {
        int r = tid >> 2, s = tid & 3;
        int c = (s < 2) ? s : (128 + s);        // 0,1,130,131
        *(bf16x4*)(xs + (r * WP + c) * 4) = (bf16x4){};
    }
    {
        int r  = tid >> 5;
        int g  = tid & 31;
        int gy = y0 + r - 2;
        int c0 = g * 4;
        bf16x8 lo = {}, hi = {};
        if ((unsigned)gy < 128u) {
            const float* p = inb + (size_t)gy * 128 + c0;
            float4 a = *(const float4*)(p);
            float4 q = *(const float4*)(p + 16384);
            float4 c = *(const float4*)(p + 32768);
            lo[0] = (__bf16)a.x; lo[1] = (__bf16)q.x; lo[2] = (__bf16)c.x;
            lo[4] = (__bf16)a.y; lo[5] = (__bf16)q.y; lo[6] = (__bf16)c.y;
            hi[0] = (__bf16)a.z; hi[1] = (__bf16)q.z; hi[2] = (__bf16)c.z;
            hi[4] = (__bf16)a.w; hi[5] = (__bf16)q.w; hi[6] = (__bf16)c.w;
        }
        *(bf16x8*)(xs + (r * WP + c0 + 2) * 4)     = lo;
        *(bf16x8*)(xs + (r * WP + c0 + 2) * 4 + 8) = hi;
    }
    __syncthreads();

    const int lane = tid & 63, wave = tid >> 6;
    const int quad = lane >> 4, l15 = lane & 15;
    constexpr int F = 8;

    int pbase[F];
    f32x4 acc[F];
#pragma unroll
    for (int f = 0; f < F; ++f) {
        pbase[f] = ((wave + 2) * WP + f * 16 + l15 + 2) * 8;
        acc[f] = f32x4{0.f, 0.f, 0.f, 0.f};
    }
    const char* xsb = (const char*)xs;

#pragma unroll
    for (int kt = 0; kt < 4; ++kt) {
        int k8 = kt * 4 + quad;
        int tap0 = k8 * 2, tap1 = tap0 + 1;
        int t0 = tap0 < 25 ? tap0 : 0;
        int t1 = tap1 < 25 ? tap1 : 0;
        int s0 = ((t0 / 5 - 2) * WP + (t0 % 5 - 2)) * 8;
        int s1 = ((t1 / 5 - 2) * WP + (t1 % 5 - 2)) * 8;
        bf16x8 av = *(const bf16x8*)(Wt + ((size_t)k8 * 16 + l15) * 8);
#pragma unroll
        for (int f = 0; f < F; ++f) {
            bf16x4 b0 = *(const bf16x4*)(xsb + pbase[f] + s0);
            bf16x4 b1 = *(const bf16x4*)(xsb + pbase[f] + s1);
            bf16x8 bv = __builtin_shufflevector(b0, b1, 0, 1, 2, 3, 4, 5, 6, 7);
            acc[f] = __builtin_amdgcn_mfma_f32_16x16x32_bf16(av, bv, acc[f], 0, 0, 0);
        }
    }

#pragma unroll
    for (int f = 0; f < F; ++f) {
        int pl = wave * 128 + f * 16 + l15;
#pragma unroll
        for (int r = 0; r < 4; ++r) {
            int m = quad * 4 + r;
            if (m < 8) cs[m * CSTR + pl] = acc[f][r];
        }
    }
    __syncthreads();

    {
        int oi  = tid >> 1;
        int cog = (tid & 1) * 4;
        int oy  = oi >> 6, ox = oi & 63;
        int pl0 = oy * 2 * 128 + ox * 2;
        float4 b4 = *(const float4*)(bias + cog);
        bf16x4 ov;
#pragma unroll
        for (int i = 0; i < 4; ++i) {
            int cr = cog + i;
            float v0 = cs[cr * CSTR + pl0],       v1 = cs[cr * CSTR + pl0 + 1];
            float v2 = cs[cr * CSTR + pl0 + 128], v3 = cs[cr * CSTR + pl0 + 129];
            float m = fmaxf(fmaxf(v0, v1), fmaxf(v2, v3)) + ((const float*)&b4)[i];
            ov[i] = (__bf16)fmaxf(m, 0.f);
        }
        size_t ob = ((size_t)b * 4096 + (size_t)(y0 / 2 + oy) * 64 + ox) * 8 + cog;
        *(bf16x4*)(out + ob) = ov;
    }
}

// ---------------------------------------------------------------------------
// Conv weight pre-convert: w[co][ci][kh][kw] fp32 -> wt[k/8][co][k%8] bf16,
// k = (kh*5+kw)*Ci + ci.
// ---------------------------------------------------------------------------
template<int Ci, int Co>
__global__ void wconv_k(const float* __restrict__ w, __bf16* __restrict__ wt) {
    const int n = 25 * Ci * Co;
    int t = blockIdx.x * 256 + threadIdx.x;
    if (t >= n) return;
    int j  = t & 7;
    int t2 = t >> 3;
    int co = t2 % Co;
    int k8 = t2 / Co;
    int k  = k8 * 8 + j;
    int tap = k / Ci, ci = k % Ci;
    int kh = tap / 5, kw = tap % 5;
    wt[t] = (__bf16)w[((co * Ci + ci) * 25) + kh * 5 + kw];
}

// ---------------------------------------------------------------------------
// FC weight pre-convert: fcw[o][k] fp32 (o<1024, k<2048) -> wt[k8][o][j] bf16.
// ---------------------------------------------------------------------------
__global__ void wfc_k(const float* __restrict__ w, __bf16* __restrict__ wt) {
    int t = blockIdx.x * 256 + threadIdx.x;   // n = 2,097,152
    int j  = t & 7;
    int t2 = t >> 3;
    int o  = t2 & 1023;
    int k8 = t2 >> 10;
    wt[t] = (__bf16)w[(size_t)o * 2048 + k8 * 8 + j];
}

// ---------------------------------------------------------------------------
// Attention weight pre-convert: w1[o][k] f32 (o<128, k<1024) ->
// wa[k8][o][j8] bf16 (A-frag layout, same as wfc).
// ---------------------------------------------------------------------------
__global__ void watt_k(const float* __restrict__ w, __bf16* __restrict__ wt) {
    int t = blockIdx.x * 256 + threadIdx.x;   // n = 131072
    if (t >= 131072) return;
    int j  = t & 7;
    int t2 = t >> 3;
    int o  = t2 & 127;
    int k8 = t2 >> 7;
    wt[t] = (__bf16)w[(size_t)o * 1024 + k8 * 8 + j];
}

// ---------------------------------------------------------------------------
// conv2..5 (round 3): single block per spatial tile handles ALL co-tiles:
// stage once, reuse B-frags across co-tiles.  Register pooling via shfl.
// ---------------------------------------------------------------------------
template<int Ci, int Co, int H, int RB, int IMGS, int OUTMODE>
__global__ __launch_bounds__(256) void conv2d_mfma_k(
    const __bf16* __restrict__ X, const __bf16* __restrict__ Wt,
    const float* __restrict__ bias, void* __restrict__ outp) {
    constexpr int W    = H;
    constexpr int PW   = W + 4;
    constexpr int PR   = RB + 4;
    constexpr int PIX  = RB * W;
    constexpr int P    = IMGS * PIX;
    constexpr int SE   = Ci + (Ci >= 16 ? 8 : 0);   // bank-coprime stride
    constexpr int SB   = SE * 2;                    // 16/48/80/144 B
    constexpr int K    = 25 * Ci;
    constexpr int KTF  = K / 32;
    constexpr int FW   = P / 64;                    // frags per wave
    constexpr int NCOT = Co / 16;                   // co tiles
    constexpr int C8   = Ci / 8;
    constexpr int BPI  = H / RB;
    constexpr int OW   = W / 2;

    __shared__ __align__(16) char smem[IMGS * PR * PW * SB];

    const int tid = threadIdx.x;
    const int b0  = (blockIdx.x / BPI) * IMGS;
    const int y0  = (blockIdx.x % BPI) * RB;

    constexpr int NSLOT = IMGS * PR * PW * C8;
    for (int i = tid; i < NSLOT; i += 256) {
        int s   = i % C8;
        int t2  = i / C8;
        int pc  = t2 % PW;
        int t3  = t2 / PW;
        int pr  = t3 % PR;
        int img = t3 / PR;
        int gy  = y0 + pr - 2;
        int gx  = pc - 2;
        bf16x8 v = {};
        if ((unsigned)gy < (unsigned)H && (unsigned)gx < (unsigned)W)
            v = *(const bf16x8*)(X + (((size_t)(b0 + img) * H + gy) * W + gx) * Ci + s * 8);
        *(bf16x8*)(smem + ((size_t)(img * PR + pr) * PW + pc) * SB + s * 16) = v;
    }
    __syncthreads();

    const int lane = tid & 63, wave = tid >> 6;
    const int quad = lane >> 4, l15 = lane & 15;

    int pbase[FW];
    f32x4 acc[FW][NCOT];
    int rg = 0, ch = 0, gbase = 0, img5 = 0;
    if constexpr (W >= 16) {
        constexpr int C16 = W / 16;
        ch = wave % C16;
        rg = wave / C16;
#pragma unroll
        for (int f = 0; f < FW; ++f) {
            int row = rg * FW + f;
            pbase[f] = ((row + 2) * PW + ch * 16 + l15 + 2) * SB;
        }
    } else {
        img5  = wave >> 1;
        gbase = (wave & 1) * FW;
#pragma unroll
        for (int f = 0; f < FW; ++f) {
            int g    = gbase + f;
            int row0 = 2 * g + (l15 >> 3);
            pbase[f] = ((img5 * PR + row0 + 2) * PW + (l15 & 7) + 2) * SB;
        }
    }
#pragma unroll
    for (int f = 0; f < FW; ++f)
#pragma unroll
        for (int c = 0; c < NCOT; ++c) acc[f][c] = f32x4{0.f, 0.f, 0.f, 0.f};

    const bf16x8 BZ = {};
    auto kstep = [&](int kt, bool mask) {
        int k8 = kt * 4 + quad;
        int kk = k8 * 8;
        bool kok = true;
        if (mask) { kok = kk < K; if (!kok) { k8 = 0; kk = 0; } }
        int tap = kk / Ci, cio = kk % Ci;
        int dy = tap / 5 - 2, dx = tap % 5 - 2;
        int shift = (dy * PW + dx) * SB + cio * 2;
        bf16x8 bv[FW];
#pragma unroll
        for (int f = 0; f < FW; ++f) {
            bv[f] = *(const bf16x8*)(smem + pbase[f] + shift);
            if (mask && !kok) bv[f] = BZ;
        }
#pragma unroll
        for (int c = 0; c < NCOT; ++c) {
            bf16x8 av = *(const bf16x8*)(Wt + ((size_t)k8 * Co + c * 16 + l15) * 8);
#pragma unroll
            for (int f = 0; f < FW; ++f)
                acc[f][c] = __builtin_amdgcn_mfma_f32_16x16x32_bf16(av, bv[f], acc[f][c], 0, 0, 0);
        }
    };
#pragma unroll 2
    for (int kt = 0; kt < KTF; ++kt) kstep(kt, false);
    if constexpr (K % 32 != 0) kstep(KTF, true);

    if constexpr (W >= 16) {
#pragma unroll
        for (int fp = 0; fp < FW / 2; ++fp) {
            int f0  = 2 * fp;
            int row = rg * FW + f0;
            int oy  = (y0 + row) >> 1;
            int ox  = (ch * 16 + l15) >> 1;
            bool on = (l15 & 1) == 0;
#pragma unroll
            for (int c = 0; c < NCOT; ++c) {
                float4 bb = *(const float4*)(bias + c * 16 + quad * 4);
                bf16x4 ov;
#pragma unroll
                for (int r = 0; r < 4; ++r) {
                    float v0 = acc[f0][c][r];
                    float h0 = fmaxf(v0, __shfl_xor(v0, 1));
                    float v1 = acc[f0 + 1][c][r];
                    float h1 = fmaxf(v1, __shfl_xor(v1, 1));
                    float m  = fmaxf(h0, h1) + ((const float*)&bb)[r];
                    ov[r] = (__bf16)fmaxf(m, 0.f);
                }
                if (on)
                    *(bf16x4*)((__bf16*)outp +
                        (((size_t)b0 * (H / 2) + oy) * OW + ox) * Co + c * 16 + quad * 4) = ov;
            }
        }
    } else {
#pragma unroll
        for (int f = 0; f < FW; ++f) {
            int g   = gbase + f;
            bool on = ((l15 & 1) == 0) && (l15 < 8);
            int ox  = (l15 & 7) >> 1;
#pragma unroll
            for (int c = 0; c < NCOT; ++c) {
                float4 bb = *(const float4*)(bias + c * 16 + quad * 4);
#pragma unroll
                for (int r = 0; r < 4; ++r) {
                    float v  = acc[f][c][r];
                    float h  = fmaxf(v, __shfl_xor(v, 1));
                    float m2 = fmaxf(h, __shfl_xor(h, 8));
                    float m  = fmaxf(m2 + ((const float*)&bb)[r], 0.f);
                    if (on)
                        ((__bf16*)outp)[(size_t)(b0 + img5) * 2048 +
                            (c * 16 + quad * 4 + r) * 16 + g * 4 + ox] = (__bf16)m;
                }
            }
        }
    }
}

// ---------------------------------------------------------------------------
// FC via MFMA; also emits bf16 copy of emb for the attention GEMM.
// ---------------------------------------------------------------------------
__global__ __launch_bounds__(256) void fc_mfma_k(
    const __bf16* __restrict__ Xb, const __bf16* __restrict__ Wfc,
    const float* __restrict__ bias, float* __restrict__ emb,
    __bf16* __restrict__ embb) {
    const int tid  = threadIdx.x;
    const int lane = tid & 63, wave = tid >> 6;
    const int quad = lane >> 4, l15 = lane & 15;
    const int n0   = blockIdx.x * 128;
    const int co0  = blockIdx.y * 16;

    int n[2];
    f32x4 acc[2];
#pragma unroll
    for (int f = 0; f < 2; ++f) {
        n[f] = n0 + wave * 32 + f * 16 + l15;
        acc[f] = f32x4{0.f, 0.f, 0.f, 0.f};
    }

#pragma unroll 4
    for (int kt = 0; kt < 64; ++kt) {
        int k8 = kt * 4 + quad;
        bf16x8 av = *(const bf16x8*)(Wfc + ((size_t)k8 * 1024 + co0 + l15) * 8);
#pragma unroll
        for (int f = 0; f < 2; ++f) {
            bf16x8 bv = *(const bf16x8*)(Xb + (size_t)n[f] * 2048 + k8 * 8);
            acc[f] = __builtin_amdgcn_mfma_f32_16x16x32_bf16(av, bv, acc[f], 0, 0, 0);
        }
    }

    float4 b4 = *(const float4*)(bias + co0 + quad * 4);
#pragma unroll
    for (int f = 0; f < 2; ++f) {
        f32x4 v = acc[f];
        v[0] += b4.x; v[1] += b4.y; v[2] += b4.z; v[3] += b4.w;
        *(f32x4*)(emb + (size_t)n[f] * 1024 + co0 + quad * 4) = v;
        bf16x4 eb;
        eb[0] = (__bf16)v[0]; eb[1] = (__bf16)v[1];
        eb[2] = (__bf16)v[2]; eb[3] = (__bf16)v[3];
        *(bf16x4*)(embb + (size_t)n[f] * 1024 + co0 + quad * 4) = eb;
    }
}

// ---------------------------------------------------------------------------
// Attention via MFMA (round 4): 32 blocks x 16 batch cols; all 128 att rows
// per block (4 waves x 2 tiles).  A = wa (preconverted bf16), B = embb.
// C layout: col = l15 = batch, row = quad*4+r = att index.
// ---------------------------------------------------------------------------
__global__ __launch_bounds__(256) void att_mfma_k(
    const __bf16* __restrict__ embb, const __bf16* __restrict__ Wa,
    const float* __restrict__ b1, const float* __restrict__ w2,
    const float* __restrict__ b2, float* __restrict__ logits) {
    const int tid = threadIdx.x, lane = tid & 63, wave = tid >> 6;
    const int quad = lane >> 4, l15 = lane & 15;
    const int n = blockIdx.x * 16 + l15;        // batch index (32 blocks)

    f32x4 acc[2];
    acc[0] = f32x4{0.f, 0.f, 0.f, 0.f};
    acc[1] = f32x4{0.f, 0.f, 0.f, 0.f};

#pragma unroll 4
    for (int kt = 0; kt < 32; ++kt) {
        int k8 = kt * 4 + quad;
        bf16x8 bv = *(const bf16x8*)(embb + (size_t)n * 1024 + k8 * 8);
#pragma unroll
        for (int t = 0; t < 2; ++t) {
            int o0 = (wave * 2 + t) * 16;
            bf16x8 av = *(const bf16x8*)(Wa + ((size_t)k8 * 128 + o0 + l15) * 8);
            acc[t] = __builtin_amdgcn_mfma_f32_16x16x32_bf16(av, bv, acc[t], 0, 0, 0);
        }
    }

    float s = 0.f;
#pragma unroll
    for (int t = 0; t < 2; ++t) {
#pragma unroll
        for (int r = 0; r < 4; ++r) {
            int o = (wave * 2 + t) * 16 + quad * 4 + r;
            s += tanhf(acc[t][r] + b1[o]) * w2[o];
        }
    }
    s += __shfl_xor(s, 16);
    s += __shfl_xor(s, 32);

    __shared__ float part[4][16];
    if (lane < 16) part[wave][l15] = s;
    __syncthreads();
    if (tid < 16)
        logits[blockIdx.x * 16 + tid] =
            part[0][tid] + part[1][tid] + part[2][tid] + part[3][tid] + b2[0];
}

// ---------------------------------------------------------------------------
// Segment softmax + aggregation + classifier
// ---------------------------------------------------------------------------
__global__ __launch_bounds__(256) void segment_k(
    const float* __restrict__ emb, const float* __restrict__ logits,
    const int* __restrict__ cid, const float* __restrict__ clf_w,
    const float* __restrict__ clf_b, float* __restrict__ out) {
    const int c = blockIdx.x;
    const int t = threadIdx.x;
    __shared__ int cids[BATCH];
    __shared__ float red[256];
    for (int i = t; i < BATCH; i += 256) cids[i] = cid[i];
    __syncthreads();

    float lm = -1e30f;
    for (int b = t; b < BATCH; b += 256)
        if (cids[b] == c) lm = fmaxf(lm, logits[b]);
    red[t] = lm; __syncthreads();
    for (int s = 128; s > 0; s >>= 1) {
        if (t < s) red[t] = fmaxf(red[t], red[t + s]);
        __syncthreads();
    }
    float smax = red[0]; __syncthreads();

    float ls = 0.f;
    for (int b = t; b < BATCH; b += 256)
        if (cids[b] == c) ls += expf(logits[b] - smax);
    red[t] = ls; __syncthreads();
    for (int s = 128; s > 0; s >>= 1) {
        if (t < s) red[t] += red[t + s];
        __syncthreads();
    }
    float denom = red[0]; __syncthreads();
    float inv = (denom > 0.f) ? 1.f / denom : 0.f;

    const int h0 = t * 4;
    float g0 = 0.f, g1 = 0.f, g2 = 0.f, g3 = 0.f;
    for (int b = 0; b < BATCH; ++b) {
        if (cids[b] == c) {
            float wgt = expf(logits[b] - smax) * inv;
            float4 ev = *(const float4*)(emb + (size_t)b * HID + h0);
            g0 = fmaf(wgt, ev.x, g0);
            g1 = fmaf(wgt, ev.y, g1);
            g2 = fmaf(wgt, ev.z, g2);
            g3 = fmaf(wgt, ev.w, g3);
        }
    }
    float4 cw = *(const float4*)(clf_w + h0);
    float ca = g0 * cw.x + g1 * cw.y + g2 * cw.z + g3 * cw.w;
    red[t] = ca; __syncthreads();
    for (int s = 128; s > 0; s >>= 1) {
        if (t < s) red[t] += red[t + s];
        __syncthreads();
    }
    if (t == 0) out[c] = 1.f / (1.f + expf(-(red[0] + clf_b[0])));
}

// ---------------------------------------------------------------------------
extern "C" void kernel_launch(void* const* d_in, const int* in_sizes, int n_in,
                              void* d_out, int out_size, void* d_ws, size_t ws_size,
                              hipStream_t stream) {
    const float* data = (const float*)d_in[0];
    const int*   cid  = (const int*)d_in[1];
    const float* cw1 = (const float*)d_in[2],  * cb1 = (const float*)d_in[3];
    const float* cw2 = (const float*)d_in[4],  * cb2 = (const float*)d_in[5];
    const float* cw3 = (const float*)d_in[6],  * cb3 = (const float*)d_in[7];
    const float* cw4 = (const float*)d_in[8],  * cb4 = (const float*)d_in[9];
    const float* cw5 = (const float*)d_in[10], * cb5 = (const float*)d_in[11];
    const float* fcw = (const float*)d_in[12], * fcb = (const float*)d_in[13];
    const float* aw1 = (const float*)d_in[14], * ab1 = (const float*)d_in[15];
    const float* aw2 = (const float*)d_in[16], * ab2 = (const float*)d_in[17];
    const float* clw = (const float*)d_in[18], * clb = (const float*)d_in[19];
    float* out = (float*)d_out;

    // workspace (bytes), non-overlapping, ~71.9 MB
    char* wsb = (char*)d_ws;
    __bf16* x1  = (__bf16*)(wsb);              // 512*4096*8   bf16 = 33,554,432 B
    __bf16* x2  = (__bf16*)(wsb + 33554432);   // 512*1024*16  bf16 = 16,777,216 B
    __bf16* x3  = (__bf16*)(wsb + 50331648);   // 512*256*32   bf16 =  8,388,608 B
    __bf16* x4  = (__bf16*)(wsb + 58720256);   // 512*64*64    bf16 =  4,194,304 B
    __bf16* x5b = (__bf16*)(wsb + 62914560);   // 512*2048     bf16 =  2,097,152 B
    float*  emb = (float*) (wsb + 65011712);   // 512*1024     f32  =  2,097,152 B
    float*  lg  = (float*) (wsb + 67108864);   // 512 f32
    __bf16* wt2 = (__bf16*)(wsb + 67110912);   //   3,200 bf16
    __bf16* wt3 = (__bf16*)(wsb + 67117312);   //  12,800 bf16
    __bf16* wt4 = (__bf16*)(wsb + 67142912);   //  51,200 bf16
    __bf16* wt5 = (__bf16*)(wsb + 67245312);   // 204,800 bf16
    __bf16* wfc = (__bf16*)(wsb + 67654912);   // 2,097,152 bf16 = 4,194,304 B
    __bf16* wt1 = (__bf16*)(wsb + 71849216);   //   2,048 bf16
    // overlaid in x1's region, which is dead after conv2 completes:
    __bf16* wa   = (__bf16*)(wsb);             // 131,072 bf16 = 262,144 B
    __bf16* embb = (__bf16*)(wsb + 1048576);   // 512*1024 bf16 = 1,048,576 B

    wconv1_k<<<8, 256, 0, stream>>>(cw1, wt1);
    wconv_k<8,  16 ><<<(3200   + 255) / 256, 256, 0, stream>>>(cw2, wt2);
    wconv_k<16, 32 ><<<(12800  + 255) / 256, 256, 0, stream>>>(cw3, wt3);
    wconv_k<32, 64 ><<<(51200  + 255) / 256, 256, 0, stream>>>(cw4, wt4);
    wconv_k<64, 128><<<(204800 + 255) / 256, 256, 0, stream>>>(cw5, wt5);
    wfc_k<<<2097152 / 256, 256, 0, stream>>>(fcw, wfc);

    // conv1: 512 images x 32 row-blocks
    conv1_mfma_k<<<16384, 256, 0, stream>>>(data, wt1, cb1, x1);

    // conv2..5: single y-block, all co-tiles per block, register pooling
    conv2d_mfma_k<8,  16,  64, 8,  1, 0><<<4096, 256, 0, stream>>>(x1, wt2, cb2, x2);
    // x1 is dead from here on: stage attention weights into its region
    watt_k<<<512, 256, 0, stream>>>(aw1, wa);
    conv2d_mfma_k<16, 32,  32, 8,  1, 0><<<2048, 256, 0, stream>>>(x2, wt3, cb3, x3);
    conv2d_mfma_k<32, 64,  16, 16, 1, 0><<<512,  256, 0, stream>>>(x3, wt4, cb4, x4);
    conv2d_mfma_k<64, 128, 8,  8,  2, 1><<<256,  256, 0, stream>>>(x4, wt5, cb5, x5b);

    fc_mfma_k<<<dim3(4, 64), 256, 0, stream>>>(x5b, wfc, fcb, emb, embb);
    att_mfma_k<<<32, 256, 0, stream>>>(embb, wa, ab1, aw2, ab2, lg);
    segment_k<<<NSEG, 256, 0, stream>>>(emb, lg, cid, clw, clb, out);
}

// Round 6
// 426.353 us; speedup vs baseline: 1.3502x; 1.0494x over previous
//
#include <hip/hip_runtime.h>
#include <hip/hip_bf16.h>
#include <math.h>

// Problem constants
#define BATCH 512
#define NSEG  64
#define HID   1024
#define ATT   128

typedef __attribute__((ext_vector_type(8))) __bf16 bf16x8;
typedef __attribute__((ext_vector_type(4))) __bf16 bf16x4;
typedef __attribute__((ext_vector_type(4))) float  f32x4;

// ---------------------------------------------------------------------------
// Fused weight pre-convert: wt1 (conv1 special), wt2..wt5, wfc in ONE launch.
// ---------------------------------------------------------------------------
__device__ inline void wcv(const float* __restrict__ w, __bf16* __restrict__ wt,
                           int t, int Ci, int Co) {
    int j  = t & 7;
    int t2 = t >> 3;
    int co = t2 % Co;
    int k8 = t2 / Co;
    int k  = k8 * 8 + j;
    int tap = k / Ci, ci = k % Ci;
    wt[t] = (__bf16)w[(co * Ci + ci) * 25 + tap];
}

__global__ void wprep_k(const float* __restrict__ cw1, const float* __restrict__ cw2,
                        const float* __restrict__ cw3, const float* __restrict__ cw4,
                        const float* __restrict__ cw5, const float* __restrict__ fcw,
                        __bf16* __restrict__ wt1, __bf16* __restrict__ wt2,
                        __bf16* __restrict__ wt3, __bf16* __restrict__ wt4,
                        __bf16* __restrict__ wt5, __bf16* __restrict__ wfc) {
    int t = blockIdx.x * 256 + threadIdx.x;
    if (t < 2048) {                       // conv1: wt[k8][m16][j8], k = tap*4+ci
        int j = t & 7, m = (t >> 3) & 15, k8 = t >> 7;
        int k = k8 * 8 + j, tap = k >> 2, ci = k & 3;
        float v = 0.f;
        if (m < 8 && ci < 3 && tap < 25) v = cw1[(m * 3 + ci) * 25 + tap];
        wt1[t] = (__bf16)v;
        return;
    }
    t -= 2048;
    if (t < 3200)  { wcv(cw2, wt2, t, 8, 16);   return; }
    t -= 3200;
    if (t < 12800) { wcv(cw3, wt3, t, 16, 32);  return; }
    t -= 12800;
    if (t < 51200) { wcv(cw4, wt4, t, 32, 64);  return; }
    t -= 51200;
    if (t < 204800){ wcv(cw5, wt5, t, 64, 128); return; }
    t -= 204800;
    if (t < 2097152) {
        int j = t & 7, t2 = t >> 3, o = t2 & 1023, k8 = t2 >> 10;
        wfc[t] = (__bf16)fcw[(size_t)o * 2048 + k8 * 8 + j];
    }
}

// ---------------------------------------------------------------------------
// Attention weight pre-convert: w1[o][k] f32 (o<128, k<1024) ->
// wa[k8][o][j8] bf16 (A-frag layout).  Separate launch: wa overlays x1's
// region, which is only dead after conv2 has consumed x1.
// ---------------------------------------------------------------------------
__global__ void watt_k(const float* __restrict__ w, __bf16* __restrict__ wt) {
    int t = blockIdx.x * 256 + threadIdx.x;   // n = 131072
    if (t >= 131072) return;
    int j  = t & 7;
    int t2 = t >> 3;
    int o  = t2 & 127;
    int k8 = t2 >> 7;
    wt[t] = (__bf16)w[(size_t)o * 1024 + k8 * 8 + j];
}

// ---------------------------------------------------------------------------
// conv1 via MFMA, 2D tile + zero-padded halo.  Round 6: register pooling
// (no cs LDS round-trip).  Wave w owns rows 2*(w>>1)..+1, cols (w&1)*64..+63;
// frag f: row +(f>>2), col (f&3)*16+l15.  Vertical pool partner = f vs f+4
// (same lane), horizontal = l15^1.  LDS 8448 B only.
// ---------------------------------------------------------------------------
__global__ __launch_bounds__(256) void conv1_mfma_k(
    const float* __restrict__ in, const __bf16* __restrict__ Wt,
    const float* __restrict__ bias, __bf16* __restrict__ out) {
    constexpr int W  = 128;
    constexpr int R  = 4;
    constexpr int RP = R + 4;
    constexpr int WP = W + 4;

    __shared__ __align__(16) __bf16 xs[RP * WP * 4];   // 8448 B

    const int tid = threadIdx.x;
    const int b   = blockIdx.x >> 5;
    const int y0  = (blockIdx.x & 31) * R;
    const float* inb = in + (size_t)b * 3 * 16384;

    if (tid < RP * 4) {
        int r = tid >> 2, s = tid & 3;
        int c = (s < 2) ? s : (128 + s);        // 0,1,130,131
        *(bf16x4*)(xs + (r * WP + c) * 4) = (bf16x4){};
    }
    {
        int r  = tid >> 5;
        int g  = tid & 31;
        int gy = y0 + r - 2;
        int c0 = g * 4;
        bf16x8 lo = {}, hi = {};
        if ((unsigned)gy < 128u) {
            const float* p = inb + (size_t)gy * 128 + c0;
            float4 a = *(const float4*)(p);
            float4 q = *(const float4*)(p + 16384);
            float4 c = *(const float4*)(p + 32768);
            lo[0] = (__bf16)a.x; lo[1] = (__bf16)q.x; lo[2] = (__bf16)c.x;
            lo[4] = (__bf16)a.y; lo[5] = (__bf16)q.y; lo[6] = (__bf16)c.y;
            hi[0] = (__bf16)a.z; hi[1] = (__bf16)q.z; hi[2] = (__bf16)c.z;
            hi[4] = (__bf16)a.w; hi[5] = (__bf16)q.w; hi[6] = (__bf16)c.w;
        }
        *(bf16x8*)(xs + (r * WP + c0 + 2) * 4)     = lo;
        *(bf16x8*)(xs + (r * WP + c0 + 2) * 4 + 8) = hi;
    }
    __syncthreads();

    const int lane = tid & 63, wave = tid >> 6;
    const int quad = lane >> 4, l15 = lane & 15;
    constexpr int F = 8;

    int pbase[F];
    f32x4 acc[F];
#pragma unroll
    for (int f = 0; f < F; ++f) {
        int row = 2 * (wave >> 1) + (f >> 2);
        int col = (wave & 1) * 64 + (f & 3) * 16 + l15;
        pbase[f] = ((row + 2) * WP + col + 2) * 8;
        acc[f] = f32x4{0.f, 0.f, 0.f, 0.f};
    }
    const char* xsb = (const char*)xs;

#pragma unroll
    for (int kt = 0; kt < 4; ++kt) {
        int k8 = kt * 4 + quad;
        int tap0 = k8 * 2, tap1 = tap0 + 1;
        int t0 = tap0 < 25 ? tap0 : 0;
        int t1 = tap1 < 25 ? tap1 : 0;
        int s0 = ((t0 / 5 - 2) * WP + (t0 % 5 - 2)) * 8;
        int s1 = ((t1 / 5 - 2) * WP + (t1 % 5 - 2)) * 8;
        bf16x8 av = *(const bf16x8*)(Wt + ((size_t)k8 * 16 + l15) * 8);
#pragma unroll
        for (int f = 0; f < F; ++f) {
            bf16x4 b0 = *(const bf16x4*)(xsb + pbase[f] + s0);
            bf16x4 b1 = *(const bf16x4*)(xsb + pbase[f] + s1);
            bf16x8 bv = __builtin_shufflevector(b0, b1, 0, 1, 2, 3, 4, 5, 6, 7);
            acc[f] = __builtin_amdgcn_mfma_f32_16x16x32_bf16(av, bv, acc[f], 0, 0, 0);
        }
    }

    // ---- pool 2x2 + bias + relu in registers ----
    {
        int cog  = (quad & 1) * 4;                  // quads 2,3 are zero-pad co
        bool on  = ((l15 & 1) == 0) && (quad < 2);
        int oy   = (y0 >> 1) + (wave >> 1);
        float4 b4 = *(const float4*)(bias + cog);
#pragma unroll
        for (int f = 0; f < 4; ++f) {
            int ox = (wave & 1) * 32 + f * 8 + (l15 >> 1);
            bf16x4 ov;
#pragma unroll
            for (int r = 0; r < 4; ++r) {
                float v0 = acc[f][r], v1 = acc[f + 4][r];
                float h = fmaxf(fmaxf(v0, __shfl_xor(v0, 1)),
                                fmaxf(v1, __shfl_xor(v1, 1)));
                ov[r] = (__bf16)fmaxf(h + ((const float*)&b4)[r], 0.f);
            }
            if (on)
                *(bf16x4*)(out + ((size_t)b * 4096 + oy * 64 + ox) * 8 + cog) = ov;
        }
    }
}

// ---------------------------------------------------------------------------
// conv2..5: stage once, all (or CS-split) co-tiles per block, register pooling.
// CS = co-split factor via blockIdx.y (occupancy lever for small grids).
// ---------------------------------------------------------------------------
template<int Ci, int Co, int H, int RB, int IMGS, int OUTMODE, int CS>
__global__ __launch_bounds__(256) void conv2d_mfma_k(
    const __bf16* __restrict__ X, const __bf16* __restrict__ Wt,
    const float* __restrict__ bias, void* __restrict__ outp) {
    constexpr int W    = H;
    constexpr int PW   = W + 4;
    constexpr int PR   = RB + 4;
    constexpr int PIX  = RB * W;
    constexpr int P    = IMGS * PIX;
    constexpr int SE   = Ci + (Ci >= 16 ? 8 : 0);   // bank-coprime stride
    constexpr int SB   = SE * 2;                    // 16/48/80/144 B
    constexpr int K    = 25 * Ci;
    constexpr int KTF  = K / 32;
    constexpr int FW   = P / 64;                    // frags per wave
    constexpr int NCOT = Co / 16 / CS;              // co tiles this block
    constexpr int C8   = Ci / 8;
    constexpr int BPI  = H / RB;
    constexpr int OW   = W / 2;

    __shared__ __align__(16) char smem[IMGS * PR * PW * SB];

    const int tid = threadIdx.x;
    const int b0  = (blockIdx.x / BPI) * IMGS;
    const int y0  = (blockIdx.x % BPI) * RB;
    const int co0 = blockIdx.y * (NCOT * 16);

    constexpr int NSLOT = IMGS * PR * PW * C8;
    for (int i = tid; i < NSLOT; i += 256) {
        int s   = i % C8;
        int t2  = i / C8;
        int pc  = t2 % PW;
        int t3  = t2 / PW;
        int pr  = t3 % PR;
        int img = t3 / PR;
        int gy  = y0 + pr - 2;
        int gx  = pc - 2;
        bf16x8 v = {};
        if ((unsigned)gy < (unsigned)H && (unsigned)gx < (unsigned)W)
            v = *(const bf16x8*)(X + (((size_t)(b0 + img) * H + gy) * W + gx) * Ci + s * 8);
        *(bf16x8*)(smem + ((size_t)(img * PR + pr) * PW + pc) * SB + s * 16) = v;
    }
    __syncthreads();

    const int lane = tid & 63, wave = tid >> 6;
    const int quad = lane >> 4, l15 = lane & 15;

    int pbase[FW];
    f32x4 acc[FW][NCOT];
    int rg = 0, ch = 0, gbase = 0, img5 = 0;
    if constexpr (W >= 16) {
        constexpr int C16 = W / 16;
        ch = wave % C16;
        rg = wave / C16;
#pragma unroll
        for (int f = 0; f < FW; ++f) {
            int row = rg * FW + f;
            pbase[f] = ((row + 2) * PW + ch * 16 + l15 + 2) * SB;
        }
    } else {
        img5  = wave >> 1;
        gbase = (wave & 1) * FW;
#pragma unroll
        for (int f = 0; f < FW; ++f) {
            int g    = gbase + f;
            int row0 = 2 * g + (l15 >> 3);
            pbase[f] = ((img5 * PR + row0 + 2) * PW + (l15 & 7) + 2) * SB;
        }
    }
#pragma unroll
    for (int f = 0; f < FW; ++f)
#pragma unroll
        for (int c = 0; c < NCOT; ++c) acc[f][c] = f32x4{0.f, 0.f, 0.f, 0.f};

    const bf16x8 BZ = {};
    auto kstep = [&](int kt, bool mask) {
        int k8 = kt * 4 + quad;
        int kk = k8 * 8;
        bool kok = true;
        if (mask) { kok = kk < K; if (!kok) { k8 = 0; kk = 0; } }
        int tap = kk / Ci, cio = kk % Ci;
        int dy = tap / 5 - 2, dx = tap % 5 - 2;
        int shift = (dy * PW + dx) * SB + cio * 2;
        bf16x8 bv[FW];
#pragma unroll
        for (int f = 0; f < FW; ++f) {
            bv[f] = *(const bf16x8*)(smem + pbase[f] + shift);
            if (mask && !kok) bv[f] = BZ;
        }
#pragma unroll
        for (int c = 0; c < NCOT; ++c) {
            bf16x8 av = *(const bf16x8*)(Wt + ((size_t)k8 * Co + co0 + c * 16 + l15) * 8);
#pragma unroll
            for (int f = 0; f < FW; ++f)
                acc[f][c] = __builtin_amdgcn_mfma_f32_16x16x32_bf16(av, bv[f], acc[f][c], 0, 0, 0);
        }
    };
#pragma unroll 2
    for (int kt = 0; kt < KTF; ++kt) kstep(kt, false);
    if constexpr (K % 32 != 0) kstep(KTF, true);

    if constexpr (W >= 16) {
#pragma unroll
        for (int fp = 0; fp < FW / 2; ++fp) {
            int f0  = 2 * fp;
            int row = rg * FW + f0;
            int oy  = (y0 + row) >> 1;
            int ox  = (ch * 16 + l15) >> 1;
            bool on = (l15 & 1) == 0;
#pragma unroll
            for (int c = 0; c < NCOT; ++c) {
                float4 bb = *(const float4*)(bias + co0 + c * 16 + quad * 4);
                bf16x4 ov;
#pragma unroll
                for (int r = 0; r < 4; ++r) {
                    float v0 = acc[f0][c][r];
                    float h0 = fmaxf(v0, __shfl_xor(v0, 1));
                    float v1 = acc[f0 + 1][c][r];
                    float h1 = fmaxf(v1, __shfl_xor(v1, 1));
                    float m  = fmaxf(h0, h1) + ((const float*)&bb)[r];
                    ov[r] = (__bf16)fmaxf(m, 0.f);
                }
                if (on)
                    *(bf16x4*)((__bf16*)outp +
                        (((size_t)b0 * (H / 2) + oy) * OW + ox) * Co + co0 + c * 16 + quad * 4) = ov;
            }
        }
    } else {
#pragma unroll
        for (int f = 0; f < FW; ++f) {
            int g   = gbase + f;
            bool on = ((l15 & 1) == 0) && (l15 < 8);
            int ox  = (l15 & 7) >> 1;
#pragma unroll
            for (int c = 0; c < NCOT; ++c) {
                float4 bb = *(const float4*)(bias + co0 + c * 16 + quad * 4);
#pragma unroll
                for (int r = 0; r < 4; ++r) {
                    float v  = acc[f][c][r];
                    float h  = fmaxf(v, __shfl_xor(v, 1));
                    float m2 = fmaxf(h, __shfl_xor(h, 8));
                    float m  = fmaxf(m2 + ((const float*)&bb)[r], 0.f);
                    if (on)
                        ((__bf16*)outp)[(size_t)(b0 + img5) * 2048 +
                            (co0 + c * 16 + quad * 4 + r) * 16 + g * 4 + ox] = (__bf16)m;
                }
            }
        }
    }
}

// ---------------------------------------------------------------------------
// FC via MFMA; also emits bf16 copy of emb for the attention GEMM.
// ---------------------------------------------------------------------------
__global__ __launch_bounds__(256) void fc_mfma_k(
    const __bf16* __restrict__ Xb, const __bf16* __restrict__ Wfc,
    const float* __restrict__ bias, float* __restrict__ emb,
    __bf16* __restrict__ embb) {
    const int tid  = threadIdx.x;
    const int lane = tid & 63, wave = tid >> 6;
    const int quad = lane >> 4, l15 = lane & 15;
    const int n0   = blockIdx.x * 128;
    const int co0  = blockIdx.y * 16;

    int n[2];
    f32x4 acc[2];
#pragma unroll
    for (int f = 0; f < 2; ++f) {
        n[f] = n0 + wave * 32 + f * 16 + l15;
        acc[f] = f32x4{0.f, 0.f, 0.f, 0.f};
    }

#pragma unroll 4
    for (int kt = 0; kt < 64; ++kt) {
        int k8 = kt * 4 + quad;
        bf16x8 av = *(const bf16x8*)(Wfc + ((size_t)k8 * 1024 + co0 + l15) * 8);
#pragma unroll
        for (int f = 0; f < 2; ++f) {
            bf16x8 bv = *(const bf16x8*)(Xb + (size_t)n[f] * 2048 + k8 * 8);
            acc[f] = __builtin_amdgcn_mfma_f32_16x16x32_bf16(av, bv, acc[f], 0, 0, 0);
        }
    }

    float4 b4 = *(const float4*)(bias + co0 + quad * 4);
#pragma unroll
    for (int f = 0; f < 2; ++f) {
        f32x4 v = acc[f];
        v[0] += b4.x; v[1] += b4.y; v[2] += b4.z; v[3] += b4.w;
        *(f32x4*)(emb + (size_t)n[f] * 1024 + co0 + quad * 4) = v;
        bf16x4 eb;
        eb[0] = (__bf16)v[0]; eb[1] = (__bf16)v[1];
        eb[2] = (__bf16)v[2]; eb[3] = (__bf16)v[3];
        *(bf16x4*)(embb + (size_t)n[f] * 1024 + co0 + quad * 4) = eb;
    }
}

// ---------------------------------------------------------------------------
// Attention via MFMA: 32 blocks x 16 batch cols; 128 att rows per block.
// ---------------------------------------------------------------------------
__global__ __launch_bounds__(256) void att_mfma_k(
    const __bf16* __restrict__ embb, const __bf16* __restrict__ Wa,
    const float* __restrict__ b1, const float* __restrict__ w2,
    const float* __restrict__ b2, float* __restrict__ logits) {
    const int tid = threadIdx.x, lane = tid & 63, wave = tid >> 6;
    const int quad = lane >> 4, l15 = lane & 15;
    const int n = blockIdx.x * 16 + l15;        // batch index (32 blocks)

    f32x4 acc[2];
    acc[0] = f32x4{0.f, 0.f, 0.f, 0.f};
    acc[1] = f32x4{0.f, 0.f, 0.f, 0.f};

#pragma unroll 4
    for (int kt = 0; kt < 32; ++kt) {
        int k8 = kt * 4 + quad;
        bf16x8 bv = *(const bf16x8*)(embb + (size_t)n * 1024 + k8 * 8);
#pragma unroll
        for (int t = 0; t < 2; ++t) {
            int o0 = (wave * 2 + t) * 16;
            bf16x8 av = *(const bf16x8*)(Wa + ((size_t)k8 * 128 + o0 + l15) * 8);
            acc[t] = __builtin_amdgcn_mfma_f32_16x16x32_bf16(av, bv, acc[t], 0, 0, 0);
        }
    }

    float s = 0.f;
#pragma unroll
    for (int t = 0; t < 2; ++t) {
#pragma unroll
        for (int r = 0; r < 4; ++r) {
            int o = (wave * 2 + t) * 16 + quad * 4 + r;
            s += tanhf(acc[t][r] + b1[o]) * w2[o];
        }
    }
    s += __shfl_xor(s, 16);
    s += __shfl_xor(s, 32);

    __shared__ float part[4][16];
    if (lane < 16) part[wave][l15] = s;
    __syncthreads();
    if (tid < 16)
        logits[blockIdx.x * 16 + tid] =
            part[0][tid] + part[1][tid] + part[2][tid] + part[3][tid] + b2[0];
}

// ---------------------------------------------------------------------------
// Segment softmax + aggregation + classifier
// ---------------------------------------------------------------------------
__global__ __launch_bounds__(256) void segment_k(
    const float* __restrict__ emb, const float* __restrict__ logits,
    const int* __restrict__ cid, const float* __restrict__ clf_w,
    const float* __restrict__ clf_b, float* __restrict__ out) {
    const int c = blockIdx.x;
    const int t = threadIdx.x;
    __shared__ int cids[BATCH];
    __shared__ float red[256];
    for (int i = t; i < BATCH; i += 256) cids[i] = cid[i];
    __syncthreads();

    float lm = -1e30f;
    for (int b = t; b < BATCH; b += 256)
        if (cids[b] == c) lm = fmaxf(lm, logits[b]);
    red[t] = lm; __syncthreads();
    for (int s = 128; s > 0; s >>= 1) {
        if (t < s) red[t] = fmaxf(red[t], red[t + s]);
        __syncthreads();
    }
    float smax = red[0]; __syncthreads();

    float ls = 0.f;
    for (int b = t; b < BATCH; b += 256)
        if (cids[b] == c) ls += expf(logits[b] - smax);
    red[t] = ls; __syncthreads();
    for (int s = 128; s > 0; s >>= 1) {
        if (t < s) red[t] += red[t + s];
        __syncthreads();
    }
    float denom = red[0]; __syncthreads();
    float inv = (denom > 0.f) ? 1.f / denom : 0.f;

    const int h0 = t * 4;
    float g0 = 0.f, g1 = 0.f, g2 = 0.f, g3 = 0.f;
    for (int b = 0; b < BATCH; ++b) {
        if (cids[b] == c) {
            float wgt = expf(logits[b] - smax) * inv;
            float4 ev = *(const float4*)(emb + (size_t)b * HID + h0);
            g0 = fmaf(wgt, ev.x, g0);
            g1 = fmaf(wgt, ev.y, g1);
            g2 = fmaf(wgt, ev.z, g2);
            g3 = fmaf(wgt, ev.w, g3);
        }
    }
    float4 cw = *(const float4*)(clf_w + h0);
    float ca = g0 * cw.x + g1 * cw.y + g2 * cw.z + g3 * cw.w;
    red[t] = ca; __syncthreads();
    for (int s = 128; s > 0; s >>= 1) {
        if (t < s) red[t] += red[t + s];
        __syncthreads();
    }
    if (t == 0) out[c] = 1.f / (1.f + expf(-(red[0] + clf_b[0])));
}

// ---------------------------------------------------------------------------
extern "C" void kernel_launch(void* const* d_in, const int* in_sizes, int n_in,
                              void* d_out, int out_size, void* d_ws, size_t ws_size,
                              hipStream_t stream) {
    const float* data = (const float*)d_in[0];
    const int*   cid  = (const int*)d_in[1];
    const float* cw1 = (const float*)d_in[2],  * cb1 = (const float*)d_in[3];
    const float* cw2 = (const float*)d_in[4],  * cb2 = (const float*)d_in[5];
    const float* cw3 = (const float*)d_in[6],  * cb3 = (const float*)d_in[7];
    const float* cw4 = (const float*)d_in[8],  * cb4 = (const float*)d_in[9];
    const float* cw5 = (const float*)d_in[10], * cb5 = (const float*)d_in[11];
    const float* fcw = (const float*)d_in[12], * fcb = (const float*)d_in[13];
    const float* aw1 = (const float*)d_in[14], * ab1 = (const float*)d_in[15];
    const float* aw2 = (const float*)d_in[16], * ab2 = (const float*)d_in[17];
    const float* clw = (const float*)d_in[18], * clb = (const float*)d_in[19];
    float* out = (float*)d_out;

    // workspace (bytes), non-overlapping, ~71.9 MB
    char* wsb = (char*)d_ws;
    __bf16* x1  = (__bf16*)(wsb);              // 512*4096*8   bf16 = 33,554,432 B
    __bf16* x2  = (__bf16*)(wsb + 33554432);   // 512*1024*16  bf16 = 16,777,216 B
    __bf16* x3  = (__bf16*)(wsb + 50331648);   // 512*256*32   bf16 =  8,388,608 B
    __bf16* x4  = (__bf16*)(wsb + 58720256);   // 512*64*64    bf16 =  4,194,304 B
    __bf16* x5b = (__bf16*)(wsb + 62914560);   // 512*2048     bf16 =  2,097,152 B
    float*  emb = (float*) (wsb + 65011712);   // 512*1024     f32  =  2,097,152 B
    float*  lg  = (float*) (wsb + 67108864);   // 512 f32
    __bf16* wt2 = (__bf16*)(wsb + 67110912);   //   3,200 bf16
    __bf16* wt3 = (__bf16*)(wsb + 67117312);   //  12,800 bf16
    __bf16* wt4 = (__bf16*)(wsb + 67142912);   //  51,200 bf16
    __bf16* wt5 = (__bf16*)(wsb + 67245312);   // 204,800 bf16
    __bf16* wfc = (__bf16*)(wsb + 67654912);   // 2,097,152 bf16 = 4,194,304 B
    __bf16* wt1 = (__bf16*)(wsb + 71849216);   //   2,048 bf16
    // overlaid in x1's region, which is dead after conv2 completes:
    __bf16* wa   = (__bf16*)(wsb);             // 131,072 bf16 = 262,144 B
    __bf16* embb = (__bf16*)(wsb + 1048576);   // 512*1024 bf16 = 1,048,576 B

    // fused weight preconvert (one launch): 2,371,200 elems
    wprep_k<<<9263, 256, 0, stream>>>(cw1, cw2, cw3, cw4, cw5, fcw,
                                      wt1, wt2, wt3, wt4, wt5, wfc);

    // conv1: 512 images x 32 row-blocks
    conv1_mfma_k<<<16384, 256, 0, stream>>>(data, wt1, cb1, x1);

    // conv2..5
    conv2d_mfma_k<8,  16,  64, 8, 1, 0, 1><<<4096, 256, 0, stream>>>(x1, wt2, cb2, x2);
    // x1 is dead from here on: stage attention weights into its region
    watt_k<<<512, 256, 0, stream>>>(aw1, wa);
    conv2d_mfma_k<16, 32,  32, 8, 1, 0, 1><<<2048, 256, 0, stream>>>(x2, wt3, cb3, x3);
    conv2d_mfma_k<32, 64,  16, 8, 1, 0, 1><<<1024, 256, 0, stream>>>(x3, wt4, cb4, x4);
    conv2d_mfma_k<64, 128, 8,  8, 2, 1, 2><<<dim3(256, 2), 256, 0, stream>>>(x4, wt5, cb5, x5b);

    fc_mfma_k<<<dim3(4, 64), 256, 0, stream>>>(x5b, wfc, fcb, emb, embb);
    att_mfma_k<<<32, 256, 0, stream>>>(embb, wa, ab1, aw2, ab2, lg);
    segment_k<<<NSEG, 256, 0, stream>>>(emb, lg, cid, clw, clb, out);
}

// Round 7
// 411.215 us; speedup vs baseline: 1.3999x; 1.0368x over previous
//
#include <hip/hip_runtime.h>
#include <hip/hip_bf16.h>
#include <math.h>

// Problem constants
#define BATCH 512
#define NSEG  64
#define HID   1024
#define ATT   128

typedef __attribute__((ext_vector_type(8))) __bf16 bf16x8;
typedef __attribute__((ext_vector_type(4))) __bf16 bf16x4;
typedef __attribute__((ext_vector_type(4))) float  f32x4;

// ---------------------------------------------------------------------------
// Fused weight pre-convert: wt1 (conv1 special), wt2..wt5, wfc in ONE launch.
// ---------------------------------------------------------------------------
__device__ inline void wcv(const float* __restrict__ w, __bf16* __restrict__ wt,
                           int t, int Ci, int Co) {
    int j  = t & 7;
    int t2 = t >> 3;
    int co = t2 % Co;
    int k8 = t2 / Co;
    int k  = k8 * 8 + j;
    int tap = k / Ci, ci = k % Ci;
    wt[t] = (__bf16)w[(co * Ci + ci) * 25 + tap];
}

__global__ void wprep_k(const float* __restrict__ cw1, const float* __restrict__ cw2,
                        const float* __restrict__ cw3, const float* __restrict__ cw4,
                        const float* __restrict__ cw5, const float* __restrict__ fcw,
                        __bf16* __restrict__ wt1, __bf16* __restrict__ wt2,
                        __bf16* __restrict__ wt3, __bf16* __restrict__ wt4,
                        __bf16* __restrict__ wt5, __bf16* __restrict__ wfc) {
    int t = blockIdx.x * 256 + threadIdx.x;
    if (t < 2048) {                       // conv1: wt[k8][m16][j8], k = tap*4+ci
        int j = t & 7, m = (t >> 3) & 15, k8 = t >> 7;
        int k = k8 * 8 + j, tap = k >> 2, ci = k & 3;
        float v = 0.f;
        if (m < 8 && ci < 3 && tap < 25) v = cw1[(m * 3 + ci) * 25 + tap];
        wt1[t] = (__bf16)v;
        return;
    }
    t -= 2048;
    if (t < 3200)  { wcv(cw2, wt2, t, 8, 16);   return; }
    t -= 3200;
    if (t < 12800) { wcv(cw3, wt3, t, 16, 32);  return; }
    t -= 12800;
    if (t < 51200) { wcv(cw4, wt4, t, 32, 64);  return; }
    t -= 51200;
    if (t < 204800){ wcv(cw5, wt5, t, 64, 128); return; }
    t -= 204800;
    if (t < 2097152) {
        int j = t & 7, t2 = t >> 3, o = t2 & 1023, k8 = t2 >> 10;
        wfc[t] = (__bf16)fcw[(size_t)o * 2048 + k8 * 8 + j];
    }
}

// ---------------------------------------------------------------------------
// Attention weight pre-convert: w1[o][k] f32 (o<128, k<1024) ->
// wa[k8][o][j8] bf16 (A-frag layout).  Separate launch: wa overlays x1's
// region, which is only dead after conv2 has consumed x1.
// ---------------------------------------------------------------------------
__global__ void watt_k(const float* __restrict__ w, __bf16* __restrict__ wt) {
    int t = blockIdx.x * 256 + threadIdx.x;   // n = 131072
    if (t >= 131072) return;
    int j  = t & 7;
    int t2 = t >> 3;
    int o  = t2 & 127;
    int k8 = t2 >> 7;
    wt[t] = (__bf16)w[(size_t)o * 1024 + k8 * 8 + j];
}

// ---------------------------------------------------------------------------
// conv1 via MFMA (round 7): R=8 rows/block, xs/cs UNION smem, cs-based
// pooling (dense coalesced writes — the round-6 register pool regressed
// due to 1/4-lane masked scattered stores).  Halo redundancy 1.5x.
// ---------------------------------------------------------------------------
__global__ __launch_bounds__(256) void conv1_mfma_k(
    const float* __restrict__ in, const __bf16* __restrict__ Wt,
    const float* __restrict__ bias, __bf16* __restrict__ out) {
    constexpr int W  = 128;
    constexpr int R  = 8;                   // output rows per block
    constexpr int RP = R + 4;               // 12 padded rows
    constexpr int WP = W + 4;               // 132 padded cols
    constexpr int CSTR = R * W + 4;         // 1028 f32 (stride 4 mod 32)
    constexpr int XS_B = RP * WP * 4 * 2;   // 12672 B
    constexpr int CS_B = 8 * CSTR * 4;      // 32896 B

    __shared__ __align__(16) char smem[CS_B > XS_B ? CS_B : XS_B];
    __bf16* xs = (__bf16*)smem;
    float*  cs = (float*)smem;

    const int tid = threadIdx.x;
    const int b   = blockIdx.x >> 4;            // 16 row-blocks per image
    const int y0  = (blockIdx.x & 15) * R;
    const float* inb = in + (size_t)b * 3 * 16384;

    // ---- zero left/right halo cols (-2,-1,130,131) ----
    if (tid < RP * 4) {
        int r = tid >> 2, s = tid & 3;
        int c = (s < 2) ? s : (128 + s);
        *(bf16x4*)(xs + (r * WP + c) * 4) = (bf16x4){};
    }
    // ---- stage rows y0-2 .. y0+R+1 as NHWC4 bf16 (zeros out-of-image) ----
    for (int i = tid; i < RP * 32; i += 256) {
        int r  = i >> 5;
        int g  = i & 31;
        int gy = y0 + r - 2;
        int c0 = g * 4;
        bf16x8 lo = {}, hi = {};
        if ((unsigned)gy < 128u) {
            const float* p = inb + (size_t)gy * 128 + c0;
            float4 a = *(const float4*)(p);
            float4 q = *(const float4*)(p + 16384);
            float4 c = *(const float4*)(p + 32768);
            lo[0] = (__bf16)a.x; lo[1] = (__bf16)q.x; lo[2] = (__bf16)c.x;
            lo[4] = (__bf16)a.y; lo[5] = (__bf16)q.y; lo[6] = (__bf16)c.y;
            hi[0] = (__bf16)a.z; hi[1] = (__bf16)q.z; hi[2] = (__bf16)c.z;
            hi[4] = (__bf16)a.w; hi[5] = (__bf16)q.w; hi[6] = (__bf16)c.w;
        }
        *(bf16x8*)(xs + (r * WP + c0 + 2) * 4)     = lo;
        *(bf16x8*)(xs + (r * WP + c0 + 2) * 4 + 8) = hi;
    }
    __syncthreads();

    const int lane = tid & 63, wave = tid >> 6;
    const int quad = lane >> 4, l15 = lane & 15;
    constexpr int F = 16;                        // frags per wave (2 rows x 8)

    // wave owns rows wave*2, wave*2+1; frag f: row +(f>>3), col (f&7)*16+l15
    const int cbase = (((wave * 2) + 2) * WP + l15 + 2) * 8;
    f32x4 acc[F];
#pragma unroll
    for (int f = 0; f < F; ++f) acc[f] = f32x4{0.f, 0.f, 0.f, 0.f};
    const char* xsb = (const char*)smem;

#pragma unroll
    for (int kt = 0; kt < 4; ++kt) {
        int k8 = kt * 4 + quad;
        int tap0 = k8 * 2, tap1 = tap0 + 1;
        int t0 = tap0 < 25 ? tap0 : 0;
        int t1 = tap1 < 25 ? tap1 : 0;
        int s0 = ((t0 / 5 - 2) * WP + (t0 % 5 - 2)) * 8;
        int s1 = ((t1 / 5 - 2) * WP + (t1 % 5 - 2)) * 8;
        bf16x8 av = *(const bf16x8*)(Wt + ((size_t)k8 * 16 + l15) * 8);
#pragma unroll
        for (int f = 0; f < F; ++f) {
            int pb = cbase + (f >> 3) * (WP * 8) + (f & 7) * 128;
            bf16x4 b0 = *(const bf16x4*)(xsb + pb + s0);
            bf16x4 b1 = *(const bf16x4*)(xsb + pb + s1);
            bf16x8 bv = __builtin_shufflevector(b0, b1, 0, 1, 2, 3, 4, 5, 6, 7);
            acc[f] = __builtin_amdgcn_mfma_f32_16x16x32_bf16(av, bv, acc[f], 0, 0, 0);
        }
    }

    __syncthreads();                            // xs reads done before cs write
#pragma unroll
    for (int f = 0; f < F; ++f) {
        int pl = (wave * 2 + (f >> 3)) * 128 + (f & 7) * 16 + l15;
#pragma unroll
        for (int r = 0; r < 4; ++r) {
            int m = quad * 4 + r;
            if (m < 8) cs[m * CSTR + pl] = acc[f][r];
        }
    }
    __syncthreads();

    // ---- pool 2x2 + bias + relu -> NHWC8 bf16; 256 opos x 8 co ----
#pragma unroll
    for (int it = 0; it < 2; ++it) {
        int oi  = (tid >> 1) + it * 128;        // 0..255 pooled positions
        int cog = (tid & 1) * 4;
        int oyl = oi >> 6, ox = oi & 63;
        int pl0 = oyl * 2 * 128 + ox * 2;
        float4 b4 = *(const float4*)(bias + cog);
        bf16x4 ov;
#pragma unroll
        for (int i = 0; i < 4; ++i) {
            int cr = cog + i;
            float v0 = cs[cr * CSTR + pl0],       v1 = cs[cr * CSTR + pl0 + 1];
            float v2 = cs[cr * CSTR + pl0 + 128], v3 = cs[cr * CSTR + pl0 + 129];
            float m = fmaxf(fmaxf(v0, v1), fmaxf(v2, v3)) + ((const float*)&b4)[i];
            ov[i] = (__bf16)fmaxf(m, 0.f);
        }
        size_t ob = ((size_t)b * 4096 + (size_t)((y0 >> 1) + oyl) * 64 + ox) * 8 + cog;
        *(bf16x4*)(out + ob) = ov;
    }
}

// ---------------------------------------------------------------------------
// conv2..5: stage once, all (or CS-split) co-tiles per block, register pooling.
// CS = co-split factor via blockIdx.y (occupancy lever for small grids).
// ---------------------------------------------------------------------------
template<int Ci, int Co, int H, int RB, int IMGS, int OUTMODE, int CS>
__global__ __launch_bounds__(256) void conv2d_mfma_k(
    const __bf16* __restrict__ X, const __bf16* __restrict__ Wt,
    const float* __restrict__ bias, void* __restrict__ outp) {
    constexpr int W    = H;
    constexpr int PW   = W + 4;
    constexpr int PR   = RB + 4;
    constexpr int PIX  = RB * W;
    constexpr int P    = IMGS * PIX;
    constexpr int SE   = Ci + (Ci >= 16 ? 8 : 0);   // bank-coprime stride
    constexpr int SB   = SE * 2;                    // 16/48/80/144 B
    constexpr int K    = 25 * Ci;
    constexpr int KTF  = K / 32;
    constexpr int FW   = P / 64;                    // frags per wave
    constexpr int NCOT = Co / 16 / CS;              // co tiles this block
    constexpr int C8   = Ci / 8;
    constexpr int BPI  = H / RB;
    constexpr int OW   = W / 2;

    __shared__ __align__(16) char smem[IMGS * PR * PW * SB];

    const int tid = threadIdx.x;
    const int b0  = (blockIdx.x / BPI) * IMGS;
    const int y0  = (blockIdx.x % BPI) * RB;
    const int co0 = blockIdx.y * (NCOT * 16);

    constexpr int NSLOT = IMGS * PR * PW * C8;
    for (int i = tid; i < NSLOT; i += 256) {
        int s   = i % C8;
        int t2  = i / C8;
        int pc  = t2 % PW;
        int t3  = t2 / PW;
        int pr  = t3 % PR;
        int img = t3 / PR;
        int gy  = y0 + pr - 2;
        int gx  = pc - 2;
        bf16x8 v = {};
        if ((unsigned)gy < (unsigned)H && (unsigned)gx < (unsigned)W)
            v = *(const bf16x8*)(X + (((size_t)(b0 + img) * H + gy) * W + gx) * Ci + s * 8);
        *(bf16x8*)(smem + ((size_t)(img * PR + pr) * PW + pc) * SB + s * 16) = v;
    }
    __syncthreads();

    const int lane = tid & 63, wave = tid >> 6;
    const int quad = lane >> 4, l15 = lane & 15;

    int pbase[FW];
    f32x4 acc[FW][NCOT];
    int rg = 0, ch = 0, gbase = 0, img5 = 0;
    if constexpr (W >= 16) {
        constexpr int C16 = W / 16;
        ch = wave % C16;
        rg = wave / C16;
#pragma unroll
        for (int f = 0; f < FW; ++f) {
            int row = rg * FW + f;
            pbase[f] = ((row + 2) * PW + ch * 16 + l15 + 2) * SB;
        }
    } else {
        img5  = wave >> 1;
        gbase = (wave & 1) * FW;
#pragma unroll
        for (int f = 0; f < FW; ++f) {
            int g    = gbase + f;
            int row0 = 2 * g + (l15 >> 3);
            pbase[f] = ((img5 * PR + row0 + 2) * PW + (l15 & 7) + 2) * SB;
        }
    }
#pragma unroll
    for (int f = 0; f < FW; ++f)
#pragma unroll
        for (int c = 0; c < NCOT; ++c) acc[f][c] = f32x4{0.f, 0.f, 0.f, 0.f};

    const bf16x8 BZ = {};
    auto kstep = [&](int kt, bool mask) {
        int k8 = kt * 4 + quad;
        int kk = k8 * 8;
        bool kok = true;
        if (mask) { kok = kk < K; if (!kok) { k8 = 0; kk = 0; } }
        int tap = kk / Ci, cio = kk % Ci;
        int dy = tap / 5 - 2, dx = tap % 5 - 2;
        int shift = (dy * PW + dx) * SB + cio * 2;
        bf16x8 bv[FW];
#pragma unroll
        for (int f = 0; f < FW; ++f) {
            bv[f] = *(const bf16x8*)(smem + pbase[f] + shift);
            if (mask && !kok) bv[f] = BZ;
        }
#pragma unroll
        for (int c = 0; c < NCOT; ++c) {
            bf16x8 av = *(const bf16x8*)(Wt + ((size_t)k8 * Co + co0 + c * 16 + l15) * 8);
#pragma unroll
            for (int f = 0; f < FW; ++f)
                acc[f][c] = __builtin_amdgcn_mfma_f32_16x16x32_bf16(av, bv[f], acc[f][c], 0, 0, 0);
        }
    };
#pragma unroll 2
    for (int kt = 0; kt < KTF; ++kt) kstep(kt, false);
    if constexpr (K % 32 != 0) kstep(KTF, true);

    if constexpr (W >= 16) {
#pragma unroll
        for (int fp = 0; fp < FW / 2; ++fp) {
            int f0  = 2 * fp;
            int row = rg * FW + f0;
            int oy  = (y0 + row) >> 1;
            int ox  = (ch * 16 + l15) >> 1;
            bool on = (l15 & 1) == 0;
#pragma unroll
            for (int c = 0; c < NCOT; ++c) {
                float4 bb = *(const float4*)(bias + co0 + c * 16 + quad * 4);
                bf16x4 ov;
#pragma unroll
                for (int r = 0; r < 4; ++r) {
                    float v0 = acc[f0][c][r];
                    float h0 = fmaxf(v0, __shfl_xor(v0, 1));
                    float v1 = acc[f0 + 1][c][r];
                    float h1 = fmaxf(v1, __shfl_xor(v1, 1));
                    float m  = fmaxf(h0, h1) + ((const float*)&bb)[r];
                    ov[r] = (__bf16)fmaxf(m, 0.f);
                }
                if (on)
                    *(bf16x4*)((__bf16*)outp +
                        (((size_t)b0 * (H / 2) + oy) * OW + ox) * Co + co0 + c * 16 + quad * 4) = ov;
            }
        }
    } else {
#pragma unroll
        for (int f = 0; f < FW; ++f) {
            int g   = gbase + f;
            bool on = ((l15 & 1) == 0) && (l15 < 8);
            int ox  = (l15 & 7) >> 1;
#pragma unroll
            for (int c = 0; c < NCOT; ++c) {
                float4 bb = *(const float4*)(bias + co0 + c * 16 + quad * 4);
#pragma unroll
                for (int r = 0; r < 4; ++r) {
                    float v  = acc[f][c][r];
                    float h  = fmaxf(v, __shfl_xor(v, 1));
                    float m2 = fmaxf(h, __shfl_xor(h, 8));
                    float m  = fmaxf(m2 + ((const float*)&bb)[r], 0.f);
                    if (on)
                        ((__bf16*)outp)[(size_t)(b0 + img5) * 2048 +
                            (co0 + c * 16 + quad * 4 + r) * 16 + g * 4 + ox] = (__bf16)m;
                }
            }
        }
    }
}

// ---------------------------------------------------------------------------
// FC via MFMA (round 7: 512 blocks, 64 batch x 16 co each; was 256 blocks).
// Also emits bf16 copy of emb for the attention GEMM.
// ---------------------------------------------------------------------------
__global__ __launch_bounds__(256) void fc_mfma_k(
    const __bf16* __restrict__ Xb, const __bf16* __restrict__ Wfc,
    const float* __restrict__ bias, float* __restrict__ emb,
    __bf16* __restrict__ embb) {
    const int tid  = threadIdx.x;
    const int lane = tid & 63, wave = tid >> 6;
    const int quad = lane >> 4, l15 = lane & 15;
    const int n    = blockIdx.x * 64 + wave * 16 + l15;
    const int co0  = blockIdx.y * 16;

    f32x4 acc = f32x4{0.f, 0.f, 0.f, 0.f};

#pragma unroll 8
    for (int kt = 0; kt < 64; ++kt) {
        int k8 = kt * 4 + quad;
        bf16x8 av = *(const bf16x8*)(Wfc + ((size_t)k8 * 1024 + co0 + l15) * 8);
        bf16x8 bv = *(const bf16x8*)(Xb + (size_t)n * 2048 + k8 * 8);
        acc = __builtin_amdgcn_mfma_f32_16x16x32_bf16(av, bv, acc, 0, 0, 0);
    }

    float4 b4 = *(const float4*)(bias + co0 + quad * 4);
    f32x4 v = acc;
    v[0] += b4.x; v[1] += b4.y; v[2] += b4.z; v[3] += b4.w;
    *(f32x4*)(emb + (size_t)n * 1024 + co0 + quad * 4) = v;
    bf16x4 eb;
    eb[0] = (__bf16)v[0]; eb[1] = (__bf16)v[1];
    eb[2] = (__bf16)v[2]; eb[3] = (__bf16)v[3];
    *(bf16x4*)(embb + (size_t)n * 1024 + co0 + quad * 4) = eb;
}

// ---------------------------------------------------------------------------
// Attention via MFMA: 32 blocks x 16 batch cols; 128 att rows per block.
// ---------------------------------------------------------------------------
__global__ __launch_bounds__(256) void att_mfma_k(
    const __bf16* __restrict__ embb, const __bf16* __restrict__ Wa,
    const float* __restrict__ b1, const float* __restrict__ w2,
    const float* __restrict__ b2, float* __restrict__ logits) {
    const int tid = threadIdx.x, lane = tid & 63, wave = tid >> 6;
    const int quad = lane >> 4, l15 = lane & 15;
    const int n = blockIdx.x * 16 + l15;        // batch index (32 blocks)

    f32x4 acc[2];
    acc[0] = f32x4{0.f, 0.f, 0.f, 0.f};
    acc[1] = f32x4{0.f, 0.f, 0.f, 0.f};

#pragma unroll 4
    for (int kt = 0; kt < 32; ++kt) {
        int k8 = kt * 4 + quad;
        bf16x8 bv = *(const bf16x8*)(embb + (size_t)n * 1024 + k8 * 8);
#pragma unroll
        for (int t = 0; t < 2; ++t) {
            int o0 = (wave * 2 + t) * 16;
            bf16x8 av = *(const bf16x8*)(Wa + ((size_t)k8 * 128 + o0 + l15) * 8);
            acc[t] = __builtin_amdgcn_mfma_f32_16x16x32_bf16(av, bv, acc[t], 0, 0, 0);
        }
    }

    float s = 0.f;
#pragma unroll
    for (int t = 0; t < 2; ++t) {
#pragma unroll
        for (int r = 0; r < 4; ++r) {
            int o = (wave * 2 + t) * 16 + quad * 4 + r;
            s += tanhf(acc[t][r] + b1[o]) * w2[o];
        }
    }
    s += __shfl_xor(s, 16);
    s += __shfl_xor(s, 32);

    __shared__ float part[4][16];
    if (lane < 16) part[wave][l15] = s;
    __syncthreads();
    if (tid < 16)
        logits[blockIdx.x * 16 + tid] =
            part[0][tid] + part[1][tid] + part[2][tid] + part[3][tid] + b2[0];
}

// ---------------------------------------------------------------------------
// Segment softmax + aggregation + classifier
// ---------------------------------------------------------------------------
__global__ __launch_bounds__(256) void segment_k(
    const float* __restrict__ emb, const float* __restrict__ logits,
    const int* __restrict__ cid, const float* __restrict__ clf_w,
    const float* __restrict__ clf_b, float* __restrict__ out) {
    const int c = blockIdx.x;
    const int t = threadIdx.x;
    __shared__ int cids[BATCH];
    __shared__ float red[256];
    for (int i = t; i < BATCH; i += 256) cids[i] = cid[i];
    __syncthreads();

    float lm = -1e30f;
    for (int b = t; b < BATCH; b += 256)
        if (cids[b] == c) lm = fmaxf(lm, logits[b]);
    red[t] = lm; __syncthreads();
    for (int s = 128; s > 0; s >>= 1) {
        if (t < s) red[t] = fmaxf(red[t], red[t + s]);
        __syncthreads();
    }
    float smax = red[0]; __syncthreads();

    float ls = 0.f;
    for (int b = t; b < BATCH; b += 256)
        if (cids[b] == c) ls += expf(logits[b] - smax);
    red[t] = ls; __syncthreads();
    for (int s = 128; s > 0; s >>= 1) {
        if (t < s) red[t] += red[t + s];
        __syncthreads();
    }
    float denom = red[0]; __syncthreads();
    float inv = (denom > 0.f) ? 1.f / denom : 0.f;

    const int h0 = t * 4;
    float g0 = 0.f, g1 = 0.f, g2 = 0.f, g3 = 0.f;
    for (int b = 0; b < BATCH; ++b) {
        if (cids[b] == c) {
            float wgt = expf(logits[b] - smax) * inv;
            float4 ev = *(const float4*)(emb + (size_t)b * HID + h0);
            g0 = fmaf(wgt, ev.x, g0);
            g1 = fmaf(wgt, ev.y, g1);
            g2 = fmaf(wgt, ev.z, g2);
            g3 = fmaf(wgt, ev.w, g3);
        }
    }
    float4 cw = *(const float4*)(clf_w + h0);
    float ca = g0 * cw.x + g1 * cw.y + g2 * cw.z + g3 * cw.w;
    red[t] = ca; __syncthreads();
    for (int s = 128; s > 0; s >>= 1) {
        if (t < s) red[t] += red[t + s];
        __syncthreads();
    }
    if (t == 0) out[c] = 1.f / (1.f + expf(-(red[0] + clf_b[0])));
}

// ---------------------------------------------------------------------------
extern "C" void kernel_launch(void* const* d_in, const int* in_sizes, int n_in,
                              void* d_out, int out_size, void* d_ws, size_t ws_size,
                              hipStream_t stream) {
    const float* data = (const float*)d_in[0];
    const int*   cid  = (const int*)d_in[1];
    const float* cw1 = (const float*)d_in[2],  * cb1 = (const float*)d_in[3];
    const float* cw2 = (const float*)d_in[4],  * cb2 = (const float*)d_in[5];
    const float* cw3 = (const float*)d_in[6],  * cb3 = (const float*)d_in[7];
    const float* cw4 = (const float*)d_in[8],  * cb4 = (const float*)d_in[9];
    const float* cw5 = (const float*)d_in[10], * cb5 = (const float*)d_in[11];
    const float* fcw = (const float*)d_in[12], * fcb = (const float*)d_in[13];
    const float* aw1 = (const float*)d_in[14], * ab1 = (const float*)d_in[15];
    const float* aw2 = (const float*)d_in[16], * ab2 = (const float*)d_in[17];
    const float* clw = (const float*)d_in[18], * clb = (const float*)d_in[19];
    float* out = (float*)d_out;

    // workspace (bytes), non-overlapping, ~71.9 MB
    char* wsb = (char*)d_ws;
    __bf16* x1  = (__bf16*)(wsb);              // 512*4096*8   bf16 = 33,554,432 B
    __bf16* x2  = (__bf16*)(wsb + 33554432);   // 512*1024*16  bf16 = 16,777,216 B
    __bf16* x3  = (__bf16*)(wsb + 50331648);   // 512*256*32   bf16 =  8,388,608 B
    __bf16* x4  = (__bf16*)(wsb + 58720256);   // 512*64*64    bf16 =  4,194,304 B
    __bf16* x5b = (__bf16*)(wsb + 62914560);   // 512*2048     bf16 =  2,097,152 B
    float*  emb = (float*) (wsb + 65011712);   // 512*1024     f32  =  2,097,152 B
    float*  lg  = (float*) (wsb + 67108864);   // 512 f32
    __bf16* wt2 = (__bf16*)(wsb + 67110912);   //   3,200 bf16
    __bf16* wt3 = (__bf16*)(wsb + 67117312);   //  12,800 bf16
    __bf16* wt4 = (__bf16*)(wsb + 67142912);   //  51,200 bf16
    __bf16* wt5 = (__bf16*)(wsb + 67245312);   // 204,800 bf16
    __bf16* wfc = (__bf16*)(wsb + 67654912);   // 2,097,152 bf16 = 4,194,304 B
    __bf16* wt1 = (__bf16*)(wsb + 71849216);   //   2,048 bf16
    // overlaid in x1's region, which is dead after conv2 completes:
    __bf16* wa   = (__bf16*)(wsb);             // 131,072 bf16 = 262,144 B
    __bf16* embb = (__bf16*)(wsb + 1048576);   // 512*1024 bf16 = 1,048,576 B

    // fused weight preconvert (one launch): 2,371,200 elems
    wprep_k<<<9263, 256, 0, stream>>>(cw1, cw2, cw3, cw4, cw5, fcw,
                                      wt1, wt2, wt3, wt4, wt5, wfc);

    // conv1: 512 images x 16 row-blocks (R=8)
    conv1_mfma_k<<<8192, 256, 0, stream>>>(data, wt1, cb1, x1);

    // conv2..5
    conv2d_mfma_k<8,  16,  64, 8, 1, 0, 1><<<4096, 256, 0, stream>>>(x1, wt2, cb2, x2);
    // x1 is dead from here on: stage attention weights into its region
    watt_k<<<512, 256, 0, stream>>>(aw1, wa);
    conv2d_mfma_k<16, 32,  32, 8, 1, 0, 1><<<2048, 256, 0, stream>>>(x2, wt3, cb3, x3);
    conv2d_mfma_k<32, 64,  16, 8, 1, 0, 2><<<dim3(1024, 2), 256, 0, stream>>>(x3, wt4, cb4, x4);
    conv2d_mfma_k<64, 128, 8,  8, 2, 1, 2><<<dim3(256, 2), 256, 0, stream>>>(x4, wt5, cb5, x5b);

    fc_mfma_k<<<dim3(8, 64), 256, 0, stream>>>(x5b, wfc, fcb, emb, embb);
    att_mfma_k<<<32, 256, 0, stream>>>(embb, wa, ab1, aw2, ab2, lg);
    segment_k<<<NSEG, 256, 0, stream>>>(emb, lg, cid, clw, clb, out);
}

// Round 8
// 391.377 us; speedup vs baseline: 1.4709x; 1.0507x over previous
//
#include <hip/hip_runtime.h>
#include <hip/hip_bf16.h>
#include <math.h>

// Problem constants
#define BATCH 512
#define NSEG  64
#define HID   1024
#define ATT   128

typedef __attribute__((ext_vector_type(8))) __bf16 bf16x8;
typedef __attribute__((ext_vector_type(4))) __bf16 bf16x4;
typedef __attribute__((ext_vector_type(4))) float  f32x4;

typedef __attribute__((address_space(1))) const unsigned char ga_t;
typedef __attribute__((address_space(3))) unsigned char la_t;

// ---------------------------------------------------------------------------
// Fused weight pre-convert: wt1 (conv1 special), wt2..wt5, wfc in ONE launch.
// ---------------------------------------------------------------------------
__device__ inline void wcv(const float* __restrict__ w, __bf16* __restrict__ wt,
                           int t, int Ci, int Co) {
    int j  = t & 7;
    int t2 = t >> 3;
    int co = t2 % Co;
    int k8 = t2 / Co;
    int k  = k8 * 8 + j;
    int tap = k / Ci, ci = k % Ci;
    wt[t] = (__bf16)w[(co * Ci + ci) * 25 + tap];
}

__global__ void wprep_k(const float* __restrict__ cw1, const float* __restrict__ cw2,
                        const float* __restrict__ cw3, const float* __restrict__ cw4,
                        const float* __restrict__ cw5, const float* __restrict__ fcw,
                        __bf16* __restrict__ wt1, __bf16* __restrict__ wt2,
                        __bf16* __restrict__ wt3, __bf16* __restrict__ wt4,
                        __bf16* __restrict__ wt5, __bf16* __restrict__ wfc) {
    int t = blockIdx.x * 256 + threadIdx.x;
    if (t < 2048) {                       // conv1: wt[k8][m16][j8], k = tap*4+ci
        int j = t & 7, m = (t >> 3) & 15, k8 = t >> 7;
        int k = k8 * 8 + j, tap = k >> 2, ci = k & 3;
        float v = 0.f;
        if (m < 8 && ci < 3 && tap < 25) v = cw1[(m * 3 + ci) * 25 + tap];
        wt1[t] = (__bf16)v;
        return;
    }
    t -= 2048;
    if (t < 3200)  { wcv(cw2, wt2, t, 8, 16);   return; }
    t -= 3200;
    if (t < 12800) { wcv(cw3, wt3, t, 16, 32);  return; }
    t -= 12800;
    if (t < 51200) { wcv(cw4, wt4, t, 32, 64);  return; }
    t -= 51200;
    if (t < 204800){ wcv(cw5, wt5, t, 64, 128); return; }
    t -= 204800;
    if (t < 2097152) {
        int j = t & 7, t2 = t >> 3, o = t2 & 1023, k8 = t2 >> 10;
        wfc[t] = (__bf16)fcw[(size_t)o * 2048 + k8 * 8 + j];
    }
}

// ---------------------------------------------------------------------------
// Attention weight pre-convert: w1[o][k] f32 -> wa[k8][o][j8] bf16.
// ---------------------------------------------------------------------------
__global__ void watt_k(const float* __restrict__ w, __bf16* __restrict__ wt) {
    int t = blockIdx.x * 256 + threadIdx.x;   // n = 131072
    if (t >= 131072) return;
    int j  = t & 7;
    int t2 = t >> 3;
    int o  = t2 & 127;
    int k8 = t2 >> 7;
    wt[t] = (__bf16)w[(size_t)o * 1024 + k8 * 8 + j];
}

// ---------------------------------------------------------------------------
// conv1 via MFMA, 2D tile + zero-padded halo — EXACT round-1 form (75.5 us
// measured; R=8/union and register-pool variants both regressed).
// ---------------------------------------------------------------------------
__global__ __launch_bounds__(256) void conv1_mfma_k(
    const float* __restrict__ in, const __bf16* __restrict__ Wt,
    const float* __restrict__ bias, __bf16* __restrict__ out) {
    constexpr int W  = 128;
    constexpr int R  = 4;
    constexpr int RP = R + 4;
    constexpr int WP = W + 4;
    constexpr int CSTR = R * W + 4;        // 516 f32

    __shared__ __align__(16) __bf16 xs[RP * WP * 4];   // 8448 B
    __shared__ float cs[8 * CSTR];                     // 16512 B

    const int tid = threadIdx.x;
    const int b   = blockIdx.x >> 5;
    const int y0  = (blockIdx.x & 31) * R;
    const float* inb = in + (size_t)b * 3 * 16384;

    if (tid < RP * 4) {
        int r = tid >> 2, s = tid & 3;
        int c = (s < 2) ? s : (128 + s);        // 0,1,130,131
        *(bf16x4*)(xs + (r * WP + c) * 4) = (bf16x4){};
    }
    {
        int r  = tid >> 5;
        int g  = tid & 31;
        int gy = y0 + r - 2;
        int c0 = g * 4;
        bf16x8 lo = {}, hi = {};
        if ((unsigned)gy < 128u) {
            const float* p = inb + (size_t)gy * 128 + c0;
            float4 a = *(const float4*)(p);
            float4 q = *(const float4*)(p + 16384);
            float4 c = *(const float4*)(p + 32768);
            lo[0] = (__bf16)a.x; lo[1] = (__bf16)q.x; lo[2] = (__bf16)c.x;
            lo[4] = (__bf16)a.y; lo[5] = (__bf16)q.y; lo[6] = (__bf16)c.y;
            hi[0] = (__bf16)a.z; hi[1] = (__bf16)q.z; hi[2] = (__bf16)c.z;
            hi[4] = (__bf16)a.w; hi[5] = (__bf16)q.w; hi[6] = (__bf16)c.w;
        }
        *(bf16x8*)(xs + (r * WP + c0 + 2) * 4)     = lo;
        *(bf16x8*)(xs + (r * WP + c0 + 2) * 4 + 8) = hi;
    }
    __syncthreads();

    const int lane = tid & 63, wave = tid >> 6;
    const int quad = lane >> 4, l15 = lane & 15;
    constexpr int F = 8;

    int pbase[F];
    f32x4 acc[F];
#pragma unroll
    for (int f = 0; f < F; ++f) {
        pbase[f] = ((wave + 2) * WP + f * 16 + l15 + 2) * 8;
        acc[f] = f32x4{0.f, 0.f, 0.f, 0.f};
    }
    const char* xsb = (const char*)xs;

#pragma unroll
    for (int kt = 0; kt < 4; ++kt) {
        int k8 = kt * 4 + quad;
        int tap0 = k8 * 2, tap1 = tap0 + 1;
        int t0 = tap0 < 25 ? tap0 : 0;
        int t1 = tap1 < 25 ? tap1 : 0;
        int s0 = ((t0 / 5 - 2) * WP + (t0 % 5 - 2)) * 8;
        int s1 = ((t1 / 5 - 2) * WP + (t1 % 5 - 2)) * 8;
        bf16x8 av = *(const bf16x8*)(Wt + ((size_t)k8 * 16 + l15) * 8);
#pragma unroll
        for (int f = 0; f < F; ++f) {
            bf16x4 b0 = *(const bf16x4*)(xsb + pbase[f] + s0);
            bf16x4 b1 = *(const bf16x4*)(xsb + pbase[f] + s1);
            bf16x8 bv = __builtin_shufflevector(b0, b1, 0, 1, 2, 3, 4, 5, 6, 7);
            acc[f] = __builtin_amdgcn_mfma_f32_16x16x32_bf16(av, bv, acc[f], 0, 0, 0);
        }
    }

#pragma unroll
    for (int f = 0; f < F; ++f) {
        int pl = wave * 128 + f * 16 + l15;
#pragma unroll
        for (int r = 0; r < 4; ++r) {
            int m = quad * 4 + r;
            if (m < 8) cs[m * CSTR + pl] = acc[f][r];
        }
    }
    __syncthreads();

    {
        int oi  = tid >> 1;
        int cog = (tid & 1) * 4;
        int oy  = oi >> 6, ox = oi & 63;
        int pl0 = oy * 2 * 128 + ox * 2;
        float4 b4 = *(const float4*)(bias + cog);
        bf16x4 ov;
#pragma unroll
        for (int i = 0; i < 4; ++i) {
            int cr = cog + i;
            float v0 = cs[cr * CSTR + pl0],       v1 = cs[cr * CSTR + pl0 + 1];
            float v2 = cs[cr * CSTR + pl0 + 128], v3 = cs[cr * CSTR + pl0 + 129];
            float m = fmaxf(fmaxf(v0, v1), fmaxf(v2, v3)) + ((const float*)&b4)[i];
            ov[i] = (__bf16)fmaxf(m, 0.f);
        }
        size_t ob = ((size_t)b * 4096 + (size_t)(y0 / 2 + oy) * 64 + ox) * 8 + cog;
        *(bf16x4*)(out + ob) = ov;
    }
}

// ---------------------------------------------------------------------------
// conv2..5: stage once, CS-split co-tiles per block, register pooling.
// Round 8: Ci==8 (conv2) staging goes through global_load_lds_dwordx4 —
// layout is dense (SB=16B, no pad), one image row = one wave-load.
// ---------------------------------------------------------------------------
template<int Ci, int Co, int H, int RB, int IMGS, int OUTMODE, int CS>
__global__ __launch_bounds__(256) void conv2d_mfma_k(
    const __bf16* __restrict__ X, const __bf16* __restrict__ Wt,
    const float* __restrict__ bias, void* __restrict__ outp) {
    constexpr int W    = H;
    constexpr int PW   = W + 4;
    constexpr int PR   = RB + 4;
    constexpr int PIX  = RB * W;
    constexpr int P    = IMGS * PIX;
    constexpr int SE   = Ci + (Ci >= 16 ? 8 : 0);   // bank-coprime stride
    constexpr int SB   = SE * 2;                    // 16/48/80/144 B
    constexpr int K    = 25 * Ci;
    constexpr int KTF  = K / 32;
    constexpr int FW   = P / 64;                    // frags per wave
    constexpr int NCOT = Co / 16 / CS;              // co tiles this block
    constexpr int C8   = Ci / 8;
    constexpr int BPI  = H / RB;
    constexpr int OW   = W / 2;

    __shared__ __align__(16) char smem[IMGS * PR * PW * SB];

    const int tid = threadIdx.x;
    const int b0  = (blockIdx.x / BPI) * IMGS;
    const int y0  = (blockIdx.x % BPI) * RB;
    const int co0 = blockIdx.y * (NCOT * 16);

    const int lane = tid & 63, wave = tid >> 6;

    if constexpr (Ci == 8 && IMGS == 1) {
        // async staging: one wave-load per in-image padded row
        __bf16* xs = (__bf16*)smem;
        if (tid < PR * 4) {                      // halo cols 0,1,W+2,W+3
            int r = tid >> 2, s = tid & 3;
            int c = (s < 2) ? s : (W + s);
            *(bf16x8*)(xs + (r * PW + c) * 8) = (bf16x8){};
        }
        for (int pr = wave; pr < PR; pr += 4) {
            int gy = y0 + pr - 2;
            if ((unsigned)gy < (unsigned)H) {
                const __bf16* gsrc = X + ((size_t)(b0 * H + gy) * W + lane) * 8;
                __bf16* ldst = xs + (pr * PW + 2) * 8;     // + lane*16B by HW
                __builtin_amdgcn_global_load_lds((ga_t*)gsrc, (la_t*)ldst, 16, 0, 0);
            } else {
                *(bf16x8*)(xs + (pr * PW + 2 + lane) * 8) = (bf16x8){};
            }
        }
    } else {
        constexpr int NSLOT = IMGS * PR * PW * C8;
        for (int i = tid; i < NSLOT; i += 256) {
            int s   = i % C8;
            int t2  = i / C8;
            int pc  = t2 % PW;
            int t3  = t2 / PW;
            int pr  = t3 % PR;
            int img = t3 / PR;
            int gy  = y0 + pr - 2;
            int gx  = pc - 2;
            bf16x8 v = {};
            if ((unsigned)gy < (unsigned)H && (unsigned)gx < (unsigned)W)
                v = *(const bf16x8*)(X + (((size_t)(b0 + img) * H + gy) * W + gx) * Ci + s * 8);
            *(bf16x8*)(smem + ((size_t)(img * PR + pr) * PW + pc) * SB + s * 16) = v;
        }
    }
    __syncthreads();

    const int quad = lane >> 4, l15 = lane & 15;

    int pbase[FW];
    f32x4 acc[FW][NCOT];
    int rg = 0, ch = 0, gbase = 0, img5 = 0;
    if constexpr (W >= 16) {
        constexpr int C16 = W / 16;
        ch = wave % C16;
        rg = wave / C16;
#pragma unroll
        for (int f = 0; f < FW; ++f) {
            int row = rg * FW + f;
            pbase[f] = ((row + 2) * PW + ch * 16 + l15 + 2) * SB;
        }
    } else {
        img5  = wave >> 1;
        gbase = (wave & 1) * FW;
#pragma unroll
        for (int f = 0; f < FW; ++f) {
            int g    = gbase + f;
            int row0 = 2 * g + (l15 >> 3);
            pbase[f] = ((img5 * PR + row0 + 2) * PW + (l15 & 7) + 2) * SB;
        }
    }
#pragma unroll
    for (int f = 0; f < FW; ++f)
#pragma unroll
        for (int c = 0; c < NCOT; ++c) acc[f][c] = f32x4{0.f, 0.f, 0.f, 0.f};

    const bf16x8 BZ = {};
    auto kstep = [&](int kt, bool mask) {
        int k8 = kt * 4 + quad;
        int kk = k8 * 8;
        bool kok = true;
        if (mask) { kok = kk < K; if (!kok) { k8 = 0; kk = 0; } }
        int tap = kk / Ci, cio = kk % Ci;
        int dy = tap / 5 - 2, dx = tap % 5 - 2;
        int shift = (dy * PW + dx) * SB + cio * 2;
        bf16x8 bv[FW];
#pragma unroll
        for (int f = 0; f < FW; ++f) {
            bv[f] = *(const bf16x8*)(smem + pbase[f] + shift);
            if (mask && !kok) bv[f] = BZ;
        }
#pragma unroll
        for (int c = 0; c < NCOT; ++c) {
            bf16x8 av = *(const bf16x8*)(Wt + ((size_t)k8 * Co + co0 + c * 16 + l15) * 8);
#pragma unroll
            for (int f = 0; f < FW; ++f)
                acc[f][c] = __builtin_amdgcn_mfma_f32_16x16x32_bf16(av, bv[f], acc[f][c], 0, 0, 0);
        }
    };
#pragma unroll 2
    for (int kt = 0; kt < KTF; ++kt) kstep(kt, false);
    if constexpr (K % 32 != 0) kstep(KTF, true);

    if constexpr (W >= 16) {
#pragma unroll
        for (int fp = 0; fp < FW / 2; ++fp) {
            int f0  = 2 * fp;
            int row = rg * FW + f0;
            int oy  = (y0 + row) >> 1;
            int ox  = (ch * 16 + l15) >> 1;
            bool on = (l15 & 1) == 0;
#pragma unroll
            for (int c = 0; c < NCOT; ++c) {
                float4 bb = *(const float4*)(bias + co0 + c * 16 + quad * 4);
                bf16x4 ov;
#pragma unroll
                for (int r = 0; r < 4; ++r) {
                    float v0 = acc[f0][c][r];
                    float h0 = fmaxf(v0, __shfl_xor(v0, 1));
                    float v1 = acc[f0 + 1][c][r];
                    float h1 = fmaxf(v1, __shfl_xor(v1, 1));
                    float m  = fmaxf(h0, h1) + ((const float*)&bb)[r];
                    ov[r] = (__bf16)fmaxf(m, 0.f);
                }
                if (on)
                    *(bf16x4*)((__bf16*)outp +
                        (((size_t)b0 * (H / 2) + oy) * OW + ox) * Co + co0 + c * 16 + quad * 4) = ov;
            }
        }
    } else {
#pragma unroll
        for (int f = 0; f < FW; ++f) {
            int g   = gbase + f;
            bool on = ((l15 & 1) == 0) && (l15 < 8);
            int ox  = (l15 & 7) >> 1;
#pragma unroll
            for (int c = 0; c < NCOT; ++c) {
                float4 bb = *(const float4*)(bias + co0 + c * 16 + quad * 4);
#pragma unroll
                for (int r = 0; r < 4; ++r) {
                    float v  = acc[f][c][r];
                    float h  = fmaxf(v, __shfl_xor(v, 1));
                    float m2 = fmaxf(h, __shfl_xor(h, 8));
                    float m  = fmaxf(m2 + ((const float*)&bb)[r], 0.f);
                    if (on)
                        ((__bf16*)outp)[(size_t)(b0 + img5) * 2048 +
                            (co0 + c * 16 + quad * 4 + r) * 16 + g * 4 + ox] = (__bf16)m;
                }
            }
        }
    }
}

// ---------------------------------------------------------------------------
// FC via MFMA (512 blocks, 64 batch x 16 co each); emits f32 + bf16 emb.
// ---------------------------------------------------------------------------
__global__ __launch_bounds__(256) void fc_mfma_k(
    const __bf16* __restrict__ Xb, const __bf16* __restrict__ Wfc,
    const float* __restrict__ bias, float* __restrict__ emb,
    __bf16* __restrict__ embb) {
    const int tid  = threadIdx.x;
    const int lane = tid & 63, wave = tid >> 6;
    const int quad = lane >> 4, l15 = lane & 15;
    const int n    = blockIdx.x * 64 + wave * 16 + l15;
    const int co0  = blockIdx.y * 16;

    f32x4 acc = f32x4{0.f, 0.f, 0.f, 0.f};

#pragma unroll 8
    for (int kt = 0; kt < 64; ++kt) {
        int k8 = kt * 4 + quad;
        bf16x8 av = *(const bf16x8*)(Wfc + ((size_t)k8 * 1024 + co0 + l15) * 8);
        bf16x8 bv = *(const bf16x8*)(Xb + (size_t)n * 2048 + k8 * 8);
        acc = __builtin_amdgcn_mfma_f32_16x16x32_bf16(av, bv, acc, 0, 0, 0);
    }

    float4 b4 = *(const float4*)(bias + co0 + quad * 4);
    f32x4 v = acc;
    v[0] += b4.x; v[1] += b4.y; v[2] += b4.z; v[3] += b4.w;
    *(f32x4*)(emb + (size_t)n * 1024 + co0 + quad * 4) = v;
    bf16x4 eb;
    eb[0] = (__bf16)v[0]; eb[1] = (__bf16)v[1];
    eb[2] = (__bf16)v[2]; eb[3] = (__bf16)v[3];
    *(bf16x4*)(embb + (size_t)n * 1024 + co0 + quad * 4) = eb;
}

// ---------------------------------------------------------------------------
// Attention via MFMA: 32 blocks x 16 batch cols; 128 att rows per block.
// ---------------------------------------------------------------------------
__global__ __launch_bounds__(256) void att_mfma_k(
    const __bf16* __restrict__ embb, const __bf16* __restrict__ Wa,
    const float* __restrict__ b1, const float* __restrict__ w2,
    const float* __restrict__ b2, float* __restrict__ logits) {
    const int tid = threadIdx.x, lane = tid & 63, wave = tid >> 6;
    const int quad = lane >> 4, l15 = lane & 15;
    const int n = blockIdx.x * 16 + l15;        // batch index (32 blocks)

    f32x4 acc[2];
    acc[0] = f32x4{0.f, 0.f, 0.f, 0.f};
    acc[1] = f32x4{0.f, 0.f, 0.f, 0.f};

#pragma unroll 4
    for (int kt = 0; kt < 32; ++kt) {
        int k8 = kt * 4 + quad;
        bf16x8 bv = *(const bf16x8*)(embb + (size_t)n * 1024 + k8 * 8);
#pragma unroll
        for (int t = 0; t < 2; ++t) {
            int o0 = (wave * 2 + t) * 16;
            bf16x8 av = *(const bf16x8*)(Wa + ((size_t)k8 * 128 + o0 + l15) * 8);
            acc[t] = __builtin_amdgcn_mfma_f32_16x16x32_bf16(av, bv, acc[t], 0, 0, 0);
        }
    }

    float s = 0.f;
#pragma unroll
    for (int t = 0; t < 2; ++t) {
#pragma unroll
        for (int r = 0; r < 4; ++r) {
            int o = (wave * 2 + t) * 16 + quad * 4 + r;
            s += tanhf(acc[t][r] + b1[o]) * w2[o];
        }
    }
    s += __shfl_xor(s, 16);
    s += __shfl_xor(s, 32);

    __shared__ float part[4][16];
    if (lane < 16) part[wave][l15] = s;
    __syncthreads();
    if (tid < 16)
        logits[blockIdx.x * 16 + tid] =
            part[0][tid] + part[1][tid] + part[2][tid] + part[3][tid] + b2[0];
}

// ---------------------------------------------------------------------------
// Segment softmax + aggregation + classifier
// ---------------------------------------------------------------------------
__global__ __launch_bounds__(256) void segment_k(
    const float* __restrict__ emb, const float* __restrict__ logits,
    const int* __restrict__ cid, const float* __restrict__ clf_w,
    const float* __restrict__ clf_b, float* __restrict__ out) {
    const int c = blockIdx.x;
    const int t = threadIdx.x;
    __shared__ int cids[BATCH];
    __shared__ float red[256];
    for (int i = t; i < BATCH; i += 256) cids[i] = cid[i];
    __syncthreads();

    float lm = -1e30f;
    for (int b = t; b < BATCH; b += 256)
        if (cids[b] == c) lm = fmaxf(lm, logits[b]);
    red[t] = lm; __syncthreads();
    for (int s = 128; s > 0; s >>= 1) {
        if (t < s) red[t] = fmaxf(red[t], red[t + s]);
        __syncthreads();
    }
    float smax = red[0]; __syncthreads();

    float ls = 0.f;
    for (int b = t; b < BATCH; b += 256)
        if (cids[b] == c) ls += expf(logits[b] - smax);
    red[t] = ls; __syncthreads();
    for (int s = 128; s > 0; s >>= 1) {
        if (t < s) red[t] += red[t + s];
        __syncthreads();
    }
    float denom = red[0]; __syncthreads();
    float inv = (denom > 0.f) ? 1.f / denom : 0.f;

    const int h0 = t * 4;
    float g0 = 0.f, g1 = 0.f, g2 = 0.f, g3 = 0.f;
    for (int b = 0; b < BATCH; ++b) {
        if (cids[b] == c) {
            float wgt = expf(logits[b] - smax) * inv;
            float4 ev = *(const float4*)(emb + (size_t)b * HID + h0);
            g0 = fmaf(wgt, ev.x, g0);
            g1 = fmaf(wgt, ev.y, g1);
            g2 = fmaf(wgt, ev.z, g2);
            g3 = fmaf(wgt, ev.w, g3);
        }
    }
    float4 cw = *(const float4*)(clf_w + h0);
    float ca = g0 * cw.x + g1 * cw.y + g2 * cw.z + g3 * cw.w;
    red[t] = ca; __syncthreads();
    for (int s = 128; s > 0; s >>= 1) {
        if (t < s) red[t] += red[t + s];
        __syncthreads();
    }
    if (t == 0) out[c] = 1.f / (1.f + expf(-(red[0] + clf_b[0])));
}

// ---------------------------------------------------------------------------
extern "C" void kernel_launch(void* const* d_in, const int* in_sizes, int n_in,
                              void* d_out, int out_size, void* d_ws, size_t ws_size,
                              hipStream_t stream) {
    const float* data = (const float*)d_in[0];
    const int*   cid  = (const int*)d_in[1];
    const float* cw1 = (const float*)d_in[2],  * cb1 = (const float*)d_in[3];
    const float* cw2 = (const float*)d_in[4],  * cb2 = (const float*)d_in[5];
    const float* cw3 = (const float*)d_in[6],  * cb3 = (const float*)d_in[7];
    const float* cw4 = (const float*)d_in[8],  * cb4 = (const float*)d_in[9];
    const float* cw5 = (const float*)d_in[10], * cb5 = (const float*)d_in[11];
    const float* fcw = (const float*)d_in[12], * fcb = (const float*)d_in[13];
    const float* aw1 = (const float*)d_in[14], * ab1 = (const float*)d_in[15];
    const float* aw2 = (const float*)d_in[16], * ab2 = (const float*)d_in[17];
    const float* clw = (const float*)d_in[18], * clb = (const float*)d_in[19];
    float* out = (float*)d_out;

    // workspace (bytes), non-overlapping, ~71.9 MB
    char* wsb = (char*)d_ws;
    __bf16* x1  = (__bf16*)(wsb);              // 512*4096*8   bf16 = 33,554,432 B
    __bf16* x2  = (__bf16*)(wsb + 33554432);   // 512*1024*16  bf16 = 16,777,216 B
    __bf16* x3  = (__bf16*)(wsb + 50331648);   // 512*256*32   bf16 =  8,388,608 B
    __bf16* x4  = (__bf16*)(wsb + 58720256);   // 512*64*64    bf16 =  4,194,304 B
    __bf16* x5b = (__bf16*)(wsb + 62914560);   // 512*2048     bf16 =  2,097,152 B
    float*  emb = (float*) (wsb + 65011712);   // 512*1024     f32  =  2,097,152 B
    float*  lg  = (float*) (wsb + 67108864);   // 512 f32
    __bf16* wt2 = (__bf16*)(wsb + 67110912);   //   3,200 bf16
    __bf16* wt3 = (__bf16*)(wsb + 67117312);   //  12,800 bf16
    __bf16* wt4 = (__bf16*)(wsb + 67142912);   //  51,200 bf16
    __bf16* wt5 = (__bf16*)(wsb + 67245312);   // 204,800 bf16
    __bf16* wfc = (__bf16*)(wsb + 67654912);   // 2,097,152 bf16 = 4,194,304 B
    __bf16* wt1 = (__bf16*)(wsb + 71849216);   //   2,048 bf16
    // overlaid in x1's region, which is dead after conv2 completes:
    __bf16* wa   = (__bf16*)(wsb);             // 131,072 bf16 = 262,144 B
    __bf16* embb = (__bf16*)(wsb + 1048576);   // 512*1024 bf16 = 1,048,576 B

    // fused weight preconvert (one launch): 2,371,200 elems
    wprep_k<<<9263, 256, 0, stream>>>(cw1, cw2, cw3, cw4, cw5, fcw,
                                      wt1, wt2, wt3, wt4, wt5, wfc);

    // conv1: 512 images x 32 row-blocks (R=4, round-1 form)
    conv1_mfma_k<<<16384, 256, 0, stream>>>(data, wt1, cb1, x1);

    // conv2..5
    conv2d_mfma_k<8,  16,  64, 8, 1, 0, 1><<<4096, 256, 0, stream>>>(x1, wt2, cb2, x2);
    // x1 is dead from here on: stage attention weights into its region
    watt_k<<<512, 256, 0, stream>>>(aw1, wa);
    conv2d_mfma_k<16, 32,  32, 8, 1, 0, 1><<<2048, 256, 0, stream>>>(x2, wt3, cb3, x3);
    conv2d_mfma_k<32, 64,  16, 8, 1, 0, 2><<<dim3(1024, 2), 256, 0, stream>>>(x3, wt4, cb4, x4);
    conv2d_mfma_k<64, 128, 8,  8, 2, 1, 2><<<dim3(256, 2), 256, 0, stream>>>(x4, wt5, cb5, x5b);

    fc_mfma_k<<<dim3(8, 64), 256, 0, stream>>>(x5b, wfc, fcb, emb, embb);
    att_mfma_k<<<32, 256, 0, stream>>>(embb, wa, ab1, aw2, ab2, lg);
    segment_k<<<NSEG, 256, 0, stream>>>(emb, lg, cid, clw, clb, out);
}

// Round 10
// 364.091 us; speedup vs baseline: 1.5811x; 1.0749x over previous
//
#include <hip/hip_runtime.h>
#include <hip/hip_bf16.h>
#include <math.h>

// Problem constants
#define BATCH 512
#define NSEG  64
#define HID   1024
#define ATT   128

typedef __attribute__((ext_vector_type(8))) __bf16 bf16x8;
typedef __attribute__((ext_vector_type(4))) __bf16 bf16x4;
typedef __attribute__((ext_vector_type(4))) float  f32x4;

typedef __attribute__((address_space(1))) const unsigned char ga_t;
typedef __attribute__((address_space(3))) unsigned char la_t;

// ---------------------------------------------------------------------------
// Fused weight pre-convert: wt1 (conv1 special), wt2..wt5, wfc in ONE launch.
// ---------------------------------------------------------------------------
__device__ inline void wcv(const float* __restrict__ w, __bf16* __restrict__ wt,
                           int t, int Ci, int Co) {
    int j  = t & 7;
    int t2 = t >> 3;
    int co = t2 % Co;
    int k8 = t2 / Co;
    int k  = k8 * 8 + j;
    int tap = k / Ci, ci = k % Ci;
    wt[t] = (__bf16)w[(co * Ci + ci) * 25 + tap];
}

__global__ void wprep_k(const float* __restrict__ cw1, const float* __restrict__ cw2,
                        const float* __restrict__ cw3, const float* __restrict__ cw4,
                        const float* __restrict__ cw5, const float* __restrict__ fcw,
                        __bf16* __restrict__ wt1, __bf16* __restrict__ wt2,
                        __bf16* __restrict__ wt3, __bf16* __restrict__ wt4,
                        __bf16* __restrict__ wt5, __bf16* __restrict__ wfc) {
    int t = blockIdx.x * 256 + threadIdx.x;
    if (t < 2048) {                       // conv1: wt[k8][m16][j8], k = tap*4+ci
        int j = t & 7, m = (t >> 3) & 15, k8 = t >> 7;
        int k = k8 * 8 + j, tap = k >> 2, ci = k & 3;
        float v = 0.f;
        if (m < 8 && ci < 3 && tap < 25) v = cw1[(m * 3 + ci) * 25 + tap];
        wt1[t] = (__bf16)v;
        return;
    }
    t -= 2048;
    if (t < 3200)  { wcv(cw2, wt2, t, 8, 16);   return; }
    t -= 3200;
    if (t < 12800) { wcv(cw3, wt3, t, 16, 32);  return; }
    t -= 12800;
    if (t < 51200) { wcv(cw4, wt4, t, 32, 64);  return; }
    t -= 51200;
    if (t < 204800){ wcv(cw5, wt5, t, 64, 128); return; }
    t -= 204800;
    if (t < 2097152) {
        int j = t & 7, t2 = t >> 3, o = t2 & 1023, k8 = t2 >> 10;
        wfc[t] = (__bf16)fcw[(size_t)o * 2048 + k8 * 8 + j];
    }
}

// ---------------------------------------------------------------------------
// Attention weight pre-convert: w1[o][k] f32 -> wa[k8][o][j8] bf16.
// ---------------------------------------------------------------------------
__global__ void watt_k(const float* __restrict__ w, __bf16* __restrict__ wt) {
    int t = blockIdx.x * 256 + threadIdx.x;   // n = 131072
    if (t >= 131072) return;
    int j  = t & 7;
    int t2 = t >> 3;
    int o  = t2 & 127;
    int k8 = t2 >> 7;
    wt[t] = (__bf16)w[(size_t)o * 1024 + k8 * 8 + j];
}

// ---------------------------------------------------------------------------
// conv1 via MFMA, 2D tile + zero-padded halo — round-1 form (measured 75.5us;
// do not touch: R=8/union and register-pool variants both regressed).
// ---------------------------------------------------------------------------
__global__ __launch_bounds__(256) void conv1_mfma_k(
    const float* __restrict__ in, const __bf16* __restrict__ Wt,
    const float* __restrict__ bias, __bf16* __restrict__ out) {
    constexpr int W  = 128;
    constexpr int R  = 4;
    constexpr int RP = R + 4;
    constexpr int WP = W + 4;
    constexpr int CSTR = R * W + 4;        // 516 f32

    __shared__ __align__(16) __bf16 xs[RP * WP * 4];   // 8448 B
    __shared__ float cs[8 * CSTR];                     // 16512 B

    const int tid = threadIdx.x;
    const int b   = blockIdx.x >> 5;
    const int y0  = (blockIdx.x & 31) * R;
    const float* inb = in + (size_t)b * 3 * 16384;

    if (tid < RP * 4) {
        int r = tid >> 2, s = tid & 3;
        int c = (s < 2) ? s : (128 + s);        // 0,1,130,131
        *(bf16x4*)(xs + (r * WP + c) * 4) = (bf16x4){};
    }
    {
        int r  = tid >> 5;
        int g  = tid & 31;
        int gy = y0 + r - 2;
        int c0 = g * 4;
        bf16x8 lo = {}, hi = {};
        if ((unsigned)gy < 128u) {
            const float* p = inb + (size_t)gy * 128 + c0;
            float4 a = *(const float4*)(p);
            float4 q = *(const float4*)(p + 16384);
            float4 c = *(const float4*)(p + 32768);
            lo[0] = (__bf16)a.x; lo[1] = (__bf16)q.x; lo[2] = (__bf16)c.x;
            lo[4] = (__bf16)a.y; lo[5] = (__bf16)q.y; lo[6] = (__bf16)c.y;
            hi[0] = (__bf16)a.z; hi[1] = (__bf16)q.z; hi[2] = (__bf16)c.z;
            hi[4] = (__bf16)a.w; hi[5] = (__bf16)q.w; hi[6] = (__bf16)c.w;
        }
        *(bf16x8*)(xs + (r * WP + c0 + 2) * 4)     = lo;
        *(bf16x8*)(xs + (r * WP + c0 + 2) * 4 + 8) = hi;
    }
    __syncthreads();

    const int lane = tid & 63, wave = tid >> 6;
    const int quad = lane >> 4, l15 = lane & 15;
    constexpr int F = 8;

    int pbase[F];
    f32x4 acc[F];
#pragma unroll
    for (int f = 0; f < F; ++f) {
        pbase[f] = ((wave + 2) * WP + f * 16 + l15 + 2) * 8;
        acc[f] = f32x4{0.f, 0.f, 0.f, 0.f};
    }
    const char* xsb = (const char*)xs;

#pragma unroll
    for (int kt = 0; kt < 4; ++kt) {
        int k8 = kt * 4 + quad;
        int tap0 = k8 * 2, tap1 = tap0 + 1;
        int t0 = tap0 < 25 ? tap0 : 0;
        int t1 = tap1 < 25 ? tap1 : 0;
        int s0 = ((t0 / 5 - 2) * WP + (t0 % 5 - 2)) * 8;
        int s1 = ((t1 / 5 - 2) * WP + (t1 % 5 - 2)) * 8;
        bf16x8 av = *(const bf16x8*)(Wt + ((size_t)k8 * 16 + l15) * 8);
#pragma unroll
        for (int f = 0; f < F; ++f) {
            bf16x4 b0 = *(const bf16x4*)(xsb + pbase[f] + s0);
            bf16x4 b1 = *(const bf16x4*)(xsb + pbase[f] + s1);
            bf16x8 bv = __builtin_shufflevector(b0, b1, 0, 1, 2, 3, 4, 5, 6, 7);
            acc[f] = __builtin_amdgcn_mfma_f32_16x16x32_bf16(av, bv, acc[f], 0, 0, 0);
        }
    }

#pragma unroll
    for (int f = 0; f < F; ++f) {
        int pl = wave * 128 + f * 16 + l15;
#pragma unroll
        for (int r = 0; r < 4; ++r) {
            int m = quad * 4 + r;
            if (m < 8) cs[m * CSTR + pl] = acc[f][r];
        }
    }
    __syncthreads();

    {
        int oi  = tid >> 1;
        int cog = (tid & 1) * 4;
        int oy  = oi >> 6, ox = oi & 63;
        int pl0 = oy * 2 * 128 + ox * 2;
        float4 b4 = *(const float4*)(bias + cog);
        bf16x4 ov;
#pragma unroll
        for (int i = 0; i < 4; ++i) {
            int cr = cog + i;
            float v0 = cs[cr * CSTR + pl0],       v1 = cs[cr * CSTR + pl0 + 1];
            float v2 = cs[cr * CSTR + pl0 + 128], v3 = cs[cr * CSTR + pl0 + 129];
            float m = fmaxf(fmaxf(v0, v1), fmaxf(v2, v3)) + ((const float*)&b4)[i];
            ov[i] = (__bf16)fmaxf(m, 0.f);
        }
        size_t ob = ((size_t)b * 4096 + (size_t)(y0 / 2 + oy) * 64 + ox) * 8 + cog;
        *(bf16x4*)(out + ob) = ov;
    }
}

// ---------------------------------------------------------------------------
// conv2..5: stage once, CS-split co-tiles per block, register pooling.
// Round 9: per-k8 LDS shift table (kills per-kt magic-div VALU in hot loop).
// Ci==8/IMGS==1 (conv2) staging via global_load_lds_dwordx4.
// ---------------------------------------------------------------------------
template<int Ci, int Co, int H, int RB, int IMGS, int OUTMODE, int CS>
__global__ __launch_bounds__(256) void conv2d_mfma_k(
    const __bf16* __restrict__ X, const __bf16* __restrict__ Wt,
    const float* __restrict__ bias, void* __restrict__ outp) {
    constexpr int W    = H;
    constexpr int PW   = W + 4;
    constexpr int PR   = RB + 4;
    constexpr int PIX  = RB * W;
    constexpr int P    = IMGS * PIX;
    constexpr int SE   = Ci + (Ci >= 16 ? 8 : 0);   // bank-coprime stride
    constexpr int SB   = SE * 2;                    // 16/48/80/144 B
    constexpr int K    = 25 * Ci;
    constexpr int KTF  = K / 32;
    constexpr int KT   = KTF + (K % 32 != 0 ? 1 : 0);
    constexpr int NK8  = KT * 4;                    // k8 slots (<=200)
    constexpr int FW   = P / 64;                    // frags per wave
    constexpr int NCOT = Co / 16 / CS;              // co tiles this block
    constexpr int C8   = Ci / 8;
    constexpr int BPI  = H / RB;
    constexpr int OW   = W / 2;

    __shared__ __align__(16) char smem[IMGS * PR * PW * SB];
    __shared__ int shtab[NK8];

    const int tid = threadIdx.x;
    const int b0  = (blockIdx.x / BPI) * IMGS;
    const int y0  = (blockIdx.x % BPI) * RB;
    const int co0 = blockIdx.y * (NCOT * 16);

    const int lane = tid & 63, wave = tid >> 6;

    // ---- per-k8 shift table (magic divs once per block, not per kt) ----
    if (tid < NK8) {
        int kk  = tid * 8;
        int kkc = kk < K ? kk : 0;
        int tap = kkc / Ci, cio = kkc % Ci;
        shtab[tid] = ((tap / 5 - 2) * PW + (tap % 5 - 2)) * SB + cio * 2;
    }

    if constexpr (Ci == 8 && IMGS == 1) {
        // async staging: one wave-load per in-image padded row
        __bf16* xs = (__bf16*)smem;
        if (tid < PR * 4) {                      // halo cols 0,1,W+2,W+3
            int r = tid >> 2, s = tid & 3;
            int c = (s < 2) ? s : (W + s);
            *(bf16x8*)(xs + (r * PW + c) * 8) = (bf16x8){};
        }
        for (int pr = wave; pr < PR; pr += 4) {
            int gy = y0 + pr - 2;
            if ((unsigned)gy < (unsigned)H) {
                const __bf16* gsrc = X + ((size_t)(b0 * H + gy) * W + lane) * 8;
                __bf16* ldst = xs + (pr * PW + 2) * 8;     // + lane*16B by HW
                __builtin_amdgcn_global_load_lds((ga_t*)gsrc, (la_t*)ldst, 16, 0, 0);
            } else {
                *(bf16x8*)(xs + (pr * PW + 2 + lane) * 8) = (bf16x8){};
            }
        }
    } else {
        constexpr int NSLOT = IMGS * PR * PW * C8;
        for (int i = tid; i < NSLOT; i += 256) {
            int s   = i % C8;
            int t2  = i / C8;
            int pc  = t2 % PW;
            int t3  = t2 / PW;
            int pr  = t3 % PR;
            int img = t3 / PR;
            int gy  = y0 + pr - 2;
            int gx  = pc - 2;
            bf16x8 v = {};
            if ((unsigned)gy < (unsigned)H && (unsigned)gx < (unsigned)W)
                v = *(const bf16x8*)(X + (((size_t)(b0 + img) * H + gy) * W + gx) * Ci + s * 8);
            *(bf16x8*)(smem + ((size_t)(img * PR + pr) * PW + pc) * SB + s * 16) = v;
        }
    }
    __syncthreads();

    const int quad = lane >> 4, l15 = lane & 15;

    int pbase[FW];
    f32x4 acc[FW][NCOT];
    int rg = 0, ch = 0, gbase = 0, img5 = 0;
    if constexpr (W >= 16) {
        constexpr int C16 = W / 16;
        ch = wave % C16;
        rg = wave / C16;
#pragma unroll
        for (int f = 0; f < FW; ++f) {
            int row = rg * FW + f;
            pbase[f] = ((row + 2) * PW + ch * 16 + l15 + 2) * SB;
        }
    } else {
        img5  = wave >> 1;
        gbase = (wave & 1) * FW;
#pragma unroll
        for (int f = 0; f < FW; ++f) {
            int g    = gbase + f;
            int row0 = 2 * g + (l15 >> 3);
            pbase[f] = ((img5 * PR + row0 + 2) * PW + (l15 & 7) + 2) * SB;
        }
    }
#pragma unroll
    for (int f = 0; f < FW; ++f)
#pragma unroll
        for (int c = 0; c < NCOT; ++c) acc[f][c] = f32x4{0.f, 0.f, 0.f, 0.f};

    const bf16x8 BZ = {};
    auto kstep = [&](int kt, bool mask) {
        int k8 = kt * 4 + quad;
        bool kok = true;
        if (mask) { kok = k8 * 8 < K; if (!kok) k8 = 0; }
        int shift = shtab[k8];
        bf16x8 bv[FW];
#pragma unroll
        for (int f = 0; f < FW; ++f) {
            bv[f] = *(const bf16x8*)(smem + pbase[f] + shift);
            if (mask && !kok) bv[f] = BZ;
        }
#pragma unroll
        for (int c = 0; c < NCOT; ++c) {
            bf16x8 av = *(const bf16x8*)(Wt + ((size_t)k8 * Co + co0 + c * 16 + l15) * 8);
#pragma unroll
            for (int f = 0; f < FW; ++f)
                acc[f][c] = __builtin_amdgcn_mfma_f32_16x16x32_bf16(av, bv[f], acc[f][c], 0, 0, 0);
        }
    };
#pragma unroll 2
    for (int kt = 0; kt < KTF; ++kt) kstep(kt, false);
    if constexpr (K % 32 != 0) kstep(KTF, true);

    if constexpr (W >= 16) {
#pragma unroll
        for (int fp = 0; fp < FW / 2; ++fp) {
            int f0  = 2 * fp;
            int row = rg * FW + f0;
            int oy  = (y0 + row) >> 1;
            int ox  = (ch * 16 + l15) >> 1;
            bool on = (l15 & 1) == 0;
#pragma unroll
            for (int c = 0; c < NCOT; ++c) {
                float4 bb = *(const float4*)(bias + co0 + c * 16 + quad * 4);
                bf16x4 ov;
#pragma unroll
                for (int r = 0; r < 4; ++r) {
                    float v0 = acc[f0][c][r];
                    float h0 = fmaxf(v0, __shfl_xor(v0, 1));
                    float v1 = acc[f0 + 1][c][r];
                    float h1 = fmaxf(v1, __shfl_xor(v1, 1));
                    float m  = fmaxf(h0, h1) + ((const float*)&bb)[r];
                    ov[r] = (__bf16)fmaxf(m, 0.f);
                }
                if (on)
                    *(bf16x4*)((__bf16*)outp +
                        (((size_t)b0 * (H / 2) + oy) * OW + ox) * Co + co0 + c * 16 + quad * 4) = ov;
            }
        }
    } else {
#pragma unroll
        for (int f = 0; f < FW; ++f) {
            int g   = gbase + f;
            bool on = ((l15 & 1) == 0) && (l15 < 8);
            int ox  = (l15 & 7) >> 1;
#pragma unroll
            for (int c = 0; c < NCOT; ++c) {
                float4 bb = *(const float4*)(bias + co0 + c * 16 + quad * 4);
#pragma unroll
                for (int r = 0; r < 4; ++r) {
                    float v  = acc[f][c][r];
                    float h  = fmaxf(v, __shfl_xor(v, 1));
                    float m2 = fmaxf(h, __shfl_xor(h, 8));
                    float m  = fmaxf(m2 + ((const float*)&bb)[r], 0.f);
                    if (on)
                        ((__bf16*)outp)[(size_t)(b0 + img5) * 2048 +
                            (co0 + c * 16 + quad * 4 + r) * 16 + g * 4 + ox] = (__bf16)m;
                }
            }
        }
    }
}

// ---------------------------------------------------------------------------
// FC via MFMA (512 blocks, 64 batch x 16 co each); emits f32 + bf16 emb.
// ---------------------------------------------------------------------------
__global__ __launch_bounds__(256) void fc_mfma_k(
    const __bf16* __restrict__ Xb, const __bf16* __restrict__ Wfc,
    const float* __restrict__ bias, float* __restrict__ emb,
    __bf16* __restrict__ embb) {
    const int tid  = threadIdx.x;
    const int lane = tid & 63, wave = tid >> 6;
    const int quad = lane >> 4, l15 = lane & 15;
    const int n    = blockIdx.x * 64 + wave * 16 + l15;
    const int co0  = blockIdx.y * 16;

    f32x4 acc = f32x4{0.f, 0.f, 0.f, 0.f};

#pragma unroll 8
    for (int kt = 0; kt < 64; ++kt) {
        int k8 = kt * 4 + quad;
        bf16x8 av = *(const bf16x8*)(Wfc + ((size_t)k8 * 1024 + co0 + l15) * 8);
        bf16x8 bv = *(const bf16x8*)(Xb + (size_t)n * 2048 + k8 * 8);
        acc = __builtin_amdgcn_mfma_f32_16x16x32_bf16(av, bv, acc, 0, 0, 0);
    }

    float4 b4 = *(const float4*)(bias + co0 + quad * 4);
    f32x4 v = acc;
    v[0] += b4.x; v[1] += b4.y; v[2] += b4.z; v[3] += b4.w;
    *(f32x4*)(emb + (size_t)n * 1024 + co0 + quad * 4) = v;
    bf16x4 eb;
    eb[0] = (__bf16)v[0]; eb[1] = (__bf16)v[1];
    eb[2] = (__bf16)v[2]; eb[3] = (__bf16)v[3];
    *(bf16x4*)(embb + (size_t)n * 1024 + co0 + quad * 4) = eb;
}

// ---------------------------------------------------------------------------
// Attention via MFMA: 32 blocks x 16 batch cols; 128 att rows per block.
// ---------------------------------------------------------------------------
__global__ __launch_bounds__(256) void att_mfma_k(
    const __bf16* __restrict__ embb, const __bf16* __restrict__ Wa,
    const float* __restrict__ b1, const float* __restrict__ w2,
    const float* __restrict__ b2, float* __restrict__ logits) {
    const int tid = threadIdx.x, lane = tid & 63, wave = tid >> 6;
    const int quad = lane >> 4, l15 = lane & 15;
    const int n = blockIdx.x * 16 + l15;        // batch index (32 blocks)

    f32x4 acc[2];
    acc[0] = f32x4{0.f, 0.f, 0.f, 0.f};
    acc[1] = f32x4{0.f, 0.f, 0.f, 0.f};

#pragma unroll 4
    for (int kt = 0; kt < 32; ++kt) {
        int k8 = kt * 4 + quad;
        bf16x8 bv = *(const bf16x8*)(embb + (size_t)n * 1024 + k8 * 8);
#pragma unroll
        for (int t = 0; t < 2; ++t) {
            int o0 = (wave * 2 + t) * 16;
            bf16x8 av = *(const bf16x8*)(Wa + ((size_t)k8 * 128 + o0 + l15) * 8);
            acc[t] = __builtin_amdgcn_mfma_f32_16x16x32_bf16(av, bv, acc[t], 0, 0, 0);
        }
    }

    float s = 0.f;
#pragma unroll
    for (int t = 0; t < 2; ++t) {
#pragma unroll
        for (int r = 0; r < 4; ++r) {
            int o = (wave * 2 + t) * 16 + quad * 4 + r;
            s += tanhf(acc[t][r] + b1[o]) * w2[o];
        }
    }
    s += __shfl_xor(s, 16);
    s += __shfl_xor(s, 32);

    __shared__ float part[4][16];
    if (lane < 16) part[wave][l15] = s;
    __syncthreads();
    if (tid < 16)
        logits[blockIdx.x * 16 + tid] =
            part[0][tid] + part[1][tid] + part[2][tid] + part[3][tid] + b2[0];
}

// ---------------------------------------------------------------------------
// Segment softmax + aggregation + classifier.  case_ids are SORTED
// (reference sorts them) -> each case is a contiguous [lo,hi) found by
// binary search; aggregation loops ~B/C elements instead of scanning all 512.
// ---------------------------------------------------------------------------
__global__ __launch_bounds__(256) void segment_k(
    const float* __restrict__ emb, const float* __restrict__ logits,
    const int* __restrict__ cid, const float* __restrict__ clf_w,
    const float* __restrict__ clf_b, float* __restrict__ out) {
    const int c = blockIdx.x;
    const int t = threadIdx.x;
    __shared__ int cids[BATCH];
    __shared__ float red[256];
    for (int i = t; i < BATCH; i += 256) cids[i] = cid[i];
    __syncthreads();

    // binary search [lo,hi) for case c (uniform across threads)
    int lo, hi;
    {
        int l = 0, r = BATCH;
        while (l < r) { int m = (l + r) >> 1; if (cids[m] < c) l = m + 1; else r = m; }
        lo = l;
        r = BATCH;
        while (l < r) { int m = (l + r) >> 1; if (cids[m] <= c) l = m + 1; else r = m; }
        hi = l;
    }

    float lm = -1e30f;
    for (int b = lo + t; b < hi; b += 256) lm = fmaxf(lm, logits[b]);
    red[t] = lm; __syncthreads();
    for (int s = 128; s > 0; s >>= 1) {
        if (t < s) red[t] = fmaxf(red[t], red[t + s]);
        __syncthreads();
    }
    float smax = red[0]; __syncthreads();

    float ls = 0.f;
    for (int b = lo + t; b < hi; b += 256) ls += expf(logits[b] - smax);
    red[t] = ls; __syncthreads();
    for (int s = 128; s > 0; s >>= 1) {
        if (t < s) red[t] += red[t + s];
        __syncthreads();
    }
    float denom = red[0]; __syncthreads();
    float inv = (denom > 0.f) ? 1.f / denom : 0.f;

    const int h0 = t * 4;
    float g0 = 0.f, g1 = 0.f, g2 = 0.f, g3 = 0.f;
    for (int b = lo; b < hi; ++b) {
        float wgt = expf(logits[b] - smax) * inv;
        float4 ev = *(const float4*)(emb + (size_t)b * HID + h0);
        g0 = fmaf(wgt, ev.x, g0);
        g1 = fmaf(wgt, ev.y, g1);
        g2 = fmaf(wgt, ev.z, g2);
        g3 = fmaf(wgt, ev.w, g3);
    }
    float4 cw = *(const float4*)(clf_w + h0);
    float ca = g0 * cw.x + g1 * cw.y + g2 * cw.z + g3 * cw.w;
    red[t] = ca; __syncthreads();
    for (int s = 128; s > 0; s >>= 1) {
        if (t < s) red[t] += red[t + s];
        __syncthreads();
    }
    if (t == 0) out[c] = 1.f / (1.f + expf(-(red[0] + clf_b[0])));
}

// ---------------------------------------------------------------------------
extern "C" void kernel_launch(void* const* d_in, const int* in_sizes, int n_in,
                              void* d_out, int out_size, void* d_ws, size_t ws_size,
                              hipStream_t stream) {
    const float* data = (const float*)d_in[0];
    const int*   cid  = (const int*)d_in[1];
    const float* cw1 = (const float*)d_in[2],  * cb1 = (const float*)d_in[3];
    const float* cw2 = (const float*)d_in[4],  * cb2 = (const float*)d_in[5];
    const float* cw3 = (const float*)d_in[6],  * cb3 = (const float*)d_in[7];
    const float* cw4 = (const float*)d_in[8],  * cb4 = (const float*)d_in[9];
    const float* cw5 = (const float*)d_in[10], * cb5 = (const float*)d_in[11];
    const float* fcw = (const float*)d_in[12], * fcb = (const float*)d_in[13];
    const float* aw1 = (const float*)d_in[14], * ab1 = (const float*)d_in[15];
    const float* aw2 = (const float*)d_in[16], * ab2 = (const float*)d_in[17];
    const float* clw = (const float*)d_in[18], * clb = (const float*)d_in[19];
    float* out = (float*)d_out;

    // workspace (bytes), non-overlapping, ~71.9 MB
    char* wsb = (char*)d_ws;
    __bf16* x1  = (__bf16*)(wsb);              // 512*4096*8   bf16 = 33,554,432 B
    __bf16* x2  = (__bf16*)(wsb + 33554432);   // 512*1024*16  bf16 = 16,777,216 B
    __bf16* x3  = (__bf16*)(wsb + 50331648);   // 512*256*32   bf16 =  8,388,608 B
    __bf16* x4  = (__bf16*)(wsb + 58720256);   // 512*64*64    bf16 =  4,194,304 B
    __bf16* x5b = (__bf16*)(wsb + 62914560);   // 512*2048     bf16 =  2,097,152 B
    float*  emb = (float*) (wsb + 65011712);   // 512*1024     f32  =  2,097,152 B
    float*  lg  = (float*) (wsb + 67108864);   // 512 f32
    __bf16* wt2 = (__bf16*)(wsb + 67110912);   //   3,200 bf16
    __bf16* wt3 = (__bf16*)(wsb + 67117312);   //  12,800 bf16
    __bf16* wt4 = (__bf16*)(wsb + 67142912);   //  51,200 bf16
    __bf16* wt5 = (__bf16*)(wsb + 67245312);   // 204,800 bf16
    __bf16* wfc = (__bf16*)(wsb + 67654912);   // 2,097,152 bf16 = 4,194,304 B
    __bf16* wt1 = (__bf16*)(wsb + 71849216);   //   2,048 bf16
    // overlaid in x1's region, which is dead after conv2 completes:
    __bf16* wa   = (__bf16*)(wsb);             // 131,072 bf16 = 262,144 B
    __bf16* embb = (__bf16*)(wsb + 1048576);   // 512*1024 bf16 = 1,048,576 B

    // fused weight preconvert (one launch): 2,371,200 elems
    wprep_k<<<9263, 256, 0, stream>>>(cw1, cw2, cw3, cw4, cw5, fcw,
                                      wt1, wt2, wt3, wt4, wt5, wfc);

    // conv1: 512 images x 32 row-blocks (R=4, round-1 form)
    conv1_mfma_k<<<16384, 256, 0, stream>>>(data, wt1, cb1, x1);

    // conv2..5
    conv2d_mfma_k<8,  16,  64, 8, 1, 0, 1><<<4096, 256, 0, stream>>>(x1, wt2, cb2, x2);
    // x1 is dead from here on: stage attention weights into its region
    watt_k<<<512, 256, 0, stream>>>(aw1, wa);
    conv2d_mfma_k<16, 32,  32, 8, 1, 0, 1><<<2048, 256, 0, stream>>>(x2, wt3, cb3, x3);
    conv2d_mfma_k<32, 64,  16, 8, 1, 0, 2><<<dim3(1024, 2), 256, 0, stream>>>(x3, wt4, cb4, x4);
    conv2d_mfma_k<64, 128, 8,  8, 2, 1, 2><<<dim3(256, 2), 256, 0, stream>>>(x4, wt5, cb5, x5b);

    fc_mfma_k<<<dim3(8, 64), 256, 0, stream>>>(x5b, wfc, fcb, emb, embb);
    att_mfma_k<<<32, 256, 0, stream>>>(embb, wa, ab1, aw2, ab2, lg);
    segment_k<<<NSEG, 256, 0, stream>>>(emb, lg, cid, clw, clb, out);
}

// Round 11
// 351.712 us; speedup vs baseline: 1.6368x; 1.0352x over previous
//
#include <hip/hip_runtime.h>
#include <hip/hip_bf16.h>
#include <math.h>

// Problem constants
#define BATCH 512
#define NSEG  64
#define HID   1024
#define ATT   128

typedef __attribute__((ext_vector_type(8))) __bf16 bf16x8;
typedef __attribute__((ext_vector_type(4))) __bf16 bf16x4;
typedef __attribute__((ext_vector_type(4))) float  f32x4;

typedef __attribute__((address_space(1))) const unsigned char ga_t;
typedef __attribute__((address_space(3))) unsigned char la_t;

// ---------------------------------------------------------------------------
// Fused weight pre-convert: wt1 (conv1 special), wt2..wt5, wfc in ONE launch.
// ---------------------------------------------------------------------------
__device__ inline void wcv(const float* __restrict__ w, __bf16* __restrict__ wt,
                           int t, int Ci, int Co) {
    int j  = t & 7;
    int t2 = t >> 3;
    int co = t2 % Co;
    int k8 = t2 / Co;
    int k  = k8 * 8 + j;
    int tap = k / Ci, ci = k % Ci;
    wt[t] = (__bf16)w[(co * Ci + ci) * 25 + tap];
}

__global__ void wprep_k(const float* __restrict__ cw1, const float* __restrict__ cw2,
                        const float* __restrict__ cw3, const float* __restrict__ cw4,
                        const float* __restrict__ cw5, const float* __restrict__ fcw,
                        __bf16* __restrict__ wt1, __bf16* __restrict__ wt2,
                        __bf16* __restrict__ wt3, __bf16* __restrict__ wt4,
                        __bf16* __restrict__ wt5, __bf16* __restrict__ wfc) {
    int t = blockIdx.x * 256 + threadIdx.x;
    if (t < 2048) {                       // conv1: wt[k8][m16][j8], k = tap*4+ci
        int j = t & 7, m = (t >> 3) & 15, k8 = t >> 7;
        int k = k8 * 8 + j, tap = k >> 2, ci = k & 3;
        float v = 0.f;
        if (m < 8 && ci < 3 && tap < 25) v = cw1[(m * 3 + ci) * 25 + tap];
        wt1[t] = (__bf16)v;
        return;
    }
    t -= 2048;
    if (t < 3200)  { wcv(cw2, wt2, t, 8, 16);   return; }
    t -= 3200;
    if (t < 12800) { wcv(cw3, wt3, t, 16, 32);  return; }
    t -= 12800;
    if (t < 51200) { wcv(cw4, wt4, t, 32, 64);  return; }
    t -= 51200;
    if (t < 204800){ wcv(cw5, wt5, t, 64, 128); return; }
    t -= 204800;
    if (t < 2097152) {
        int j = t & 7, t2 = t >> 3, o = t2 & 1023, k8 = t2 >> 10;
        wfc[t] = (__bf16)fcw[(size_t)o * 2048 + k8 * 8 + j];
    }
}

// ---------------------------------------------------------------------------
// Attention weight pre-convert: w1[o][k] f32 -> wa[k8][o][j8] bf16.
// ---------------------------------------------------------------------------
__global__ void watt_k(const float* __restrict__ w, __bf16* __restrict__ wt) {
    int t = blockIdx.x * 256 + threadIdx.x;   // n = 131072
    if (t >= 131072) return;
    int j  = t & 7;
    int t2 = t >> 3;
    int o  = t2 & 127;
    int k8 = t2 >> 7;
    wt[t] = (__bf16)w[(size_t)o * 1024 + k8 * 8 + j];
}

// ---------------------------------------------------------------------------
// conv1 via MFMA, 2D tile + zero-padded halo — round-1 form (measured ~76-81us;
// do not touch: R=8/union and register-pool variants both regressed).
// ---------------------------------------------------------------------------
__global__ __launch_bounds__(256) void conv1_mfma_k(
    const float* __restrict__ in, const __bf16* __restrict__ Wt,
    const float* __restrict__ bias, __bf16* __restrict__ out) {
    constexpr int W  = 128;
    constexpr int R  = 4;
    constexpr int RP = R + 4;
    constexpr int WP = W + 4;
    constexpr int CSTR = R * W + 4;        // 516 f32

    __shared__ __align__(16) __bf16 xs[RP * WP * 4];   // 8448 B
    __shared__ float cs[8 * CSTR];                     // 16512 B

    const int tid = threadIdx.x;
    const int b   = blockIdx.x >> 5;
    const int y0  = (blockIdx.x & 31) * R;
    const float* inb = in + (size_t)b * 3 * 16384;

    if (tid < RP * 4) {
        int r = tid >> 2, s = tid & 3;
        int c = (s < 2) ? s : (128 + s);        // 0,1,130,131
        *(bf16x4*)(xs + (r * WP + c) * 4) = (bf16x4){};
    }
    {
        int r  = tid >> 5;
        int g  = tid & 31;
        int gy = y0 + r - 2;
        int c0 = g * 4;
        bf16x8 lo = {}, hi = {};
        if ((unsigned)gy < 128u) {
            const float* p = inb + (size_t)gy * 128 + c0;
            float4 a = *(const float4*)(p);
            float4 q = *(const float4*)(p + 16384);
            float4 c = *(const float4*)(p + 32768);
            lo[0] = (__bf16)a.x; lo[1] = (__bf16)q.x; lo[2] = (__bf16)c.x;
            lo[4] = (__bf16)a.y; lo[5] = (__bf16)q.y; lo[6] = (__bf16)c.y;
            hi[0] = (__bf16)a.z; hi[1] = (__bf16)q.z; hi[2] = (__bf16)c.z;
            hi[4] = (__bf16)a.w; hi[5] = (__bf16)q.w; hi[6] = (__bf16)c.w;
        }
        *(bf16x8*)(xs + (r * WP + c0 + 2) * 4)     = lo;
        *(bf16x8*)(xs + (r * WP + c0 + 2) * 4 + 8) = hi;
    }
    __syncthreads();

    const int lane = tid & 63, wave = tid >> 6;
    const int quad = lane >> 4, l15 = lane & 15;
    constexpr int F = 8;

    int pbase[F];
    f32x4 acc[F];
#pragma unroll
    for (int f = 0; f < F; ++f) {
        pbase[f] = ((wave + 2) * WP + f * 16 + l15 + 2) * 8;
        acc[f] = f32x4{0.f, 0.f, 0.f, 0.f};
    }
    const char* xsb = (const char*)xs;

#pragma unroll
    for (int kt = 0; kt < 4; ++kt) {
        int k8 = kt * 4 + quad;
        int tap0 = k8 * 2, tap1 = tap0 + 1;
        int t0 = tap0 < 25 ? tap0 : 0;
        int t1 = tap1 < 25 ? tap1 : 0;
        int s0 = ((t0 / 5 - 2) * WP + (t0 % 5 - 2)) * 8;
        int s1 = ((t1 / 5 - 2) * WP + (t1 % 5 - 2)) * 8;
        bf16x8 av = *(const bf16x8*)(Wt + ((size_t)k8 * 16 + l15) * 8);
#pragma unroll
        for (int f = 0; f < F; ++f) {
            bf16x4 b0 = *(const bf16x4*)(xsb + pbase[f] + s0);
            bf16x4 b1 = *(const bf16x4*)(xsb + pbase[f] + s1);
            bf16x8 bv = __builtin_shufflevector(b0, b1, 0, 1, 2, 3, 4, 5, 6, 7);
            acc[f] = __builtin_amdgcn_mfma_f32_16x16x32_bf16(av, bv, acc[f], 0, 0, 0);
        }
    }

#pragma unroll
    for (int f = 0; f < F; ++f) {
        int pl = wave * 128 + f * 16 + l15;
#pragma unroll
        for (int r = 0; r < 4; ++r) {
            int m = quad * 4 + r;
            if (m < 8) cs[m * CSTR + pl] = acc[f][r];
        }
    }
    __syncthreads();

    {
        int oi  = tid >> 1;
        int cog = (tid & 1) * 4;
        int oy  = oi >> 6, ox = oi & 63;
        int pl0 = oy * 2 * 128 + ox * 2;
        float4 b4 = *(const float4*)(bias + cog);
        bf16x4 ov;
#pragma unroll
        for (int i = 0; i < 4; ++i) {
            int cr = cog + i;
            float v0 = cs[cr * CSTR + pl0],       v1 = cs[cr * CSTR + pl0 + 1];
            float v2 = cs[cr * CSTR + pl0 + 128], v3 = cs[cr * CSTR + pl0 + 129];
            float m = fmaxf(fmaxf(v0, v1), fmaxf(v2, v3)) + ((const float*)&b4)[i];
            ov[i] = (__bf16)fmaxf(m, 0.f);
        }
        size_t ob = ((size_t)b * 4096 + (size_t)(y0 / 2 + oy) * 64 + ox) * 8 + cog;
        *(bf16x4*)(out + ob) = ov;
    }
}

// ---------------------------------------------------------------------------
// conv2..5: stage once, CS-split co-tiles per block, register pooling.
// Round 11: explicit A-fragment software pipeline — av for kt+1 is loaded
// (global, L2/L3) at the top of the body so its ~200cy latency hides behind
// the current kstep's ds_reads + MFMAs.  shtab keeps divs out of the loop.
// Ci==8/IMGS==1 (conv2) staging via global_load_lds_dwordx4.
// ---------------------------------------------------------------------------
template<int Ci, int Co, int H, int RB, int IMGS, int OUTMODE, int CS>
__global__ __launch_bounds__(256) void conv2d_mfma_k(
    const __bf16* __restrict__ X, const __bf16* __restrict__ Wt,
    const float* __restrict__ bias, void* __restrict__ outp) {
    constexpr int W    = H;
    constexpr int PW   = W + 4;
    constexpr int PR   = RB + 4;
    constexpr int PIX  = RB * W;
    constexpr int P    = IMGS * PIX;
    constexpr int SE   = Ci + (Ci >= 16 ? 8 : 0);   // bank-coprime stride
    constexpr int SB   = SE * 2;                    // 16/48/80/144 B
    constexpr int K    = 25 * Ci;
    constexpr int KTF  = K / 32;
    constexpr int KT   = KTF + (K % 32 != 0 ? 1 : 0);
    constexpr int NK8  = KT * 4;                    // k8 slots (<=200)
    constexpr int FW   = P / 64;                    // frags per wave
    constexpr int NCOT = Co / 16 / CS;              // co tiles this block
    constexpr int C8   = Ci / 8;
    constexpr int BPI  = H / RB;
    constexpr int OW   = W / 2;

    __shared__ __align__(16) char smem[IMGS * PR * PW * SB];
    __shared__ int shtab[NK8];

    const int tid = threadIdx.x;
    const int b0  = (blockIdx.x / BPI) * IMGS;
    const int y0  = (blockIdx.x % BPI) * RB;
    const int co0 = blockIdx.y * (NCOT * 16);

    const int lane = tid & 63, wave = tid >> 6;

    // ---- per-k8 shift table (magic divs once per block, not per kt) ----
    if (tid < NK8) {
        int kk  = tid * 8;
        int kkc = kk < K ? kk : 0;
        int tap = kkc / Ci, cio = kkc % Ci;
        shtab[tid] = ((tap / 5 - 2) * PW + (tap % 5 - 2)) * SB + cio * 2;
    }

    if constexpr (Ci == 8 && IMGS == 1) {
        // async staging: one wave-load per in-image padded row
        __bf16* xs = (__bf16*)smem;
        if (tid < PR * 4) {                      // halo cols 0,1,W+2,W+3
            int r = tid >> 2, s = tid & 3;
            int c = (s < 2) ? s : (W + s);
            *(bf16x8*)(xs + (r * PW + c) * 8) = (bf16x8){};
        }
        for (int pr = wave; pr < PR; pr += 4) {
            int gy = y0 + pr - 2;
            if ((unsigned)gy < (unsigned)H) {
                const __bf16* gsrc = X + ((size_t)(b0 * H + gy) * W + lane) * 8;
                __bf16* ldst = xs + (pr * PW + 2) * 8;     // + lane*16B by HW
                __builtin_amdgcn_global_load_lds((ga_t*)gsrc, (la_t*)ldst, 16, 0, 0);
            } else {
                *(bf16x8*)(xs + (pr * PW + 2 + lane) * 8) = (bf16x8){};
            }
        }
    } else {
        constexpr int NSLOT = IMGS * PR * PW * C8;
        for (int i = tid; i < NSLOT; i += 256) {
            int s   = i % C8;
            int t2  = i / C8;
            int pc  = t2 % PW;
            int t3  = t2 / PW;
            int pr  = t3 % PR;
            int img = t3 / PR;
            int gy  = y0 + pr - 2;
            int gx  = pc - 2;
            bf16x8 v = {};
            if ((unsigned)gy < (unsigned)H && (unsigned)gx < (unsigned)W)
                v = *(const bf16x8*)(X + (((size_t)(b0 + img) * H + gy) * W + gx) * Ci + s * 8);
            *(bf16x8*)(smem + ((size_t)(img * PR + pr) * PW + pc) * SB + s * 16) = v;
        }
    }
    __syncthreads();

    const int quad = lane >> 4, l15 = lane & 15;

    int pbase[FW];
    f32x4 acc[FW][NCOT];
    int rg = 0, ch = 0, gbase = 0, img5 = 0;
    if constexpr (W >= 16) {
        constexpr int C16 = W / 16;
        ch = wave % C16;
        rg = wave / C16;
#pragma unroll
        for (int f = 0; f < FW; ++f) {
            int row = rg * FW + f;
            pbase[f] = ((row + 2) * PW + ch * 16 + l15 + 2) * SB;
        }
    } else {
        img5  = wave >> 1;
        gbase = (wave & 1) * FW;
#pragma unroll
        for (int f = 0; f < FW; ++f) {
            int g    = gbase + f;
            int row0 = 2 * g + (l15 >> 3);
            pbase[f] = ((img5 * PR + row0 + 2) * PW + (l15 & 7) + 2) * SB;
        }
    }
#pragma unroll
    for (int f = 0; f < FW; ++f)
#pragma unroll
        for (int c = 0; c < NCOT; ++c) acc[f][c] = f32x4{0.f, 0.f, 0.f, 0.f};

    const bf16x8 BZ = {};

    // ---- K loop with A-fragment software pipeline (1 kstep lookahead) ----
    bf16x8 avc[NCOT];
    {
        int k8 = quad;                      // kt = 0 (always valid: 8*quad < K)
#pragma unroll
        for (int c = 0; c < NCOT; ++c)
            avc[c] = *(const bf16x8*)(Wt + ((size_t)k8 * Co + co0 + c * 16 + l15) * 8);
    }
#pragma unroll 2
    for (int kt = 0; kt < KT; ++kt) {
        // prefetch next kstep's A (clamped; past-end loads slot 0, harmless)
        bf16x8 avn[NCOT];
        {
            int k8n = (kt + 1) * 4 + quad;
            if (kt + 1 >= KT || k8n * 8 >= K) k8n = 0;
#pragma unroll
            for (int c = 0; c < NCOT; ++c)
                avn[c] = *(const bf16x8*)(Wt + ((size_t)k8n * Co + co0 + c * 16 + l15) * 8);
        }
        int k8 = kt * 4 + quad;
        bool kok = true;
        if (K % 32 != 0 && kt == KT - 1) {    // tail kstep only (compile-time gate)
            kok = k8 * 8 < K;
            if (!kok) k8 = 0;
        }
        int shift = shtab[k8];
        bf16x8 bv[FW];
#pragma unroll
        for (int f = 0; f < FW; ++f) {
            bv[f] = *(const bf16x8*)(smem + pbase[f] + shift);
            if (!kok) bv[f] = BZ;
        }
#pragma unroll
        for (int c = 0; c < NCOT; ++c)
#pragma unroll
            for (int f = 0; f < FW; ++f)
                acc[f][c] = __builtin_amdgcn_mfma_f32_16x16x32_bf16(avc[c], bv[f], acc[f][c], 0, 0, 0);
#pragma unroll
        for (int c = 0; c < NCOT; ++c) avc[c] = avn[c];
    }

    if constexpr (W >= 16) {
#pragma unroll
        for (int fp = 0; fp < FW / 2; ++fp) {
            int f0  = 2 * fp;
            int row = rg * FW + f0;
            int oy  = (y0 + row) >> 1;
            int ox  = (ch * 16 + l15) >> 1;
            bool on = (l15 & 1) == 0;
#pragma unroll
            for (int c = 0; c < NCOT; ++c) {
                float4 bb = *(const float4*)(bias + co0 + c * 16 + quad * 4);
                bf16x4 ov;
#pragma unroll
                for (int r = 0; r < 4; ++r) {
                    float v0 = acc[f0][c][r];
                    float h0 = fmaxf(v0, __shfl_xor(v0, 1));
                    float v1 = acc[f0 + 1][c][r];
                    float h1 = fmaxf(v1, __shfl_xor(v1, 1));
                    float m  = fmaxf(h0, h1) + ((const float*)&bb)[r];
                    ov[r] = (__bf16)fmaxf(m, 0.f);
                }
                if (on)
                    *(bf16x4*)((__bf16*)outp +
                        (((size_t)b0 * (H / 2) + oy) * OW + ox) * Co + co0 + c * 16 + quad * 4) = ov;
            }
        }
    } else {
#pragma unroll
        for (int f = 0; f < FW; ++f) {
            int g   = gbase + f;
            bool on = ((l15 & 1) == 0) && (l15 < 8);
            int ox  = (l15 & 7) >> 1;
#pragma unroll
            for (int c = 0; c < NCOT; ++c) {
                float4 bb = *(const float4*)(bias + co0 + c * 16 + quad * 4);
#pragma unroll
                for (int r = 0; r < 4; ++r) {
                    float v  = acc[f][c][r];
                    float h  = fmaxf(v, __shfl_xor(v, 1));
                    float m2 = fmaxf(h, __shfl_xor(h, 8));
                    float m  = fmaxf(m2 + ((const float*)&bb)[r], 0.f);
                    if (on)
                        ((__bf16*)outp)[(size_t)(b0 + img5) * 2048 +
                            (co0 + c * 16 + quad * 4 + r) * 16 + g * 4 + ox] = (__bf16)m;
                }
            }
        }
    }
}

// ---------------------------------------------------------------------------
// FC via MFMA (512 blocks, 64 batch x 16 co each); emits f32 + bf16 emb.
// ---------------------------------------------------------------------------
__global__ __launch_bounds__(256) void fc_mfma_k(
    const __bf16* __restrict__ Xb, const __bf16* __restrict__ Wfc,
    const float* __restrict__ bias, float* __restrict__ emb,
    __bf16* __restrict__ embb) {
    const int tid  = threadIdx.x;
    const int lane = tid & 63, wave = tid >> 6;
    const int quad = lane >> 4, l15 = lane & 15;
    const int n    = blockIdx.x * 64 + wave * 16 + l15;
    const int co0  = blockIdx.y * 16;

    f32x4 acc = f32x4{0.f, 0.f, 0.f, 0.f};

#pragma unroll 8
    for (int kt = 0; kt < 64; ++kt) {
        int k8 = kt * 4 + quad;
        bf16x8 av = *(const bf16x8*)(Wfc + ((size_t)k8 * 1024 + co0 + l15) * 8);
        bf16x8 bv = *(const bf16x8*)(Xb + (size_t)n * 2048 + k8 * 8);
        acc = __builtin_amdgcn_mfma_f32_16x16x32_bf16(av, bv, acc, 0, 0, 0);
    }

    float4 b4 = *(const float4*)(bias + co0 + quad * 4);
    f32x4 v = acc;
    v[0] += b4.x; v[1] += b4.y; v[2] += b4.z; v[3] += b4.w;
    *(f32x4*)(emb + (size_t)n * 1024 + co0 + quad * 4) = v;
    bf16x4 eb;
    eb[0] = (__bf16)v[0]; eb[1] = (__bf16)v[1];
    eb[2] = (__bf16)v[2]; eb[3] = (__bf16)v[3];
    *(bf16x4*)(embb + (size_t)n * 1024 + co0 + quad * 4) = eb;
}

// ---------------------------------------------------------------------------
// Attention via MFMA: 32 blocks x 16 batch cols; 128 att rows per block.
// ---------------------------------------------------------------------------
__global__ __launch_bounds__(256) void att_mfma_k(
    const __bf16* __restrict__ embb, const __bf16* __restrict__ Wa,
    const float* __restrict__ b1, const float* __restrict__ w2,
    const float* __restrict__ b2, float* __restrict__ logits) {
    const int tid = threadIdx.x, lane = tid & 63, wave = tid >> 6;
    const int quad = lane >> 4, l15 = lane & 15;
    const int n = blockIdx.x * 16 + l15;        // batch index (32 blocks)

    f32x4 acc[2];
    acc[0] = f32x4{0.f, 0.f, 0.f, 0.f};
    acc[1] = f32x4{0.f, 0.f, 0.f, 0.f};

#pragma unroll 4
    for (int kt = 0; kt < 32; ++kt) {
        int k8 = kt * 4 + quad;
        bf16x8 bv = *(const bf16x8*)(embb + (size_t)n * 1024 + k8 * 8);
#pragma unroll
        for (int t = 0; t < 2; ++t) {
            int o0 = (wave * 2 + t) * 16;
            bf16x8 av = *(const bf16x8*)(Wa + ((size_t)k8 * 128 + o0 + l15) * 8);
            acc[t] = __builtin_amdgcn_mfma_f32_16x16x32_bf16(av, bv, acc[t], 0, 0, 0);
        }
    }

    float s = 0.f;
#pragma unroll
    for (int t = 0; t < 2; ++t) {
#pragma unroll
        for (int r = 0; r < 4; ++r) {
            int o = (wave * 2 + t) * 16 + quad * 4 + r;
            s += tanhf(acc[t][r] + b1[o]) * w2[o];
        }
    }
    s += __shfl_xor(s, 16);
    s += __shfl_xor(s, 32);

    __shared__ float part[4][16];
    if (lane < 16) part[wave][l15] = s;
    __syncthreads();
    if (tid < 16)
        logits[blockIdx.x * 16 + tid] =
            part[0][tid] + part[1][tid] + part[2][tid] + part[3][tid] + b2[0];
}

// ---------------------------------------------------------------------------
// Segment softmax + aggregation + classifier.  case_ids are SORTED
// (reference sorts them) -> each case is a contiguous [lo,hi) found by
// binary search; aggregation loops ~B/C elements instead of scanning all 512.
// ---------------------------------------------------------------------------
__global__ __launch_bounds__(256) void segment_k(
    const float* __restrict__ emb, const float* __restrict__ logits,
    const int* __restrict__ cid, const float* __restrict__ clf_w,
    const float* __restrict__ clf_b, float* __restrict__ out) {
    const int c = blockIdx.x;
    const int t = threadIdx.x;
    __shared__ int cids[BATCH];
    __shared__ float red[256];
    for (int i = t; i < BATCH; i += 256) cids[i] = cid[i];
    __syncthreads();

    // binary search [lo,hi) for case c (uniform across threads)
    int lo, hi;
    {
        int l = 0, r = BATCH;
        while (l < r) { int m = (l + r) >> 1; if (cids[m] < c) l = m + 1; else r = m; }
        lo = l;
        r = BATCH;
        while (l < r) { int m = (l + r) >> 1; if (cids[m] <= c) l = m + 1; else r = m; }
        hi = l;
    }

    float lm = -1e30f;
    for (int b = lo + t; b < hi; b += 256) lm = fmaxf(lm, logits[b]);
    red[t] = lm; __syncthreads();
    for (int s = 128; s > 0; s >>= 1) {
        if (t < s) red[t] = fmaxf(red[t], red[t + s]);
        __syncthreads();
    }
    float smax = red[0]; __syncthreads();

    float ls = 0.f;
    for (int b = lo + t; b < hi; b += 256) ls += expf(logits[b] - smax);
    red[t] = ls; __syncthreads();
    for (int s = 128; s > 0; s >>= 1) {
        if (t < s) red[t] += red[t + s];
        __syncthreads();
    }
    float denom = red[0]; __syncthreads();
    float inv = (denom > 0.f) ? 1.f / denom : 0.f;

    const int h0 = t * 4;
    float g0 = 0.f, g1 = 0.f, g2 = 0.f, g3 = 0.f;
    for (int b = lo; b < hi; ++b) {
        float wgt = expf(logits[b] - smax) * inv;
        float4 ev = *(const float4*)(emb + (size_t)b * HID + h0);
        g0 = fmaf(wgt, ev.x, g0);
        g1 = fmaf(wgt, ev.y, g1);
        g2 = fmaf(wgt, ev.z, g2);
        g3 = fmaf(wgt, ev.w, g3);
    }
    float4 cw = *(const float4*)(clf_w + h0);
    float ca = g0 * cw.x + g1 * cw.y + g2 * cw.z + g3 * cw.w;
    red[t] = ca; __syncthreads();
    for (int s = 128; s > 0; s >>= 1) {
        if (t < s) red[t] += red[t + s];
        __syncthreads();
    }
    if (t == 0) out[c] = 1.f / (1.f + expf(-(red[0] + clf_b[0])));
}

// ---------------------------------------------------------------------------
extern "C" void kernel_launch(void* const* d_in, const int* in_sizes, int n_in,
                              void* d_out, int out_size, void* d_ws, size_t ws_size,
                              hipStream_t stream) {
    const float* data = (const float*)d_in[0];
    const int*   cid  = (const int*)d_in[1];
    const float* cw1 = (const float*)d_in[2],  * cb1 = (const float*)d_in[3];
    const float* cw2 = (const float*)d_in[4],  * cb2 = (const float*)d_in[5];
    const float* cw3 = (const float*)d_in[6],  * cb3 = (const float*)d_in[7];
    const float* cw4 = (const float*)d_in[8],  * cb4 = (const float*)d_in[9];
    const float* cw5 = (const float*)d_in[10], * cb5 = (const float*)d_in[11];
    const float* fcw = (const float*)d_in[12], * fcb = (const float*)d_in[13];
    const float* aw1 = (const float*)d_in[14], * ab1 = (const float*)d_in[15];
    const float* aw2 = (const float*)d_in[16], * ab2 = (const float*)d_in[17];
    const float* clw = (const float*)d_in[18], * clb = (const float*)d_in[19];
    float* out = (float*)d_out;

    // workspace (bytes), non-overlapping, ~71.9 MB
    char* wsb = (char*)d_ws;
    __bf16* x1  = (__bf16*)(wsb);              // 512*4096*8   bf16 = 33,554,432 B
    __bf16* x2  = (__bf16*)(wsb + 33554432);   // 512*1024*16  bf16 = 16,777,216 B
    __bf16* x3  = (__bf16*)(wsb + 50331648);   // 512*256*32   bf16 =  8,388,608 B
    __bf16* x4  = (__bf16*)(wsb + 58720256);   // 512*64*64    bf16 =  4,194,304 B
    __bf16* x5b = (__bf16*)(wsb + 62914560);   // 512*2048     bf16 =  2,097,152 B
    float*  emb = (float*) (wsb + 65011712);   // 512*1024     f32  =  2,097,152 B
    float*  lg  = (float*) (wsb + 67108864);   // 512 f32
    __bf16* wt2 = (__bf16*)(wsb + 67110912);   //   3,200 bf16
    __bf16* wt3 = (__bf16*)(wsb + 67117312);   //  12,800 bf16
    __bf16* wt4 = (__bf16*)(wsb + 67142912);   //  51,200 bf16
    __bf16* wt5 = (__bf16*)(wsb + 67245312);   // 204,800 bf16
    __bf16* wfc = (__bf16*)(wsb + 67654912);   // 2,097,152 bf16 = 4,194,304 B
    __bf16* wt1 = (__bf16*)(wsb + 71849216);   //   2,048 bf16
    // overlaid in x1's region, which is dead after conv2 completes:
    __bf16* wa   = (__bf16*)(wsb);             // 131,072 bf16 = 262,144 B
    __bf16* embb = (__bf16*)(wsb + 1048576);   // 512*1024 bf16 = 1,048,576 B

    // fused weight preconvert (one launch): 2,371,200 elems
    wprep_k<<<9263, 256, 0, stream>>>(cw1, cw2, cw3, cw4, cw5, fcw,
                                      wt1, wt2, wt3, wt4, wt5, wfc);

    // conv1: 512 images x 32 row-blocks (R=4, round-1 form)
    conv1_mfma_k<<<16384, 256, 0, stream>>>(data, wt1, cb1, x1);

    // conv2..5
    conv2d_mfma_k<8,  16,  64, 8, 1, 0, 1><<<4096, 256, 0, stream>>>(x1, wt2, cb2, x2);
    // x1 is dead from here on: stage attention weights into its region
    watt_k<<<512, 256, 0, stream>>>(aw1, wa);
    conv2d_mfma_k<16, 32,  32, 8, 1, 0, 1><<<2048, 256, 0, stream>>>(x2, wt3, cb3, x3);
    conv2d_mfma_k<32, 64,  16, 8, 1, 0, 2><<<dim3(1024, 2), 256, 0, stream>>>(x3, wt4, cb4, x4);
    conv2d_mfma_k<64, 128, 8,  8, 2, 1, 4><<<dim3(256, 4), 256, 0, stream>>>(x4, wt5, cb5, x5b);

    fc_mfma_k<<<dim3(8, 64), 256, 0, stream>>>(x5b, wfc, fcb, emb, embb);
    att_mfma_k<<<32, 256, 0, stream>>>(embb, wa, ab1, aw2, ab2, lg);
    segment_k<<<NSEG, 256, 0, stream>>>(emb, lg, cid, clw, clb, out);
}

// Round 12
// 349.420 us; speedup vs baseline: 1.6475x; 1.0066x over previous
//
#include <hip/hip_runtime.h>
#include <hip/hip_bf16.h>
#include <math.h>

// Problem constants
#define BATCH 512
#define NSEG  64
#define HID   1024
#define ATT   128

typedef __attribute__((ext_vector_type(8))) __bf16 bf16x8;
typedef __attribute__((ext_vector_type(4))) __bf16 bf16x4;
typedef __attribute__((ext_vector_type(4))) float  f32x4;

typedef __attribute__((address_space(1))) const unsigned char ga_t;
typedef __attribute__((address_space(3))) unsigned char la_t;

// ---------------------------------------------------------------------------
// Fused weight pre-convert: wt1 (conv1 special), wt2..wt5, wfc in ONE launch.
// ---------------------------------------------------------------------------
__device__ inline void wcv(const float* __restrict__ w, __bf16* __restrict__ wt,
                           int t, int Ci, int Co) {
    int j  = t & 7;
    int t2 = t >> 3;
    int co = t2 % Co;
    int k8 = t2 / Co;
    int k  = k8 * 8 + j;
    int tap = k / Ci, ci = k % Ci;
    wt[t] = (__bf16)w[(co * Ci + ci) * 25 + tap];
}

__global__ void wprep_k(const float* __restrict__ cw1, const float* __restrict__ cw2,
                        const float* __restrict__ cw3, const float* __restrict__ cw4,
                        const float* __restrict__ cw5, const float* __restrict__ fcw,
                        __bf16* __restrict__ wt1, __bf16* __restrict__ wt2,
                        __bf16* __restrict__ wt3, __bf16* __restrict__ wt4,
                        __bf16* __restrict__ wt5, __bf16* __restrict__ wfc) {
    int t = blockIdx.x * 256 + threadIdx.x;
    if (t < 2048) {                       // conv1: wt[k8][m16][j8], k = tap*4+ci
        int j = t & 7, m = (t >> 3) & 15, k8 = t >> 7;
        int k = k8 * 8 + j, tap = k >> 2, ci = k & 3;
        float v = 0.f;
        if (m < 8 && ci < 3 && tap < 25) v = cw1[(m * 3 + ci) * 25 + tap];
        wt1[t] = (__bf16)v;
        return;
    }
    t -= 2048;
    if (t < 3200)  { wcv(cw2, wt2, t, 8, 16);   return; }
    t -= 3200;
    if (t < 12800) { wcv(cw3, wt3, t, 16, 32);  return; }
    t -= 12800;
    if (t < 51200) { wcv(cw4, wt4, t, 32, 64);  return; }
    t -= 51200;
    if (t < 204800){ wcv(cw5, wt5, t, 64, 128); return; }
    t -= 204800;
    if (t < 2097152) {
        int j = t & 7, t2 = t >> 3, o = t2 & 1023, k8 = t2 >> 10;
        wfc[t] = (__bf16)fcw[(size_t)o * 2048 + k8 * 8 + j];
    }
}

// ---------------------------------------------------------------------------
// Attention weight pre-convert: w1[o][k] f32 -> wa[k8][o][j8] bf16.
// ---------------------------------------------------------------------------
__global__ void watt_k(const float* __restrict__ w, __bf16* __restrict__ wt) {
    int t = blockIdx.x * 256 + threadIdx.x;   // n = 131072
    if (t >= 131072) return;
    int j  = t & 7;
    int t2 = t >> 3;
    int o  = t2 & 127;
    int k8 = t2 >> 7;
    wt[t] = (__bf16)w[(size_t)o * 1024 + k8 * 8 + j];
}

// ---------------------------------------------------------------------------
// conv1 via MFMA, 2D tile + zero-padded halo — round-1 form (measured ~76us;
// do not touch: R=8/union and register-pool variants both regressed).
// ---------------------------------------------------------------------------
__global__ __launch_bounds__(256) void conv1_mfma_k(
    const float* __restrict__ in, const __bf16* __restrict__ Wt,
    const float* __restrict__ bias, __bf16* __restrict__ out) {
    constexpr int W  = 128;
    constexpr int R  = 4;
    constexpr int RP = R + 4;
    constexpr int WP = W + 4;
    constexpr int CSTR = R * W + 4;        // 516 f32

    __shared__ __align__(16) __bf16 xs[RP * WP * 4];   // 8448 B
    __shared__ float cs[8 * CSTR];                     // 16512 B

    const int tid = threadIdx.x;
    const int b   = blockIdx.x >> 5;
    const int y0  = (blockIdx.x & 31) * R;
    const float* inb = in + (size_t)b * 3 * 16384;

    if (tid < RP * 4) {
        int r = tid >> 2, s = tid & 3;
        int c = (s < 2) ? s : (128 + s);        // 0,1,130,131
        *(bf16x4*)(xs + (r * WP + c) * 4) = (bf16x4){};
    }
    {
        int r  = tid >> 5;
        int g  = tid & 31;
        int gy = y0 + r - 2;
        int c0 = g * 4;
        bf16x8 lo = {}, hi = {};
        if ((unsigned)gy < 128u) {
            const float* p = inb + (size_t)gy * 128 + c0;
            float4 a = *(const float4*)(p);
            float4 q = *(const float4*)(p + 16384);
            float4 c = *(const float4*)(p + 32768);
            lo[0] = (__bf16)a.x; lo[1] = (__bf16)q.x; lo[2] = (__bf16)c.x;
            lo[4] = (__bf16)a.y; lo[5] = (__bf16)q.y; lo[6] = (__bf16)c.y;
            hi[0] = (__bf16)a.z; hi[1] = (__bf16)q.z; hi[2] = (__bf16)c.z;
            hi[4] = (__bf16)a.w; hi[5] = (__bf16)q.w; hi[6] = (__bf16)c.w;
        }
        *(bf16x8*)(xs + (r * WP + c0 + 2) * 4)     = lo;
        *(bf16x8*)(xs + (r * WP + c0 + 2) * 4 + 8) = hi;
    }
    __syncthreads();

    const int lane = tid & 63, wave = tid >> 6;
    const int quad = lane >> 4, l15 = lane & 15;
    constexpr int F = 8;

    int pbase[F];
    f32x4 acc[F];
#pragma unroll
    for (int f = 0; f < F; ++f) {
        pbase[f] = ((wave + 2) * WP + f * 16 + l15 + 2) * 8;
        acc[f] = f32x4{0.f, 0.f, 0.f, 0.f};
    }
    const char* xsb = (const char*)xs;

#pragma unroll
    for (int kt = 0; kt < 4; ++kt) {
        int k8 = kt * 4 + quad;
        int tap0 = k8 * 2, tap1 = tap0 + 1;
        int t0 = tap0 < 25 ? tap0 : 0;
        int t1 = tap1 < 25 ? tap1 : 0;
        int s0 = ((t0 / 5 - 2) * WP + (t0 % 5 - 2)) * 8;
        int s1 = ((t1 / 5 - 2) * WP + (t1 % 5 - 2)) * 8;
        bf16x8 av = *(const bf16x8*)(Wt + ((size_t)k8 * 16 + l15) * 8);
#pragma unroll
        for (int f = 0; f < F; ++f) {
            bf16x4 b0 = *(const bf16x4*)(xsb + pbase[f] + s0);
            bf16x4 b1 = *(const bf16x4*)(xsb + pbase[f] + s1);
            bf16x8 bv = __builtin_shufflevector(b0, b1, 0, 1, 2, 3, 4, 5, 6, 7);
            acc[f] = __builtin_amdgcn_mfma_f32_16x16x32_bf16(av, bv, acc[f], 0, 0, 0);
        }
    }

#pragma unroll
    for (int f = 0; f < F; ++f) {
        int pl = wave * 128 + f * 16 + l15;
#pragma unroll
        for (int r = 0; r < 4; ++r) {
            int m = quad * 4 + r;
            if (m < 8) cs[m * CSTR + pl] = acc[f][r];
        }
    }
    __syncthreads();

    {
        int oi  = tid >> 1;
        int cog = (tid & 1) * 4;
        int oy  = oi >> 6, ox = oi & 63;
        int pl0 = oy * 2 * 128 + ox * 2;
        float4 b4 = *(const float4*)(bias + cog);
        bf16x4 ov;
#pragma unroll
        for (int i = 0; i < 4; ++i) {
            int cr = cog + i;
            float v0 = cs[cr * CSTR + pl0],       v1 = cs[cr * CSTR + pl0 + 1];
            float v2 = cs[cr * CSTR + pl0 + 128], v3 = cs[cr * CSTR + pl0 + 129];
            float m = fmaxf(fmaxf(v0, v1), fmaxf(v2, v3)) + ((const float*)&b4)[i];
            ov[i] = (__bf16)fmaxf(m, 0.f);
        }
        size_t ob = ((size_t)b * 4096 + (size_t)(y0 / 2 + oy) * 64 + ox) * 8 + cog;
        *(bf16x4*)(out + ob) = ov;
    }
}

// ---------------------------------------------------------------------------
// conv2..5: stage once, CS-split co-tiles per block, register pooling.
// Round 12: (a) shift value pipelined one kstep ahead (shtab LDS read off the
// bv critical path, like av); (b) pow2-only staging address math (wave-per-
// row); (c) full K-loop unroll for KT<=16; (d) OUTMODE=1 writes k-major
// x5b [k8][n][j] so fc's B reads coalesce.
// ---------------------------------------------------------------------------
template<int Ci, int Co, int H, int RB, int IMGS, int OUTMODE, int CS>
__global__ __launch_bounds__(256) void conv2d_mfma_k(
    const __bf16* __restrict__ X, const __bf16* __restrict__ Wt,
    const float* __restrict__ bias, void* __restrict__ outp) {
    constexpr int W    = H;
    constexpr int PW   = W + 4;
    constexpr int PR   = RB + 4;
    constexpr int PIX  = RB * W;
    constexpr int P    = IMGS * PIX;
    constexpr int SE   = Ci + (Ci >= 16 ? 8 : 0);   // bank-coprime stride
    constexpr int SB   = SE * 2;                    // 16/48/80/144 B
    constexpr int K    = 25 * Ci;
    constexpr int KTF  = K / 32;
    constexpr int KT   = KTF + (K % 32 != 0 ? 1 : 0);
    constexpr int NK8  = KT * 4;                    // k8 slots (<=200)
    constexpr int FW   = P / 64;                    // frags per wave
    constexpr int NCOT = Co / 16 / CS;              // co tiles this block
    constexpr int C8   = Ci / 8;
    constexpr int LC8  = (C8 == 1 ? 0 : (C8 == 2 ? 1 : (C8 == 4 ? 2 : 3)));
    constexpr int BPI  = H / RB;
    constexpr int OW   = W / 2;

    __shared__ __align__(16) char smem[IMGS * PR * PW * SB];
    __shared__ int shtab[NK8];

    const int tid = threadIdx.x;
    const int b0  = (blockIdx.x / BPI) * IMGS;
    const int y0  = (blockIdx.x % BPI) * RB;
    const int co0 = blockIdx.y * (NCOT * 16);

    const int lane = tid & 63, wave = tid >> 6;

    // ---- per-k8 shift table (magic divs once per block, not per kt) ----
    if (tid < NK8) {
        int kk  = tid * 8;
        int kkc = kk < K ? kk : 0;
        int tap = kkc / Ci, cio = kkc % Ci;
        shtab[tid] = ((tap / 5 - 2) * PW + (tap % 5 - 2)) * SB + cio * 2;
    }

    if constexpr (Ci == 8 && IMGS == 1) {
        // async staging: one wave-load per in-image padded row
        __bf16* xs = (__bf16*)smem;
        if (tid < PR * 4) {                      // halo cols 0,1,W+2,W+3
            int r = tid >> 2, s = tid & 3;
            int c = (s < 2) ? s : (W + s);
            *(bf16x8*)(xs + (r * PW + c) * 8) = (bf16x8){};
        }
        for (int pr = wave; pr < PR; pr += 4) {
            int gy = y0 + pr - 2;
            if ((unsigned)gy < (unsigned)H) {
                const __bf16* gsrc = X + ((size_t)(b0 * H + gy) * W + lane) * 8;
                __bf16* ldst = xs + (pr * PW + 2) * 8;     // + lane*16B by HW
                __builtin_amdgcn_global_load_lds((ga_t*)gsrc, (la_t*)ldst, 16, 0, 0);
            } else {
                *(bf16x8*)(xs + (pr * PW + 2 + lane) * 8) = (bf16x8){};
            }
        }
    } else {
        // wave-per-row staging; inner index math is pow2-only (shift/mask)
        for (int rr = wave; rr < IMGS * PR; rr += 4) {
            int img = (IMGS == 1) ? 0 : (rr / PR);
            int pr  = rr - img * PR;
            int gy  = y0 + pr - 2;
            char* rowp = smem + ((size_t)(img * PR + pr) * PW) * SB;
            const __bf16* grow = X + (((size_t)(b0 + img) * H + gy) * W) * Ci;
            for (int j = lane; j < PW * C8; j += 64) {
                int pc = j >> LC8;
                int s  = j & (C8 - 1);
                int gx = pc - 2;
                bf16x8 v = {};
                if ((unsigned)gy < (unsigned)H && (unsigned)gx < (unsigned)W)
                    v = *(const bf16x8*)(grow + (size_t)gx * Ci + s * 8);
                *(bf16x8*)(rowp + (size_t)pc * SB + s * 16) = v;
            }
        }
    }
    __syncthreads();

    const int quad = lane >> 4, l15 = lane & 15;

    int pbase[FW];
    f32x4 acc[FW][NCOT];
    int rg = 0, ch = 0, gbase = 0, img5 = 0;
    if constexpr (W >= 16) {
        constexpr int C16 = W / 16;
        ch = wave % C16;
        rg = wave / C16;
#pragma unroll
        for (int f = 0; f < FW; ++f) {
            int row = rg * FW + f;
            pbase[f] = ((row + 2) * PW + ch * 16 + l15 + 2) * SB;
        }
    } else {
        img5  = wave >> 1;
        gbase = (wave & 1) * FW;
#pragma unroll
        for (int f = 0; f < FW; ++f) {
            int g    = gbase + f;
            int row0 = 2 * g + (l15 >> 3);
            pbase[f] = ((img5 * PR + row0 + 2) * PW + (l15 & 7) + 2) * SB;
        }
    }
#pragma unroll
    for (int f = 0; f < FW; ++f)
#pragma unroll
        for (int c = 0; c < NCOT; ++c) acc[f][c] = f32x4{0.f, 0.f, 0.f, 0.f};

    const bf16x8 BZ = {};

    // ---- K loop: av AND shift pipelined one kstep ahead ----
    bf16x8 avc[NCOT];
    int shc;
    {
        int k8 = quad;                      // kt = 0 (always valid)
        shc = shtab[k8];
#pragma unroll
        for (int c = 0; c < NCOT; ++c)
            avc[c] = *(const bf16x8*)(Wt + ((size_t)k8 * Co + co0 + c * 16 + l15) * 8);
    }

    auto body = [&](int kt) {
        // prefetch next kstep's A + shift (off critical path)
        bf16x8 avn[NCOT];
        int shn;
        {
            int k8n = (kt + 1) * 4 + quad;
            if (kt + 1 >= KT || k8n * 8 >= K) k8n = 0;
            shn = shtab[k8n];
#pragma unroll
            for (int c = 0; c < NCOT; ++c)
                avn[c] = *(const bf16x8*)(Wt + ((size_t)k8n * Co + co0 + c * 16 + l15) * 8);
        }
        bool kok = true;
        if (K % 32 != 0 && kt == KT - 1)
            kok = (kt * 4 + quad) * 8 < K;
        bf16x8 bv[FW];
#pragma unroll
        for (int f = 0; f < FW; ++f) {
            bv[f] = *(const bf16x8*)(smem + pbase[f] + shc);
            if (!kok) bv[f] = BZ;
        }
#pragma unroll
        for (int c = 0; c < NCOT; ++c)
#pragma unroll
            for (int f = 0; f < FW; ++f)
                acc[f][c] = __builtin_amdgcn_mfma_f32_16x16x32_bf16(avc[c], bv[f], acc[f][c], 0, 0, 0);
        shc = shn;
#pragma unroll
        for (int c = 0; c < NCOT; ++c) avc[c] = avn[c];
    };

    if constexpr (KT <= 16) {
#pragma unroll
        for (int kt = 0; kt < KT; ++kt) body(kt);
    } else {
#pragma unroll 2
        for (int kt = 0; kt < KT; ++kt) body(kt);
    }

    if constexpr (W >= 16) {
#pragma unroll
        for (int fp = 0; fp < FW / 2; ++fp) {
            int f0  = 2 * fp;
            int row = rg * FW + f0;
            int oy  = (y0 + row) >> 1;
            int ox  = (ch * 16 + l15) >> 1;
            bool on = (l15 & 1) == 0;
#pragma unroll
            for (int c = 0; c < NCOT; ++c) {
                float4 bb = *(const float4*)(bias + co0 + c * 16 + quad * 4);
                bf16x4 ov;
#pragma unroll
                for (int r = 0; r < 4; ++r) {
                    float v0 = acc[f0][c][r];
                    float h0 = fmaxf(v0, __shfl_xor(v0, 1));
                    float v1 = acc[f0 + 1][c][r];
                    float h1 = fmaxf(v1, __shfl_xor(v1, 1));
                    float m  = fmaxf(h0, h1) + ((const float*)&bb)[r];
                    ov[r] = (__bf16)fmaxf(m, 0.f);
                }
                if (on)
                    *(bf16x4*)((__bf16*)outp +
                        (((size_t)b0 * (H / 2) + oy) * OW + ox) * Co + co0 + c * 16 + quad * 4) = ov;
            }
        }
    } else {
#pragma unroll
        for (int f = 0; f < FW; ++f) {
            int g   = gbase + f;
            bool on = ((l15 & 1) == 0) && (l15 < 8);
            int ox  = (l15 & 7) >> 1;
#pragma unroll
            for (int c = 0; c < NCOT; ++c) {
                float4 bb = *(const float4*)(bias + co0 + c * 16 + quad * 4);
#pragma unroll
                for (int r = 0; r < 4; ++r) {
                    float v  = acc[f][c][r];
                    float h  = fmaxf(v, __shfl_xor(v, 1));
                    float m2 = fmaxf(h, __shfl_xor(h, 8));
                    float m  = fmaxf(m2 + ((const float*)&bb)[r], 0.f);
                    if (on) {
                        if (OUTMODE == 1) {
                            // k-major x5b: [k8][n][j], k = co*16 + oy*4 + ox
                            int k = (co0 + c * 16 + quad * 4 + r) * 16 + g * 4 + ox;
                            ((__bf16*)outp)[((size_t)(k >> 3) * BATCH + (b0 + img5)) * 8 + (k & 7)] = (__bf16)m;
                        } else {
                            ((__bf16*)outp)[(size_t)(b0 + img5) * 2048 +
                                (co0 + c * 16 + quad * 4 + r) * 16 + g * 4 + ox] = (__bf16)m;
                        }
                    }
                }
            }
        }
    }
}

// ---------------------------------------------------------------------------
// FC via MFMA (512 blocks, 64 batch x 16 co each); emits f32 + bf16 emb.
// Round 12: Xb is k-major [k8][n][j] -> B reads are 256B coalesced.
// ---------------------------------------------------------------------------
__global__ __launch_bounds__(256) void fc_mfma_k(
    const __bf16* __restrict__ Xb, const __bf16* __restrict__ Wfc,
    const float* __restrict__ bias, float* __restrict__ emb,
    __bf16* __restrict__ embb) {
    const int tid  = threadIdx.x;
    const int lane = tid & 63, wave = tid >> 6;
    const int quad = lane >> 4, l15 = lane & 15;
    const int n    = blockIdx.x * 64 + wave * 16 + l15;
    const int co0  = blockIdx.y * 16;

    f32x4 acc = f32x4{0.f, 0.f, 0.f, 0.f};

#pragma unroll 8
    for (int kt = 0; kt < 64; ++kt) {
        int k8 = kt * 4 + quad;
        bf16x8 av = *(const bf16x8*)(Wfc + ((size_t)k8 * 1024 + co0 + l15) * 8);
        bf16x8 bv = *(const bf16x8*)(Xb + ((size_t)k8 * BATCH + n) * 8);
        acc = __builtin_amdgcn_mfma_f32_16x16x32_bf16(av, bv, acc, 0, 0, 0);
    }

    float4 b4 = *(const float4*)(bias + co0 + quad * 4);
    f32x4 v = acc;
    v[0] += b4.x; v[1] += b4.y; v[2] += b4.z; v[3] += b4.w;
    *(f32x4*)(emb + (size_t)n * 1024 + co0 + quad * 4) = v;
    bf16x4 eb;
    eb[0] = (__bf16)v[0]; eb[1] = (__bf16)v[1];
    eb[2] = (__bf16)v[2]; eb[3] = (__bf16)v[3];
    *(bf16x4*)(embb + (size_t)n * 1024 + co0 + quad * 4) = eb;
}

// ---------------------------------------------------------------------------
// Attention via MFMA: 32 blocks x 16 batch cols; 128 att rows per block.
// ---------------------------------------------------------------------------
__global__ __launch_bounds__(256) void att_mfma_k(
    const __bf16* __restrict__ embb, const __bf16* __restrict__ Wa,
    const float* __restrict__ b1, const float* __restrict__ w2,
    const float* __restrict__ b2, float* __restrict__ logits) {
    const int tid = threadIdx.x, lane = tid & 63, wave = tid >> 6;
    const int quad = lane >> 4, l15 = lane & 15;
    const int n = blockIdx.x * 16 + l15;        // batch index (32 blocks)

    f32x4 acc[2];
    acc[0] = f32x4{0.f, 0.f, 0.f, 0.f};
    acc[1] = f32x4{0.f, 0.f, 0.f, 0.f};

#pragma unroll 4
    for (int kt = 0; kt < 32; ++kt) {
        int k8 = kt * 4 + quad;
        bf16x8 bv = *(const bf16x8*)(embb + (size_t)n * 1024 + k8 * 8);
#pragma unroll
        for (int t = 0; t < 2; ++t) {
            int o0 = (wave * 2 + t) * 16;
            bf16x8 av = *(const bf16x8*)(Wa + ((size_t)k8 * 128 + o0 + l15) * 8);
            acc[t] = __builtin_amdgcn_mfma_f32_16x16x32_bf16(av, bv, acc[t], 0, 0, 0);
        }
    }

    float s = 0.f;
#pragma unroll
    for (int t = 0; t < 2; ++t) {
#pragma unroll
        for (int r = 0; r < 4; ++r) {
            int o = (wave * 2 + t) * 16 + quad * 4 + r;
            s += tanhf(acc[t][r] + b1[o]) * w2[o];
        }
    }
    s += __shfl_xor(s, 16);
    s += __shfl_xor(s, 32);

    __shared__ float part[4][16];
    if (lane < 16) part[wave][l15] = s;
    __syncthreads();
    if (tid < 16)
        logits[blockIdx.x * 16 + tid] =
            part[0][tid] + part[1][tid] + part[2][tid] + part[3][tid] + b2[0];
}

// ---------------------------------------------------------------------------
// Segment softmax + aggregation + classifier.  case_ids are SORTED ->
// binary search for the contiguous [lo,hi) range of each case.
// ---------------------------------------------------------------------------
__global__ __launch_bounds__(256) void segment_k(
    const float* __restrict__ emb, const float* __restrict__ logits,
    const int* __restrict__ cid, const float* __restrict__ clf_w,
    const float* __restrict__ clf_b, float* __restrict__ out) {
    const int c = blockIdx.x;
    const int t = threadIdx.x;
    __shared__ int cids[BATCH];
    __shared__ float red[256];
    for (int i = t; i < BATCH; i += 256) cids[i] = cid[i];
    __syncthreads();

    int lo, hi;
    {
        int l = 0, r = BATCH;
        while (l < r) { int m = (l + r) >> 1; if (cids[m] < c) l = m + 1; else r = m; }
        lo = l;
        r = BATCH;
        while (l < r) { int m = (l + r) >> 1; if (cids[m] <= c) l = m + 1; else r = m; }
        hi = l;
    }

    float lm = -1e30f;
    for (int b = lo + t; b < hi; b += 256) lm = fmaxf(lm, logits[b]);
    red[t] = lm; __syncthreads();
    for (int s = 128; s > 0; s >>= 1) {
        if (t < s) red[t] = fmaxf(red[t], red[t + s]);
        __syncthreads();
    }
    float smax = red[0]; __syncthreads();

    float ls = 0.f;
    for (int b = lo + t; b < hi; b += 256) ls += expf(logits[b] - smax);
    red[t] = ls; __syncthreads();
    for (int s = 128; s > 0; s >>= 1) {
        if (t < s) red[t] += red[t + s];
        __syncthreads();
    }
    float denom = red[0]; __syncthreads();
    float inv = (denom > 0.f) ? 1.f / denom : 0.f;

    const int h0 = t * 4;
    float g0 = 0.f, g1 = 0.f, g2 = 0.f, g3 = 0.f;
    for (int b = lo; b < hi; ++b) {
        float wgt = expf(logits[b] - smax) * inv;
        float4 ev = *(const float4*)(emb + (size_t)b * HID + h0);
        g0 = fmaf(wgt, ev.x, g0);
        g1 = fmaf(wgt, ev.y, g1);
        g2 = fmaf(wgt, ev.z, g2);
        g3 = fmaf(wgt, ev.w, g3);
    }
    float4 cw = *(const float4*)(clf_w + h0);
    float ca = g0 * cw.x + g1 * cw.y + g2 * cw.z + g3 * cw.w;
    red[t] = ca; __syncthreads();
    for (int s = 128; s > 0; s >>= 1) {
        if (t < s) red[t] += red[t + s];
        __syncthreads();
    }
    if (t == 0) out[c] = 1.f / (1.f + expf(-(red[0] + clf_b[0])));
}

// ---------------------------------------------------------------------------
extern "C" void kernel_launch(void* const* d_in, const int* in_sizes, int n_in,
                              void* d_out, int out_size, void* d_ws, size_t ws_size,
                              hipStream_t stream) {
    const float* data = (const float*)d_in[0];
    const int*   cid  = (const int*)d_in[1];
    const float* cw1 = (const float*)d_in[2],  * cb1 = (const float*)d_in[3];
    const float* cw2 = (const float*)d_in[4],  * cb2 = (const float*)d_in[5];
    const float* cw3 = (const float*)d_in[6],  * cb3 = (const float*)d_in[7];
    const float* cw4 = (const float*)d_in[8],  * cb4 = (const float*)d_in[9];
    const float* cw5 = (const float*)d_in[10], * cb5 = (const float*)d_in[11];
    const float* fcw = (const float*)d_in[12], * fcb = (const float*)d_in[13];
    const float* aw1 = (const float*)d_in[14], * ab1 = (const float*)d_in[15];
    const float* aw2 = (const float*)d_in[16], * ab2 = (const float*)d_in[17];
    const float* clw = (const float*)d_in[18], * clb = (const float*)d_in[19];
    float* out = (float*)d_out;

    // workspace (bytes), non-overlapping, ~71.9 MB
    char* wsb = (char*)d_ws;
    __bf16* x1  = (__bf16*)(wsb);              // 512*4096*8   bf16 = 33,554,432 B
    __bf16* x2  = (__bf16*)(wsb + 33554432);   // 512*1024*16  bf16 = 16,777,216 B
    __bf16* x3  = (__bf16*)(wsb + 50331648);   // 512*256*32   bf16 =  8,388,608 B
    __bf16* x4  = (__bf16*)(wsb + 58720256);   // 512*64*64    bf16 =  4,194,304 B
    __bf16* x5b = (__bf16*)(wsb + 62914560);   // 512*2048     bf16 =  2,097,152 B
    float*  emb = (float*) (wsb + 65011712);   // 512*1024     f32  =  2,097,152 B
    float*  lg  = (float*) (wsb + 67108864);   // 512 f32
    __bf16* wt2 = (__bf16*)(wsb + 67110912);   //   3,200 bf16
    __bf16* wt3 = (__bf16*)(wsb + 67117312);   //  12,800 bf16
    __bf16* wt4 = (__bf16*)(wsb + 67142912);   //  51,200 bf16
    __bf16* wt5 = (__bf16*)(wsb + 67245312);   // 204,800 bf16
    __bf16* wfc = (__bf16*)(wsb + 67654912);   // 2,097,152 bf16 = 4,194,304 B
    __bf16* wt1 = (__bf16*)(wsb + 71849216);   //   2,048 bf16
    // overlaid in x1's region, which is dead after conv2 completes:
    __bf16* wa   = (__bf16*)(wsb);             // 131,072 bf16 = 262,144 B
    __bf16* embb = (__bf16*)(wsb + 1048576);   // 512*1024 bf16 = 1,048,576 B

    // fused weight preconvert (one launch): 2,371,200 elems
    wprep_k<<<9263, 256, 0, stream>>>(cw1, cw2, cw3, cw4, cw5, fcw,
                                      wt1, wt2, wt3, wt4, wt5, wfc);

    // conv1: 512 images x 32 row-blocks (R=4, round-1 form)
    conv1_mfma_k<<<16384, 256, 0, stream>>>(data, wt1, cb1, x1);

    // conv2..5
    conv2d_mfma_k<8,  16,  64, 8, 1, 0, 1><<<4096, 256, 0, stream>>>(x1, wt2, cb2, x2);
    // x1 is dead from here on: stage attention weights into its region
    watt_k<<<512, 256, 0, stream>>>(aw1, wa);
    conv2d_mfma_k<16, 32,  32, 8, 1, 0, 1><<<2048, 256, 0, stream>>>(x2, wt3, cb3, x3);
    conv2d_mfma_k<32, 64,  16, 8, 1, 0, 2><<<dim3(1024, 2), 256, 0, stream>>>(x3, wt4, cb4, x4);
    conv2d_mfma_k<64, 128, 8,  8, 2, 1, 4><<<dim3(256, 4), 256, 0, stream>>>(x4, wt5, cb5, x5b);

    fc_mfma_k<<<dim3(8, 64), 256, 0, stream>>>(x5b, wfc, fcb, emb, embb);
    att_mfma_k<<<32, 256, 0, stream>>>(embb, wa, ab1, aw2, ab2, lg);
    segment_k<<<NSEG, 256, 0, stream>>>(emb, lg, cid, clw, clb, out);
}